// Round 8
// baseline (223.931 us; speedup 1.0000x reference)
//
#include <hip/hip_runtime.h>
#include <hip/hip_bf16.h>

#define EPSV 1e-5f

typedef __attribute__((ext_vector_type(8))) short short8v;   // 8 bf16 in 4 VGPRs
typedef __attribute__((ext_vector_type(4))) float f32x4;

__device__ inline unsigned short f2bf(float f) {
  __hip_bfloat16 h = __float2bfloat16(f);
  return *reinterpret_cast<unsigned short*>(&h);
}

__device__ inline float siluf(float x) { return x / (1.f + expf(-x)); }

__device__ inline f32x4 silu4(f32x4 v) {
  f32x4 o;
  o[0] = siluf(v[0]); o[1] = siluf(v[1]);
  o[2] = siluf(v[2]); o[3] = siluf(v[3]);
  return o;
}

// ---------------- block-wide sum (256 threads = 4 waves) ----------------
__device__ inline float block_sum(float v, float* lds) {
  #pragma unroll
  for (int o = 32; o; o >>= 1) v += __shfl_xor(v, o);
  int tid = threadIdx.x;
  if ((tid & 63) == 0) lds[tid >> 6] = v;
  __syncthreads();
  float r = lds[0] + lds[1] + lds[2] + lds[3];
  __syncthreads();
  return r;
}

// inclusive prefix sum over 64 lanes (call from wave 0 only)
__device__ inline float wave_prefix_incl(float v, int lane) {
  #pragma unroll
  for (int o = 1; o < 64; o <<= 1) {
    float u = __shfl_up(v, o);
    if (lane >= o) v += u;
  }
  return v;
}

// ------- weight transpose tile W[K][N] -> Wt[N][K] bf16 -------
__device__ inline void wtconv_tile(const float* __restrict__ W,
                                   unsigned short* __restrict__ Wt,
                                   int K, int N, int bx, int by) {
  __shared__ float tile[64][65];
  int n0 = bx * 64, k0 = by * 64;
  int tid = threadIdx.x;
  int r = tid >> 4, c4 = (tid & 15) * 4;
  #pragma unroll
  for (int i = 0; i < 4; i++) {
    int kk = r + i * 16;
    float4 v = make_float4(0.f, 0.f, 0.f, 0.f);
    if (n0 + c4 < N) v = *reinterpret_cast<const float4*>(&W[(long)(k0 + kk) * N + n0 + c4]);
    tile[kk][c4] = v.x; tile[kk][c4 + 1] = v.y; tile[kk][c4 + 2] = v.z; tile[kk][c4 + 3] = v.w;
  }
  __syncthreads();
  #pragma unroll
  for (int i = 0; i < 4; i++) {
    int nl = r + i * 16;
    if (n0 + nl < N) {
      ushort4 o;
      o.x = f2bf(tile[c4 + 0][nl]);
      o.y = f2bf(tile[c4 + 1][nl]);
      o.z = f2bf(tile[c4 + 2][nl]);
      o.w = f2bf(tile[c4 + 3][nl]);
      *reinterpret_cast<ushort4*>(&Wt[(long)(n0 + nl) * K + k0 + c4]) = o;
    }
  }
}

// ---- fused prologue: spa LN (2 rows/block, bf16 out) + all 4 weight transposes ----
__global__ __launch_bounds__(256) void ln_wt_fused(const float* __restrict__ x,
                                                   const float* __restrict__ w,
                                                   const float* __restrict__ bb,
                                                   unsigned short* __restrict__ outA,
                                                   const float* __restrict__ W0,
                                                   unsigned short* __restrict__ T0,
                                                   const float* __restrict__ W1,
                                                   unsigned short* __restrict__ T1,
                                                   const float* __restrict__ W2,
                                                   unsigned short* __restrict__ T2,
                                                   const float* __restrict__ W3,
                                                   unsigned short* __restrict__ T3) {
  int id = blockIdx.x;
  if (id < 4096) {
    int tid = threadIdx.x;
    __shared__ float lds[4];
    long row = (long)id * 2 + (tid >> 7);
    int lane = tid & 127;
    int base = (tid >> 7) << 1;
    float v = x[row * 128 + lane];
    float s = v;
    #pragma unroll
    for (int o = 32; o; o >>= 1) s += __shfl_xor(s, o);
    if ((tid & 63) == 0) lds[tid >> 6] = s;
    __syncthreads();
    float m = (lds[base] + lds[base + 1]) * (1.f / 128.f);
    float d = v - m;
    float q = d * d;
    #pragma unroll
    for (int o = 32; o; o >>= 1) q += __shfl_xor(q, o);
    __syncthreads();
    if ((tid & 63) == 0) lds[tid >> 6] = q;
    __syncthreads();
    float inv = rsqrtf((lds[base] + lds[base + 1]) * (1.f / 128.f) + EPSV);
    outA[row * 128 + lane] = f2bf(d * inv * w[lane] + bb[lane]);
  } else {
    id -= 4096;
    if (id < 22)        { int r = id;        wtconv_tile(W0, T0, 128,  644,  r % 11, r / 11); }
    else if (id < 30)   { int r = id - 22;   wtconv_tile(W1, T1, 256,  128,  r % 2,  r / 2); }
    else if (id < 1102) { int r = id - 30;   wtconv_tile(W2, T2, 1024, 4256, r % 67, r / 67); }
    else                { int r = id - 1102; wtconv_tile(W3, T3, 2048, 1024, r % 16, r / 16); }
  }
}

// ---- spe LN pass 1: partial sums over 256-row L-segments (grid: seg×b) ----
__global__ __launch_bounds__(256) void spe_stats_part(const float* __restrict__ xspa,
                                                      float* __restrict__ part) {
  int seg = blockIdx.x, b = blockIdx.y;
  int tid = threadIdx.x;
  int sub = tid >> 5;
  int cg = (tid & 31) * 4;
  const float* base = xspa + (long)b * 131072 + (long)(seg * 256 + sub * 32) * 128 + cg;
  f32x4 s = {0.f, 0.f, 0.f, 0.f}, q = s;
  for (int l = 0; l < 32; l++) {
    f32x4 v = *reinterpret_cast<const f32x4*>(base + l * 128);
    s += v;
    q += v * v;
  }
  __shared__ float S[8][128], Q[8][128];
  *reinterpret_cast<f32x4*>(&S[sub][cg]) = s;
  *reinterpret_cast<f32x4*>(&Q[sub][cg]) = q;
  __syncthreads();
  if (tid < 128) {
    float ss = 0.f, qq = 0.f;
    #pragma unroll
    for (int i = 0; i < 8; i++) { ss += S[i][tid]; qq += Q[i][tid]; }
    float2 o; o.x = ss; o.y = qq;
    *reinterpret_cast<float2*>(&part[((seg * 8 + b) * 128 + tid) * 2]) = o;
  }
}

// ---- spe LN pass 2: finalize stats + normalize + transpose, emit bf16 ----
__global__ __launch_bounds__(256) void spe_normT(const float* __restrict__ xspa,
                                                 const float* __restrict__ part,
                                                 const float* __restrict__ w,
                                                 const float* __restrict__ bb,
                                                 unsigned short* __restrict__ out) {
  __shared__ float tile[128][65];
  int c0 = blockIdx.x * 64, l0 = blockIdx.y * 128, b = blockIdx.z;
  int tid = threadIdx.x;
  int rr = tid >> 4, c4 = (tid & 15) * 4;
  #pragma unroll
  for (int p = 0; p < 8; p++) {
    int l = rr + p * 16;
    f32x4 v = *reinterpret_cast<const f32x4*>(
        &xspa[((long)b * 1024 + l0 + l) * 128 + c0 + c4]);
    tile[l][c4] = v[0]; tile[l][c4 + 1] = v[1];
    tile[l][c4 + 2] = v[2]; tile[l][c4 + 3] = v[3];
  }
  __syncthreads();
  int ch = tid >> 2, lq = tid & 3;
  float ssum = 0.f, qsum = 0.f;
  #pragma unroll
  for (int sgi = 0; sgi < 4; sgi++) {
    float2 pq = *reinterpret_cast<const float2*>(&part[((sgi * 8 + b) * 128 + c0 + ch) * 2]);
    ssum += pq.x; qsum += pq.y;
  }
  float mm = ssum * (1.f / 1024.f);
  float rstd = rsqrtf(qsum * (1.f / 1024.f) - mm * mm + EPSV);
  #pragma unroll
  for (int j = 0; j < 8; j++) {
    int qidx = lq + j * 4;
    int l = qidx * 4;
    float4 wv = *reinterpret_cast<const float4*>(&w[l0 + l]);
    float4 bv = *reinterpret_cast<const float4*>(&bb[l0 + l]);
    ushort4 o;
    o.x = f2bf((tile[l + 0][ch] - mm) * rstd * wv.x + bv.x);
    o.y = f2bf((tile[l + 1][ch] - mm) * rstd * wv.y + bv.y);
    o.z = f2bf((tile[l + 2][ch] - mm) * rstd * wv.z + bv.z);
    o.w = f2bf((tile[l + 3][ch] - mm) * rstd * wv.w + bv.w);
    *reinterpret_cast<ushort4*>(&out[((long)b * 128 + c0 + ch) * 1024 + l0 + l]) = o;
  }
}

// ------- 128x128-tile bf16 MFMA GEMM with column-split epilogue -------
__global__ __launch_bounds__(256) void gemm128_split(const unsigned short* __restrict__ A,
                                                     const unsigned short* __restrict__ Bt,
                                                     float* __restrict__ out,
                                                     float* __restrict__ o2,
                                                     float* __restrict__ o3,
                                                     int M, int N, int K,
                                                     int c1, int c2) {
  __shared__ unsigned short As[128 * 40];
  __shared__ unsigned short Bs[128 * 40];
  int tid = threadIdx.x;
  int lane = tid & 63, w = tid >> 6;
  int wr = (w >> 1) * 64, wc = (w & 1) * 64;
  int ln15 = lane & 15, kg = lane >> 4;
  int rowBase = blockIdx.y * 128, colBase = blockIdx.x * 128;
  int sr = tid >> 1, sk = (tid & 1) * 16;
  f32x4 acc[4][4] = {};
  for (int k0 = 0; k0 < K; k0 += 32) {
    {
      const unsigned short* ap = &A[(long)(rowBase + sr) * K + k0 + sk];
      short8v a0 = *reinterpret_cast<const short8v*>(ap);
      short8v a1 = *reinterpret_cast<const short8v*>(ap + 8);
      *reinterpret_cast<short8v*>(&As[sr * 40 + sk]) = a0;
      *reinterpret_cast<short8v*>(&As[sr * 40 + sk + 8]) = a1;
      int n = colBase + sr;
      short8v b0 = {0, 0, 0, 0, 0, 0, 0, 0}, b1 = b0;
      if (n < N) {
        const unsigned short* bp = &Bt[(long)n * K + k0 + sk];
        b0 = *reinterpret_cast<const short8v*>(bp);
        b1 = *reinterpret_cast<const short8v*>(bp + 8);
      }
      *reinterpret_cast<short8v*>(&Bs[sr * 40 + sk]) = b0;
      *reinterpret_cast<short8v*>(&Bs[sr * 40 + sk + 8]) = b1;
    }
    __syncthreads();
    short8v af[4], bfr[4];
    #pragma unroll
    for (int mt = 0; mt < 4; mt++)
      af[mt] = *reinterpret_cast<const short8v*>(&As[(wr + mt * 16 + ln15) * 40 + kg * 8]);
    #pragma unroll
    for (int nt = 0; nt < 4; nt++)
      bfr[nt] = *reinterpret_cast<const short8v*>(&Bs[(wc + nt * 16 + ln15) * 40 + kg * 8]);
    #pragma unroll
    for (int mt = 0; mt < 4; mt++)
      #pragma unroll
      for (int nt = 0; nt < 4; nt++)
        acc[mt][nt] = __builtin_amdgcn_mfma_f32_16x16x32_bf16(af[mt], bfr[nt], acc[mt][nt], 0, 0, 0);
    __syncthreads();
  }
  #pragma unroll
  for (int mt = 0; mt < 4; mt++)
    #pragma unroll
    for (int nt = 0; nt < 4; nt++)
      #pragma unroll
      for (int q = 0; q < 4; q++) {
        int r = rowBase + wr + mt * 16 + kg * 4 + q;
        int c = colBase + wc + nt * 16 + ln15;
        if (c < N) {
          float v = acc[mt][nt][q];
          if (c < c1) out[(long)r * c1 + c] = v;
          else if (c < c2) o2[(long)r * (c2 - c1) + (c - c1)] = v;
          else o3[(long)r * (N - c2) + (c - c2)] = v;
        }
      }
}

// ---------------- 64x64-tile bf16 MFMA GEMM (W_out epilogues) ----------------
template <int MODE>
__global__ __launch_bounds__(256) void gemm_mfma(const unsigned short* __restrict__ A,
                                                 const unsigned short* __restrict__ Bt,
                                                 const float* __restrict__ R,
                                                 float* __restrict__ out,
                                                 int M, int N, int K) {
  __shared__ unsigned short As[64 * 40];
  __shared__ unsigned short Bs[64 * 40];
  int tid = threadIdx.x;
  int lane = tid & 63, w = tid >> 6;
  int wr = (w >> 1) * 32, wc = (w & 1) * 32;
  int ln15 = lane & 15, kg = lane >> 4;
  int rowBase = blockIdx.y * 64, colBase = blockIdx.x * 64;
  int sm = tid >> 2, skb = (tid & 3) * 8;
  f32x4 acc[2][2] = {};
  for (int k0 = 0; k0 < K; k0 += 32) {
    {
      short8v av = *reinterpret_cast<const short8v*>(&A[(long)(rowBase + sm) * K + k0 + skb]);
      *reinterpret_cast<short8v*>(&As[sm * 40 + skb]) = av;
      int n = colBase + sm;
      short8v bv = {0, 0, 0, 0, 0, 0, 0, 0};
      if (n < N) bv = *reinterpret_cast<const short8v*>(&Bt[(long)n * K + k0 + skb]);
      *reinterpret_cast<short8v*>(&Bs[sm * 40 + skb]) = bv;
    }
    __syncthreads();
    short8v af[2], bfr[2];
    #pragma unroll
    for (int mt = 0; mt < 2; mt++)
      af[mt] = *reinterpret_cast<const short8v*>(&As[(wr + mt * 16 + ln15) * 40 + kg * 8]);
    #pragma unroll
    for (int nt = 0; nt < 2; nt++)
      bfr[nt] = *reinterpret_cast<const short8v*>(&Bs[(wc + nt * 16 + ln15) * 40 + kg * 8]);
    #pragma unroll
    for (int mt = 0; mt < 2; mt++)
      #pragma unroll
      for (int nt = 0; nt < 2; nt++)
        acc[mt][nt] = __builtin_amdgcn_mfma_f32_16x16x32_bf16(af[mt], bfr[nt], acc[mt][nt], 0, 0, 0);
    __syncthreads();
  }
  #pragma unroll
  for (int mt = 0; mt < 2; mt++)
    #pragma unroll
    for (int nt = 0; nt < 2; nt++)
      #pragma unroll
      for (int q = 0; q < 4; q++) {
        int r = rowBase + wr + mt * 16 + kg * 4 + q;
        int c = colBase + wc + nt * 16 + ln15;
        if (c < N) {
          float v = acc[mt][nt][q];
          if (MODE == 1) {
            out[(long)r * N + c] = v + R[(long)r * N + c];
          } else {
            int bb = r >> 7, ch = r & 127;
            out[(long)bb * 131072 + (long)c * 128 + ch] =
                v + R[((long)bb * 1024 + c) * 128 + ch];
          }
        }
      }
}

// ---- inline conv helper: conv'd+silu'd f32x4 at (batch row rowb+lt, ch) ----
__device__ inline f32x4 conv4(const float* __restrict__ xbc,
                              const float* __restrict__ cw,
                              const float* __restrict__ cb,
                              long rowb, int lt, int ch, int conv_dim) {
  f32x4 acc = *reinterpret_cast<const f32x4*>(&cb[ch]);
  #pragma unroll
  for (int k = 0; k < 4; k++) {
    int tt = lt + k - 3;
    if (tt >= 0) {
      f32x4 wv = *reinterpret_cast<const f32x4*>(&cw[k * conv_dim + ch]);
      f32x4 zv = *reinterpret_cast<const f32x4*>(&xbc[(rowb + tt) * conv_dim + ch]);
      acc += wv * zv;
    }
  }
  return silu4(acc);
}

// ===================== chunked SSD (T=64), conv+dtda inline =====================
// K1: chunk-state S_c[p,n]; grid = BH * nc_launch (c in [0, nc_launch))
__global__ __launch_bounds__(256) void ssd_local(const float* __restrict__ xbc,
                                                 const float* __restrict__ cw,
                                                 const float* __restrict__ cb,
                                                 const float* __restrict__ dtraw,
                                                 const float* __restrict__ dtbias,
                                                 const float* __restrict__ alog,
                                                 float* __restrict__ Sc,
                                                 float* __restrict__ Aprod,
                                                 int NC, int nc_launch, int H,
                                                 int conv_dim, int d_inner, int L) {
  int blk = blockIdx.x;
  int c = blk % nc_launch, bh = blk / nc_launch;
  int h = bh % H, b = bh / H;
  int tid = threadIdx.x;
  int lt0 = c * 64;
  long rowb = (long)b * L;
  __shared__ float Xs[64][64];
  __shared__ float Bs[64][64];
  __shared__ float Ws[64];
  int tq = tid >> 4, cq = (tid & 15) << 2;
  int xch = (h << 6) + cq, bch = d_inner + cq;
  #pragma unroll
  for (int i = 0; i < 4; i++) {
    int t = tq + i * 16, lt = lt0 + t;
    *reinterpret_cast<f32x4*>(&Xs[t][cq]) = conv4(xbc, cw, cb, rowb, lt, xch, conv_dim);
    *reinterpret_cast<f32x4*>(&Bs[t][cq]) = conv4(xbc, cw, cb, rowb, lt, bch, conv_dim);
  }
  if (tid < 64) {
    long r = (rowb + lt0 + tid) * H + h;
    float v = dtraw[r] + dtbias[h];
    float sp = (v > 20.f) ? v : log1pf(expf(v));
    float lav = -expf(alog[h]) * sp;
    float cum = wave_prefix_incl(lav, tid);
    float cT = __shfl(cum, 63);
    Ws[tid] = expf(cT - cum) * sp;
    if (tid == 63) Aprod[(long)bh * NC + c] = expf(cT);
  }
  __syncthreads();
  int p0 = (tid >> 4) << 2, n0 = (tid & 15) << 2;
  f32x4 S0 = {0.f, 0.f, 0.f, 0.f}, S1 = S0, S2 = S0, S3 = S0;
  for (int t = 0; t < 64; t++) {
    float w = Ws[t];
    f32x4 xv = *reinterpret_cast<const f32x4*>(&Xs[t][p0]);
    f32x4 bv = *reinterpret_cast<const f32x4*>(&Bs[t][n0]);
    S0 += bv * (w * xv[0]);
    S1 += bv * (w * xv[1]);
    S2 += bv * (w * xv[2]);
    S3 += bv * (w * xv[3]);
  }
  float* base = Sc + ((long)bh * NC + c) * 4096;
  *reinterpret_cast<f32x4*>(&base[(p0 + 0) * 64 + n0]) = S0;
  *reinterpret_cast<f32x4*>(&base[(p0 + 1) * 64 + n0]) = S1;
  *reinterpret_cast<f32x4*>(&base[(p0 + 2) * 64 + n0]) = S2;
  *reinterpret_cast<f32x4*>(&base[(p0 + 3) * 64 + n0]) = S3;
}

// K2: carry, parallel over p (spa only)
__global__ __launch_bounds__(128) void ssd_carry(float* __restrict__ Sc,
                                                 const float* __restrict__ Aprod,
                                                 int NC) {
  int blk = blockIdx.x;
  int bh = blk >> 3, ps = blk & 7;
  int tid = threadIdx.x;
  int p = ps * 8 + (tid >> 4);
  int n0 = (tid & 15) << 2;
  long off = (long)p * 64 + n0;
  f32x4 hacc = {0.f, 0.f, 0.f, 0.f};
  for (int c = 0; c < NC; c++) {
    float* base = Sc + ((long)bh * NC + c) * 4096;
    float a = Aprod[bh * NC + c];
    f32x4 s = *reinterpret_cast<f32x4*>(&base[off]);
    *reinterpret_cast<f32x4*>(&base[off]) = hacc;
    hacc = hacc * a + s;
  }
}

// K3: outputs. hp_prev=0: Hp[bh*NC+c] (carried in place). hp_prev=1: Hp[bh*NC+c-1],
// zero state for c==0 (Z phase skipped).
__global__ __launch_bounds__(256) void ssd_out(const float* __restrict__ xbc,
                                               const float* __restrict__ cw,
                                               const float* __restrict__ cb,
                                               const float* __restrict__ dtraw,
                                               const float* __restrict__ dtbias,
                                               const float* __restrict__ alog,
                                               const float* __restrict__ Hp,
                                               const float* __restrict__ Dvec,
                                               float* __restrict__ y,
                                               int NC, int H, int conv_dim,
                                               int d_inner, int L, int hp_prev) {
  int blk = blockIdx.x;
  int c = blk % NC, bh = blk / NC;
  int h = bh % H, b = bh / H;
  int tid = threadIdx.x;
  int lt0 = c * 64;
  long rowb = (long)b * L;
  __shared__ float CsT[64 * 68];   // [n][t]
  __shared__ float shB[64 * 68];   // BsT[n][s]  -> GmT[s][t]
  __shared__ float shX[64 * 68];   // Xs[s][p]   -> HpT[n][p]
  __shared__ float Cum[64], Dt[64];
  int tq = tid >> 4, cq = (tid & 15) << 2;
  int xch = (h << 6) + cq, bch = d_inner + cq, cch = d_inner + 64 + cq;
  #pragma unroll
  for (int i = 0; i < 4; i++) {
    int t = tq + i * 16, lt = lt0 + t;
    f32x4 cv = conv4(xbc, cw, cb, rowb, lt, cch, conv_dim);
    f32x4 bv = conv4(xbc, cw, cb, rowb, lt, bch, conv_dim);
    f32x4 xv = conv4(xbc, cw, cb, rowb, lt, xch, conv_dim);
    #pragma unroll
    for (int j = 0; j < 4; j++) {
      CsT[(cq + j) * 68 + t] = cv[j];
      shB[(cq + j) * 68 + t] = bv[j];
    }
    *reinterpret_cast<f32x4*>(&shX[t * 68 + cq]) = xv;
  }
  if (tid < 64) {
    long r = (rowb + lt0 + tid) * H + h;
    float v = dtraw[r] + dtbias[h];
    float sp = (v > 20.f) ? v : log1pf(expf(v));
    float lav = -expf(alog[h]) * sp;
    Cum[tid] = wave_prefix_incl(lav, tid);
    Dt[tid] = sp;
  }
  __syncthreads();
  int t0 = (tid >> 4) << 2, q0 = (tid & 15) << 2;
  // Phase A: G[t,s] = sum_n C[t,n] B[s,n]
  f32x4 G0 = {0.f, 0.f, 0.f, 0.f}, G1 = G0, G2 = G0, G3 = G0;
  for (int n = 0; n < 64; n++) {
    f32x4 cv = *reinterpret_cast<const f32x4*>(&CsT[n * 68 + t0]);
    f32x4 bv = *reinterpret_cast<const f32x4*>(&shB[n * 68 + q0]);
    G0 += cv * bv[0];
    G1 += cv * bv[1];
    G2 += cv * bv[2];
    G3 += cv * bv[3];
  }
  f32x4 gm[4] = {G0, G1, G2, G3};
  #pragma unroll
  for (int j = 0; j < 4; j++) {
    int s = q0 + j;
    float ds = Dt[s], cs = Cum[s];
    #pragma unroll
    for (int i = 0; i < 4; i++) {
      int t = t0 + i;
      gm[j][i] = (s <= t) ? gm[j][i] * expf(Cum[t] - cs) * ds : 0.f;
    }
  }
  __syncthreads();
  #pragma unroll
  for (int j = 0; j < 4; j++)
    *reinterpret_cast<f32x4*>(&shB[(q0 + j) * 68 + t0]) = gm[j];
  __syncthreads();
  // Phase B: Y = Gm @ X
  f32x4 Y0 = {0.f, 0.f, 0.f, 0.f}, Y1 = Y0, Y2 = Y0, Y3 = Y0;
  for (int s = 0; s < 64; s++) {
    f32x4 g4 = *reinterpret_cast<const f32x4*>(&shB[s * 68 + t0]);
    f32x4 x4 = *reinterpret_cast<const f32x4*>(&shX[s * 68 + q0]);
    Y0 += x4 * g4[0];
    Y1 += x4 * g4[1];
    Y2 += x4 * g4[2];
    Y3 += x4 * g4[3];
  }
  // save x values needed in Phase D before shX is overwritten
  f32x4 xg[4];
  #pragma unroll
  for (int i = 0; i < 4; i++)
    xg[i] = *reinterpret_cast<const f32x4*>(&shX[(t0 + i) * 68 + q0]);
  f32x4 Z0 = {0.f, 0.f, 0.f, 0.f}, Z1 = Z0, Z2 = Z0, Z3 = Z0;
  bool hasZ = !(hp_prev && c == 0);
  if (hasZ) {
    __syncthreads();
    const float* hb = Hp + ((long)bh * NC + c - (hp_prev ? 1 : 0)) * 4096;
    #pragma unroll
    for (int i = 0; i < 4; i++) {
      int p = tq + i * 16;
      f32x4 hv = *reinterpret_cast<const f32x4*>(&hb[p * 64 + cq]);
      #pragma unroll
      for (int j = 0; j < 4; j++) shX[(cq + j) * 68 + p] = hv[j];
    }
    __syncthreads();
    for (int n = 0; n < 64; n++) {
      f32x4 cv = *reinterpret_cast<const f32x4*>(&CsT[n * 68 + t0]);
      f32x4 hv = *reinterpret_cast<const f32x4*>(&shX[n * 68 + q0]);
      Z0 += hv * cv[0];
      Z1 += hv * cv[1];
      Z2 += hv * cv[2];
      Z3 += hv * cv[3];
    }
  }
  float Dv = Dvec[h];
  f32x4 Yv[4] = {Y0, Y1, Y2, Y3};
  f32x4 Zv[4] = {Z0, Z1, Z2, Z3};
  #pragma unroll
  for (int i = 0; i < 4; i++) {
    int t = t0 + i;
    float wB = expf(Cum[t]);
    f32x4 o = Yv[i] + Zv[i] * wB + xg[i] * Dv;
    *reinterpret_cast<f32x4*>(&y[(rowb + lt0 + t) * d_inner + (h << 6) + q0]) = o;
  }
}

// --- g = y*silu(z); g *= rsqrt(mean(g^2)+eps)*rms_w; emit bf16 A directly ---
template <int NJ>
__global__ __launch_bounds__(256) void gate_rms_bf16(const float* __restrict__ y,
                                                     const float* __restrict__ z,
                                                     const float* __restrict__ rmsw,
                                                     unsigned short* __restrict__ ab,
                                                     int d_inner) {
  long row = blockIdx.x;
  const float* yr = y + row * d_inner;
  const float* zr = z + row * d_inner;
  __shared__ float lds[4];
  float g[NJ];
  float ss = 0.f;
  #pragma unroll
  for (int j = 0; j < NJ; j++) {
    int c = threadIdx.x + (j << 8);
    float gv = yr[c] * siluf(zr[c]);
    g[j] = gv;
    ss += gv * gv;
  }
  float tot = block_sum(ss, lds);
  float inv = rsqrtf(tot / (float)d_inner + EPSV);
  #pragma unroll
  for (int j = 0; j < NJ; j++) {
    int c = threadIdx.x + (j << 8);
    ab[row * d_inner + c] = f2bf(g[j] * inv * rmsw[c]);
  }
}

extern "C" void kernel_launch(void* const* d_in, const int* in_sizes, int n_in,
                              void* d_out, int out_size, void* d_ws,
                              size_t ws_size, hipStream_t stream) {
  const float* x        = (const float*)d_in[0];
  const float* ln_spa_w = (const float*)d_in[1];
  const float* ln_spa_b = (const float*)d_in[2];
  const float* ln_spe_w = (const float*)d_in[3];
  const float* ln_spe_b = (const float*)d_in[4];
  const float* spa_W_in   = (const float*)d_in[5];
  const float* spa_conv_w = (const float*)d_in[6];
  const float* spa_conv_b = (const float*)d_in[7];
  const float* spa_dt_b   = (const float*)d_in[8];
  const float* spa_A_log  = (const float*)d_in[9];
  const float* spa_D      = (const float*)d_in[10];
  const float* spa_rms_w  = (const float*)d_in[11];
  const float* spa_W_out  = (const float*)d_in[12];
  const float* spe_W_in   = (const float*)d_in[13];
  const float* spe_conv_w = (const float*)d_in[14];
  const float* spe_conv_b = (const float*)d_in[15];
  const float* spe_dt_b   = (const float*)d_in[16];
  const float* spe_A_log  = (const float*)d_in[17];
  const float* spe_D      = (const float*)d_in[18];
  const float* spe_rms_w  = (const float*)d_in[19];
  const float* spe_W_out  = (const float*)d_in[20];
  float* out = (float*)d_out;

  float* ws = (float*)d_ws;
  // layout (floats) — same proven 63.9 MB budget
  float* xspa   = ws;                 // 1,048,576
  float* z      = ws + 1048576;       // 2,097,152
  float* xbcraw = ws + 3145728;       // 3,145,728 (stays live through SSD)
  float* dtraw  = ws + 6291456;       // 32,768
  float* Sc     = ws + 6324224;       // 2,097,152 (in old cv region)
  float* Ap     = ws + 8421376;       // 32,768
  float* part   = ws + 9469952;       // 8,192 (spe LN partials)
  float* yb     = ws + 9535488;       // 2,097,152
  unsigned short* Abf     = (unsigned short*)(ws + 11634688);  // 1,048,576 fl
  unsigned short* Wt_spai = (unsigned short*)(ws + 12683264);  // 41,216 fl
  unsigned short* Wt_spao = (unsigned short*)(ws + 12724480);  // 16,384 fl
  unsigned short* Wt_spei = (unsigned short*)(ws + 12740864);  // 2,179,072 fl
  unsigned short* Wt_speo = (unsigned short*)(ws + 14919936);  // 1,048,576 fl

  // 1. fused prologue: spa LN (blocks 0..4095) + all weight transposes
  hipLaunchKernelGGL(ln_wt_fused, dim3(5710), dim3(256), 0, stream,
                     x, ln_spa_w, ln_spa_b, Abf,
                     spa_W_in, Wt_spai, spa_W_out, Wt_spao,
                     spe_W_in, Wt_spei, spe_W_out, Wt_speo);

  // ================= spatial mamba (L=1024, d_model=128) =================
  hipLaunchKernelGGL(gemm128_split, dim3(6, 64), dim3(256), 0, stream,
                     Abf, Wt_spai, z, xbcraw, dtraw,
                     8192, 644, 128, 256, 640);
  hipLaunchKernelGGL(ssd_local, dim3(512), dim3(256), 0, stream,
                     xbcraw, spa_conv_w, spa_conv_b, dtraw, spa_dt_b, spa_A_log,
                     Sc, Ap, 16, 16, 4, 384, 256, 1024);
  hipLaunchKernelGGL(ssd_carry, dim3(256), dim3(128), 0, stream, Sc, Ap, 16);
  hipLaunchKernelGGL(ssd_out, dim3(512), dim3(256), 0, stream,
                     xbcraw, spa_conv_w, spa_conv_b, dtraw, spa_dt_b, spa_A_log,
                     Sc, spa_D, yb, 16, 4, 384, 256, 1024, 0);
  hipLaunchKernelGGL((gate_rms_bf16<1>), dim3(8192), dim3(256), 0, stream,
                     yb, z, spa_rms_w, Abf, 256);
  hipLaunchKernelGGL((gemm_mfma<1>), dim3(2, 128), dim3(256), 0, stream,
                     Abf, Wt_spao, x, xspa, 8192, 128, 256);

  // ================= spectral mamba (L=128, d_model=1024) =================
  hipLaunchKernelGGL(spe_stats_part, dim3(4, 8), dim3(256), 0, stream,
                     xspa, part);
  hipLaunchKernelGGL(spe_normT, dim3(2, 8, 8), dim3(256), 0, stream,
                     xspa, part, ln_spe_w, ln_spe_b, Abf);
  hipLaunchKernelGGL(gemm128_split, dim3(34, 8), dim3(256), 0, stream,
                     Abf, Wt_spei, z, xbcraw, dtraw,
                     1024, 4256, 1024, 2048, 4224);
  // only chunk 0's state is needed (NC=2): hprev(c=1) = S_0
  hipLaunchKernelGGL(ssd_local, dim3(256), dim3(256), 0, stream,
                     xbcraw, spe_conv_w, spe_conv_b, dtraw, spe_dt_b, spe_A_log,
                     Sc, Ap, 2, 1, 32, 2176, 2048, 128);
  hipLaunchKernelGGL(ssd_out, dim3(512), dim3(256), 0, stream,
                     xbcraw, spe_conv_w, spe_conv_b, dtraw, spe_dt_b, spe_A_log,
                     Sc, spe_D, yb, 2, 32, 2176, 2048, 128, 1);
  hipLaunchKernelGGL((gate_rms_bf16<8>), dim3(1024), dim3(256), 0, stream,
                     yb, z, spe_rms_w, Abf, 2048);
  hipLaunchKernelGGL((gemm_mfma<2>), dim3(16, 16), dim3(256), 0, stream,
                     Abf, Wt_speo, xspa, out, 1024, 1024, 2048);
}

// Round 9
// 201.710 us; speedup vs baseline: 1.1102x; 1.1102x over previous
//
#include <hip/hip_runtime.h>
#include <hip/hip_bf16.h>

#define EPSV 1e-5f

typedef __attribute__((ext_vector_type(8))) short short8v;   // 8 bf16 in 4 VGPRs
typedef __attribute__((ext_vector_type(4))) float f32x4;

__device__ inline unsigned short f2bf(float f) {
  __hip_bfloat16 h = __float2bfloat16(f);
  return *reinterpret_cast<unsigned short*>(&h);
}

__device__ inline float siluf(float x) { return x / (1.f + expf(-x)); }

// ---------------- block-wide sum (256 threads = 4 waves) ----------------
__device__ inline float block_sum(float v, float* lds) {
  #pragma unroll
  for (int o = 32; o; o >>= 1) v += __shfl_xor(v, o);
  int tid = threadIdx.x;
  if ((tid & 63) == 0) lds[tid >> 6] = v;
  __syncthreads();
  float r = lds[0] + lds[1] + lds[2] + lds[3];
  __syncthreads();
  return r;
}

// inclusive prefix sum over 64 lanes (call from wave 0 only)
__device__ inline float wave_prefix_incl(float v, int lane) {
  #pragma unroll
  for (int o = 1; o < 64; o <<= 1) {
    float u = __shfl_up(v, o);
    if (lane >= o) v += u;
  }
  return v;
}

// ------- weight transpose tile W[K][N] -> Wt[N][K] bf16 -------
__device__ inline void wtconv_tile(const float* __restrict__ W,
                                   unsigned short* __restrict__ Wt,
                                   int K, int N, int bx, int by) {
  __shared__ float tile[64][65];
  int n0 = bx * 64, k0 = by * 64;
  int tid = threadIdx.x;
  int r = tid >> 4, c4 = (tid & 15) * 4;
  #pragma unroll
  for (int i = 0; i < 4; i++) {
    int kk = r + i * 16;
    float4 v = make_float4(0.f, 0.f, 0.f, 0.f);
    if (n0 + c4 < N) v = *reinterpret_cast<const float4*>(&W[(long)(k0 + kk) * N + n0 + c4]);
    tile[kk][c4] = v.x; tile[kk][c4 + 1] = v.y; tile[kk][c4 + 2] = v.z; tile[kk][c4 + 3] = v.w;
  }
  __syncthreads();
  #pragma unroll
  for (int i = 0; i < 4; i++) {
    int nl = r + i * 16;
    if (n0 + nl < N) {
      ushort4 o;
      o.x = f2bf(tile[c4 + 0][nl]);
      o.y = f2bf(tile[c4 + 1][nl]);
      o.z = f2bf(tile[c4 + 2][nl]);
      o.w = f2bf(tile[c4 + 3][nl]);
      *reinterpret_cast<ushort4*>(&Wt[(long)(n0 + nl) * K + k0 + c4]) = o;
    }
  }
}

// ---- fused prologue: spa LN (2 rows/block, bf16 out) + all 4 weight transposes ----
__global__ __launch_bounds__(256) void ln_wt_fused(const float* __restrict__ x,
                                                   const float* __restrict__ w,
                                                   const float* __restrict__ bb,
                                                   unsigned short* __restrict__ outA,
                                                   const float* __restrict__ W0,
                                                   unsigned short* __restrict__ T0,
                                                   const float* __restrict__ W1,
                                                   unsigned short* __restrict__ T1,
                                                   const float* __restrict__ W2,
                                                   unsigned short* __restrict__ T2,
                                                   const float* __restrict__ W3,
                                                   unsigned short* __restrict__ T3) {
  int id = blockIdx.x;
  if (id < 4096) {
    int tid = threadIdx.x;
    __shared__ float lds[4];
    long row = (long)id * 2 + (tid >> 7);
    int lane = tid & 127;
    int base = (tid >> 7) << 1;
    float v = x[row * 128 + lane];
    float s = v;
    #pragma unroll
    for (int o = 32; o; o >>= 1) s += __shfl_xor(s, o);
    if ((tid & 63) == 0) lds[tid >> 6] = s;
    __syncthreads();
    float m = (lds[base] + lds[base + 1]) * (1.f / 128.f);
    float d = v - m;
    float q = d * d;
    #pragma unroll
    for (int o = 32; o; o >>= 1) q += __shfl_xor(q, o);
    __syncthreads();
    if ((tid & 63) == 0) lds[tid >> 6] = q;
    __syncthreads();
    float inv = rsqrtf((lds[base] + lds[base + 1]) * (1.f / 128.f) + EPSV);
    outA[row * 128 + lane] = f2bf(d * inv * w[lane] + bb[lane]);
  } else {
    id -= 4096;
    if (id < 22)        { int r = id;        wtconv_tile(W0, T0, 128,  644,  r % 11, r / 11); }
    else if (id < 30)   { int r = id - 22;   wtconv_tile(W1, T1, 256,  128,  r % 2,  r / 2); }
    else if (id < 1102) { int r = id - 30;   wtconv_tile(W2, T2, 1024, 4256, r % 67, r / 67); }
    else                { int r = id - 1102; wtconv_tile(W3, T3, 2048, 1024, r % 16, r / 16); }
  }
}

// ---- spe LN pass 1: partial sums over 256-row L-segments (grid: seg×b) ----
__global__ __launch_bounds__(256) void spe_stats_part(const float* __restrict__ xspa,
                                                      float* __restrict__ part) {
  int seg = blockIdx.x, b = blockIdx.y;
  int tid = threadIdx.x;
  int sub = tid >> 5;
  int cg = (tid & 31) * 4;
  const float* base = xspa + (long)b * 131072 + (long)(seg * 256 + sub * 32) * 128 + cg;
  f32x4 s = {0.f, 0.f, 0.f, 0.f}, q = s;
  for (int l = 0; l < 32; l++) {
    f32x4 v = *reinterpret_cast<const f32x4*>(base + l * 128);
    s += v;
    q += v * v;
  }
  __shared__ float S[8][128], Q[8][128];
  *reinterpret_cast<f32x4*>(&S[sub][cg]) = s;
  *reinterpret_cast<f32x4*>(&Q[sub][cg]) = q;
  __syncthreads();
  if (tid < 128) {
    float ss = 0.f, qq = 0.f;
    #pragma unroll
    for (int i = 0; i < 8; i++) { ss += S[i][tid]; qq += Q[i][tid]; }
    float2 o; o.x = ss; o.y = qq;
    *reinterpret_cast<float2*>(&part[((seg * 8 + b) * 128 + tid) * 2]) = o;
  }
}

// ---- spe LN pass 2: finalize stats + normalize + transpose, emit bf16 ----
__global__ __launch_bounds__(256) void spe_normT(const float* __restrict__ xspa,
                                                 const float* __restrict__ part,
                                                 const float* __restrict__ w,
                                                 const float* __restrict__ bb,
                                                 unsigned short* __restrict__ out) {
  __shared__ float tile[128][65];
  int c0 = blockIdx.x * 64, l0 = blockIdx.y * 128, b = blockIdx.z;
  int tid = threadIdx.x;
  int rr = tid >> 4, c4 = (tid & 15) * 4;
  #pragma unroll
  for (int p = 0; p < 8; p++) {
    int l = rr + p * 16;
    f32x4 v = *reinterpret_cast<const f32x4*>(
        &xspa[((long)b * 1024 + l0 + l) * 128 + c0 + c4]);
    tile[l][c4] = v[0]; tile[l][c4 + 1] = v[1];
    tile[l][c4 + 2] = v[2]; tile[l][c4 + 3] = v[3];
  }
  __syncthreads();
  int ch = tid >> 2, lq = tid & 3;
  float ssum = 0.f, qsum = 0.f;
  #pragma unroll
  for (int sgi = 0; sgi < 4; sgi++) {
    float2 pq = *reinterpret_cast<const float2*>(&part[((sgi * 8 + b) * 128 + c0 + ch) * 2]);
    ssum += pq.x; qsum += pq.y;
  }
  float mm = ssum * (1.f / 1024.f);
  float rstd = rsqrtf(qsum * (1.f / 1024.f) - mm * mm + EPSV);
  #pragma unroll
  for (int j = 0; j < 8; j++) {
    int qidx = lq + j * 4;
    int l = qidx * 4;
    float4 wv = *reinterpret_cast<const float4*>(&w[l0 + l]);
    float4 bv = *reinterpret_cast<const float4*>(&bb[l0 + l]);
    ushort4 o;
    o.x = f2bf((tile[l + 0][ch] - mm) * rstd * wv.x + bv.x);
    o.y = f2bf((tile[l + 1][ch] - mm) * rstd * wv.y + bv.y);
    o.z = f2bf((tile[l + 2][ch] - mm) * rstd * wv.z + bv.z);
    o.w = f2bf((tile[l + 3][ch] - mm) * rstd * wv.w + bv.w);
    *reinterpret_cast<ushort4*>(&out[((long)b * 128 + c0 + ch) * 1024 + l0 + l]) = o;
  }
}

// ------- 128x128-tile bf16 MFMA GEMM with column-split epilogue -------
__global__ __launch_bounds__(256) void gemm128_split(const unsigned short* __restrict__ A,
                                                     const unsigned short* __restrict__ Bt,
                                                     float* __restrict__ out,
                                                     float* __restrict__ o2,
                                                     float* __restrict__ o3,
                                                     int M, int N, int K,
                                                     int c1, int c2) {
  __shared__ unsigned short As[128 * 40];
  __shared__ unsigned short Bs[128 * 40];
  int tid = threadIdx.x;
  int lane = tid & 63, w = tid >> 6;
  int wr = (w >> 1) * 64, wc = (w & 1) * 64;
  int ln15 = lane & 15, kg = lane >> 4;
  int rowBase = blockIdx.y * 128, colBase = blockIdx.x * 128;
  int sr = tid >> 1, sk = (tid & 1) * 16;
  f32x4 acc[4][4] = {};
  for (int k0 = 0; k0 < K; k0 += 32) {
    {
      const unsigned short* ap = &A[(long)(rowBase + sr) * K + k0 + sk];
      short8v a0 = *reinterpret_cast<const short8v*>(ap);
      short8v a1 = *reinterpret_cast<const short8v*>(ap + 8);
      *reinterpret_cast<short8v*>(&As[sr * 40 + sk]) = a0;
      *reinterpret_cast<short8v*>(&As[sr * 40 + sk + 8]) = a1;
      int n = colBase + sr;
      short8v b0 = {0, 0, 0, 0, 0, 0, 0, 0}, b1 = b0;
      if (n < N) {
        const unsigned short* bp = &Bt[(long)n * K + k0 + sk];
        b0 = *reinterpret_cast<const short8v*>(bp);
        b1 = *reinterpret_cast<const short8v*>(bp + 8);
      }
      *reinterpret_cast<short8v*>(&Bs[sr * 40 + sk]) = b0;
      *reinterpret_cast<short8v*>(&Bs[sr * 40 + sk + 8]) = b1;
    }
    __syncthreads();
    short8v af[4], bfr[4];
    #pragma unroll
    for (int mt = 0; mt < 4; mt++)
      af[mt] = *reinterpret_cast<const short8v*>(&As[(wr + mt * 16 + ln15) * 40 + kg * 8]);
    #pragma unroll
    for (int nt = 0; nt < 4; nt++)
      bfr[nt] = *reinterpret_cast<const short8v*>(&Bs[(wc + nt * 16 + ln15) * 40 + kg * 8]);
    #pragma unroll
    for (int mt = 0; mt < 4; mt++)
      #pragma unroll
      for (int nt = 0; nt < 4; nt++)
        acc[mt][nt] = __builtin_amdgcn_mfma_f32_16x16x32_bf16(af[mt], bfr[nt], acc[mt][nt], 0, 0, 0);
    __syncthreads();
  }
  #pragma unroll
  for (int mt = 0; mt < 4; mt++)
    #pragma unroll
    for (int nt = 0; nt < 4; nt++)
      #pragma unroll
      for (int q = 0; q < 4; q++) {
        int r = rowBase + wr + mt * 16 + kg * 4 + q;
        int c = colBase + wc + nt * 16 + ln15;
        if (c < N) {
          float v = acc[mt][nt][q];
          if (c < c1) out[(long)r * c1 + c] = v;
          else if (c < c2) o2[(long)r * (c2 - c1) + (c - c1)] = v;
          else o3[(long)r * (N - c2) + (c - c2)] = v;
        }
      }
}

// ---------------- 64x64-tile bf16 MFMA GEMM (W_out epilogues) ----------------
template <int MODE>
__global__ __launch_bounds__(256) void gemm_mfma(const unsigned short* __restrict__ A,
                                                 const unsigned short* __restrict__ Bt,
                                                 const float* __restrict__ R,
                                                 float* __restrict__ out,
                                                 int M, int N, int K) {
  __shared__ unsigned short As[64 * 40];
  __shared__ unsigned short Bs[64 * 40];
  int tid = threadIdx.x;
  int lane = tid & 63, w = tid >> 6;
  int wr = (w >> 1) * 32, wc = (w & 1) * 32;
  int ln15 = lane & 15, kg = lane >> 4;
  int rowBase = blockIdx.y * 64, colBase = blockIdx.x * 64;
  int sm = tid >> 2, skb = (tid & 3) * 8;
  f32x4 acc[2][2] = {};
  for (int k0 = 0; k0 < K; k0 += 32) {
    {
      short8v av = *reinterpret_cast<const short8v*>(&A[(long)(rowBase + sm) * K + k0 + skb]);
      *reinterpret_cast<short8v*>(&As[sm * 40 + skb]) = av;
      int n = colBase + sm;
      short8v bv = {0, 0, 0, 0, 0, 0, 0, 0};
      if (n < N) bv = *reinterpret_cast<const short8v*>(&Bt[(long)n * K + k0 + skb]);
      *reinterpret_cast<short8v*>(&Bs[sm * 40 + skb]) = bv;
    }
    __syncthreads();
    short8v af[2], bfr[2];
    #pragma unroll
    for (int mt = 0; mt < 2; mt++)
      af[mt] = *reinterpret_cast<const short8v*>(&As[(wr + mt * 16 + ln15) * 40 + kg * 8]);
    #pragma unroll
    for (int nt = 0; nt < 2; nt++)
      bfr[nt] = *reinterpret_cast<const short8v*>(&Bs[(wc + nt * 16 + ln15) * 40 + kg * 8]);
    #pragma unroll
    for (int mt = 0; mt < 2; mt++)
      #pragma unroll
      for (int nt = 0; nt < 2; nt++)
        acc[mt][nt] = __builtin_amdgcn_mfma_f32_16x16x32_bf16(af[mt], bfr[nt], acc[mt][nt], 0, 0, 0);
    __syncthreads();
  }
  #pragma unroll
  for (int mt = 0; mt < 2; mt++)
    #pragma unroll
    for (int nt = 0; nt < 2; nt++)
      #pragma unroll
      for (int q = 0; q < 4; q++) {
        int r = rowBase + wr + mt * 16 + kg * 4 + q;
        int c = colBase + wc + nt * 16 + ln15;
        if (c < N) {
          float v = acc[mt][nt][q];
          if (MODE == 1) {
            out[(long)r * N + c] = v + R[(long)r * N + c];
          } else {
            int bb = r >> 7, ch = r & 127;
            out[(long)bb * 131072 + (long)c * 128 + ch] =
                v + R[((long)bb * 1024 + c) * 128 + ch];
          }
        }
      }
}

// ---- fused: causal depthwise conv (float4 channels) + bias + SiLU | dt/la ----
__global__ __launch_bounds__(256) void conv_dtda(const float* __restrict__ zx,
                                                 const float* __restrict__ cw,
                                                 const float* __restrict__ cb,
                                                 float* __restrict__ cout,
                                                 const float* __restrict__ raw,
                                                 const float* __restrict__ dtbias,
                                                 const float* __restrict__ alog,
                                                 float* __restrict__ dt,
                                                 float* __restrict__ la,
                                                 int Bb, int L, int conv_dim,
                                                 int H, int rowsH, int convBlocks) {
  int tid = threadIdx.x;
  if ((int)blockIdx.x < convBlocks) {
    long idx4 = (long)blockIdx.x * 256 + tid;
    int nch4 = conv_dim >> 2;
    long total4 = (long)Bb * L * nch4;
    if (idx4 >= total4) return;
    int ch = (int)(idx4 % nch4) << 2;
    long rt = idx4 / nch4;
    int t = (int)(rt % L);
    int b = (int)(rt / L);
    f32x4 acc = *reinterpret_cast<const f32x4*>(&cb[ch]);
    #pragma unroll
    for (int k = 0; k < 4; k++) {
      int tt = t + k - 3;
      if (tt >= 0) {
        f32x4 wv = *reinterpret_cast<const f32x4*>(&cw[k * conv_dim + ch]);
        f32x4 zv = *reinterpret_cast<const f32x4*>(
            &zx[((long)b * L + tt) * conv_dim + ch]);
        acc += wv * zv;
      }
    }
    f32x4 o;
    o[0] = siluf(acc[0]); o[1] = siluf(acc[1]);
    o[2] = siluf(acc[2]); o[3] = siluf(acc[3]);
    *reinterpret_cast<f32x4*>(&cout[rt * conv_dim + ch]) = o;
  } else {
    int idx = ((int)blockIdx.x - convBlocks) * 256 + tid;
    if (idx >= rowsH) return;
    int h = idx % H;
    float v = raw[idx] + dtbias[h];
    float sp = (v > 20.f) ? v : log1pf(expf(v));
    dt[idx] = sp;
    la[idx] = -expf(alog[h]) * sp;
  }
}

// ===================== chunked SSD (T=64 per chunk) =====================
// K1: chunk-state S_c[p,n]; grid = BH * nc_launch (c in [0, nc_launch))
__global__ __launch_bounds__(256) void ssd_local(const float* __restrict__ xbc,
                                                 const float* __restrict__ dtv,
                                                 const float* __restrict__ la,
                                                 float* __restrict__ Sc,
                                                 float* __restrict__ Aprod,
                                                 int NC, int nc_launch, int H,
                                                 int conv_dim, int d_inner) {
  int blk = blockIdx.x;
  int c = blk % nc_launch, bh = blk / nc_launch;
  int h = bh % H, b = bh / H;
  int tid = threadIdx.x;
  long row0 = ((long)(b * NC + c)) * 64;
  __shared__ float Xs[64][64];
  __shared__ float Bs[64][64];
  __shared__ float Ws[64];
  int tq = tid >> 4, cq = (tid & 15) << 2;
  #pragma unroll
  for (int i = 0; i < 4; i++) {
    int t = tq + i * 16;
    const float* rp = xbc + (row0 + t) * conv_dim;
    *reinterpret_cast<f32x4*>(&Xs[t][cq]) =
        *reinterpret_cast<const f32x4*>(rp + (h << 6) + cq);
    *reinterpret_cast<f32x4*>(&Bs[t][cq]) =
        *reinterpret_cast<const f32x4*>(rp + d_inner + cq);
  }
  if (tid < 64) {
    long r = (row0 + tid) * H + h;
    float cum = wave_prefix_incl(la[r], tid);
    float cT = __shfl(cum, 63);
    Ws[tid] = expf(cT - cum) * dtv[r];
    if (tid == 63) Aprod[(long)bh * NC + c] = expf(cT);
  }
  __syncthreads();
  int p0 = (tid >> 4) << 2, n0 = (tid & 15) << 2;
  f32x4 S0 = {0.f, 0.f, 0.f, 0.f}, S1 = S0, S2 = S0, S3 = S0;
  for (int t = 0; t < 64; t++) {
    float w = Ws[t];
    f32x4 xv = *reinterpret_cast<const f32x4*>(&Xs[t][p0]);
    f32x4 bv = *reinterpret_cast<const f32x4*>(&Bs[t][n0]);
    S0 += bv * (w * xv[0]);
    S1 += bv * (w * xv[1]);
    S2 += bv * (w * xv[2]);
    S3 += bv * (w * xv[3]);
  }
  float* base = Sc + ((long)bh * NC + c) * 4096;
  *reinterpret_cast<f32x4*>(&base[(p0 + 0) * 64 + n0]) = S0;
  *reinterpret_cast<f32x4*>(&base[(p0 + 1) * 64 + n0]) = S1;
  *reinterpret_cast<f32x4*>(&base[(p0 + 2) * 64 + n0]) = S2;
  *reinterpret_cast<f32x4*>(&base[(p0 + 3) * 64 + n0]) = S3;
}

// K2: carry, parallel over p (spa only)
__global__ __launch_bounds__(128) void ssd_carry(float* __restrict__ Sc,
                                                 const float* __restrict__ Aprod,
                                                 int NC) {
  int blk = blockIdx.x;
  int bh = blk >> 3, ps = blk & 7;
  int tid = threadIdx.x;
  int p = ps * 8 + (tid >> 4);
  int n0 = (tid & 15) << 2;
  long off = (long)p * 64 + n0;
  f32x4 hacc = {0.f, 0.f, 0.f, 0.f};
  for (int c = 0; c < NC; c++) {
    float* base = Sc + ((long)bh * NC + c) * 4096;
    float a = Aprod[bh * NC + c];
    f32x4 s = *reinterpret_cast<f32x4*>(&base[off]);
    *reinterpret_cast<f32x4*>(&base[off]) = hacc;
    hacc = hacc * a + s;
  }
}

// K3: outputs. hp_prev=0: Hp slot (bh*NC+c) holds carried h_prev (in place).
// hp_prev=1: h_prev = Hp slot (bh*NC+c-1) = raw S of previous chunk; c==0 has
// zero state (Z phase skipped).
__global__ __launch_bounds__(256) void ssd_out(const float* __restrict__ xbc,
                                               const float* __restrict__ dtv,
                                               const float* __restrict__ la,
                                               const float* __restrict__ Hp,
                                               const float* __restrict__ Dvec,
                                               float* __restrict__ y,
                                               int NC, int H, int conv_dim,
                                               int d_inner, int hp_prev) {
  int blk = blockIdx.x;
  int c = blk % NC, bh = blk / NC;
  int h = bh % H, b = bh / H;
  int tid = threadIdx.x;
  long row0 = ((long)(b * NC + c)) * 64;
  __shared__ float CsT[64 * 68];   // [n][t]
  __shared__ float shB[64 * 68];   // BsT[n][s]  -> GmT[s][t]
  __shared__ float shX[64 * 68];   // Xs[s][p]   -> HpT[n][p]
  __shared__ float Cum[64], Dt[64];
  int tq = tid >> 4, cq = (tid & 15) << 2;
  #pragma unroll
  for (int i = 0; i < 4; i++) {
    int t = tq + i * 16;
    const float* rp = xbc + (row0 + t) * conv_dim;
    f32x4 cv = *reinterpret_cast<const f32x4*>(rp + d_inner + 64 + cq);
    f32x4 bv = *reinterpret_cast<const f32x4*>(rp + d_inner + cq);
    f32x4 xv = *reinterpret_cast<const f32x4*>(rp + (h << 6) + cq);
    #pragma unroll
    for (int j = 0; j < 4; j++) {
      CsT[(cq + j) * 68 + t] = cv[j];
      shB[(cq + j) * 68 + t] = bv[j];
    }
    *reinterpret_cast<f32x4*>(&shX[t * 68 + cq]) = xv;
  }
  if (tid < 64) {
    long r = (row0 + tid) * H + h;
    Cum[tid] = wave_prefix_incl(la[r], tid);
    Dt[tid] = dtv[r];
  }
  __syncthreads();
  int t0 = (tid >> 4) << 2, q0 = (tid & 15) << 2;
  // Phase A: G[t,s] = sum_n C[t,n] B[s,n]
  f32x4 G0 = {0.f, 0.f, 0.f, 0.f}, G1 = G0, G2 = G0, G3 = G0;
  for (int n = 0; n < 64; n++) {
    f32x4 cv = *reinterpret_cast<const f32x4*>(&CsT[n * 68 + t0]);
    f32x4 bv = *reinterpret_cast<const f32x4*>(&shB[n * 68 + q0]);
    G0 += cv * bv[0];
    G1 += cv * bv[1];
    G2 += cv * bv[2];
    G3 += cv * bv[3];
  }
  f32x4 gm[4] = {G0, G1, G2, G3};
  #pragma unroll
  for (int j = 0; j < 4; j++) {
    int s = q0 + j;
    float ds = Dt[s], cs = Cum[s];
    #pragma unroll
    for (int i = 0; i < 4; i++) {
      int t = t0 + i;
      gm[j][i] = (s <= t) ? gm[j][i] * expf(Cum[t] - cs) * ds : 0.f;
    }
  }
  __syncthreads();
  #pragma unroll
  for (int j = 0; j < 4; j++)
    *reinterpret_cast<f32x4*>(&shB[(q0 + j) * 68 + t0]) = gm[j];
  __syncthreads();
  // Phase B: Y = Gm @ X
  f32x4 Y0 = {0.f, 0.f, 0.f, 0.f}, Y1 = Y0, Y2 = Y0, Y3 = Y0;
  for (int s = 0; s < 64; s++) {
    f32x4 g4 = *reinterpret_cast<const f32x4*>(&shB[s * 68 + t0]);
    f32x4 x4 = *reinterpret_cast<const f32x4*>(&shX[s * 68 + q0]);
    Y0 += x4 * g4[0];
    Y1 += x4 * g4[1];
    Y2 += x4 * g4[2];
    Y3 += x4 * g4[3];
  }
  f32x4 Z0 = {0.f, 0.f, 0.f, 0.f}, Z1 = Z0, Z2 = Z0, Z3 = Z0;
  bool hasZ = !(hp_prev && c == 0);
  if (hasZ) {
    __syncthreads();
    const float* hb = Hp + ((long)bh * NC + c - (hp_prev ? 1 : 0)) * 4096;
    #pragma unroll
    for (int i = 0; i < 4; i++) {
      int p = tq + i * 16;
      f32x4 hv = *reinterpret_cast<const f32x4*>(&hb[p * 64 + cq]);
      #pragma unroll
      for (int j = 0; j < 4; j++) shX[(cq + j) * 68 + p] = hv[j];
    }
    __syncthreads();
    for (int n = 0; n < 64; n++) {
      f32x4 cv = *reinterpret_cast<const f32x4*>(&CsT[n * 68 + t0]);
      f32x4 hv = *reinterpret_cast<const f32x4*>(&shX[n * 68 + q0]);
      Z0 += hv * cv[0];
      Z1 += hv * cv[1];
      Z2 += hv * cv[2];
      Z3 += hv * cv[3];
    }
  }
  float Dv = Dvec[h];
  f32x4 Yv[4] = {Y0, Y1, Y2, Y3};
  f32x4 Zv[4] = {Z0, Z1, Z2, Z3};
  #pragma unroll
  for (int i = 0; i < 4; i++) {
    int t = t0 + i;
    float wB = expf(Cum[t]);
    const float* xp = xbc + (row0 + t) * conv_dim + (h << 6) + q0;
    f32x4 xg = *reinterpret_cast<const f32x4*>(xp);
    f32x4 o = Yv[i] + Zv[i] * wB + xg * Dv;
    *reinterpret_cast<f32x4*>(&y[(row0 + t) * d_inner + (h << 6) + q0]) = o;
  }
}

// --- g = y*silu(z); g *= rsqrt(mean(g^2)+eps)*rms_w; emit bf16 A directly ---
template <int NJ>
__global__ __launch_bounds__(256) void gate_rms_bf16(const float* __restrict__ y,
                                                     const float* __restrict__ z,
                                                     const float* __restrict__ rmsw,
                                                     unsigned short* __restrict__ ab,
                                                     int d_inner) {
  long row = blockIdx.x;
  const float* yr = y + row * d_inner;
  const float* zr = z + row * d_inner;
  __shared__ float lds[4];
  float g[NJ];
  float ss = 0.f;
  #pragma unroll
  for (int j = 0; j < NJ; j++) {
    int c = threadIdx.x + (j << 8);
    float gv = yr[c] * siluf(zr[c]);
    g[j] = gv;
    ss += gv * gv;
  }
  float tot = block_sum(ss, lds);
  float inv = rsqrtf(tot / (float)d_inner + EPSV);
  #pragma unroll
  for (int j = 0; j < NJ; j++) {
    int c = threadIdx.x + (j << 8);
    ab[row * d_inner + c] = f2bf(g[j] * inv * rmsw[c]);
  }
}

extern "C" void kernel_launch(void* const* d_in, const int* in_sizes, int n_in,
                              void* d_out, int out_size, void* d_ws,
                              size_t ws_size, hipStream_t stream) {
  const float* x        = (const float*)d_in[0];
  const float* ln_spa_w = (const float*)d_in[1];
  const float* ln_spa_b = (const float*)d_in[2];
  const float* ln_spe_w = (const float*)d_in[3];
  const float* ln_spe_b = (const float*)d_in[4];
  const float* spa_W_in   = (const float*)d_in[5];
  const float* spa_conv_w = (const float*)d_in[6];
  const float* spa_conv_b = (const float*)d_in[7];
  const float* spa_dt_b   = (const float*)d_in[8];
  const float* spa_A_log  = (const float*)d_in[9];
  const float* spa_D      = (const float*)d_in[10];
  const float* spa_rms_w  = (const float*)d_in[11];
  const float* spa_W_out  = (const float*)d_in[12];
  const float* spe_W_in   = (const float*)d_in[13];
  const float* spe_conv_w = (const float*)d_in[14];
  const float* spe_conv_b = (const float*)d_in[15];
  const float* spe_dt_b   = (const float*)d_in[16];
  const float* spe_A_log  = (const float*)d_in[17];
  const float* spe_D      = (const float*)d_in[18];
  const float* spe_rms_w  = (const float*)d_in[19];
  const float* spe_W_out  = (const float*)d_in[20];
  float* out = (float*)d_out;

  float* ws = (float*)d_ws;
  // layout (floats) — same proven 63.9 MB budget
  float* xspa   = ws;                 // 1,048,576
  float* z      = ws + 1048576;       // 2,097,152
  float* xbcraw = ws + 3145728;       // 3,145,728 (later Sc)
  float* dtraw  = ws + 6291456;       // 32,768    (later Aprod)
  float* cv     = ws + 6324224;       // 3,145,728
  float* dtb    = ws + 9469952;       // 32,768    (also spe LN partials)
  float* la     = ws + 9502720;       // 32,768
  float* yb     = ws + 9535488;       // 2,097,152
  unsigned short* Abf     = (unsigned short*)(ws + 11634688);  // 1,048,576 fl
  unsigned short* Wt_spai = (unsigned short*)(ws + 12683264);  // 41,216 fl
  unsigned short* Wt_spao = (unsigned short*)(ws + 12724480);  // 16,384 fl
  unsigned short* Wt_spei = (unsigned short*)(ws + 12740864);  // 2,179,072 fl
  unsigned short* Wt_speo = (unsigned short*)(ws + 14919936);  // 1,048,576 fl

  // 1. fused prologue: spa LN (blocks 0..4095) + all weight transposes
  hipLaunchKernelGGL(ln_wt_fused, dim3(5710), dim3(256), 0, stream,
                     x, ln_spa_w, ln_spa_b, Abf,
                     spa_W_in, Wt_spai, spa_W_out, Wt_spao,
                     spe_W_in, Wt_spei, spe_W_out, Wt_speo);

  // ================= spatial mamba (L=1024, d_model=128) =================
  hipLaunchKernelGGL(gemm128_split, dim3(6, 64), dim3(256), 0, stream,
                     Abf, Wt_spai, z, xbcraw, dtraw,
                     8192, 644, 128, 256, 640);
  hipLaunchKernelGGL(conv_dtda, dim3(3200), dim3(256), 0, stream,
                     xbcraw, spa_conv_w, spa_conv_b, cv,
                     dtraw, spa_dt_b, spa_A_log, dtb, la,
                     8, 1024, 384, 4, 32768, 3072);
  hipLaunchKernelGGL(ssd_local, dim3(512), dim3(256), 0, stream,
                     cv, dtb, la, xbcraw, dtraw, 16, 16, 4, 384, 256);
  hipLaunchKernelGGL(ssd_carry, dim3(256), dim3(128), 0, stream,
                     xbcraw, dtraw, 16);
  hipLaunchKernelGGL(ssd_out, dim3(512), dim3(256), 0, stream,
                     cv, dtb, la, xbcraw, spa_D, yb, 16, 4, 384, 256, 0);
  hipLaunchKernelGGL((gate_rms_bf16<1>), dim3(8192), dim3(256), 0, stream,
                     yb, z, spa_rms_w, Abf, 256);
  hipLaunchKernelGGL((gemm_mfma<1>), dim3(2, 128), dim3(256), 0, stream,
                     Abf, Wt_spao, x, xspa, 8192, 128, 256);

  // ================= spectral mamba (L=128, d_model=1024) =================
  hipLaunchKernelGGL(spe_stats_part, dim3(4, 8), dim3(256), 0, stream,
                     xspa, dtb);
  hipLaunchKernelGGL(spe_normT, dim3(2, 8, 8), dim3(256), 0, stream,
                     xspa, dtb, ln_spe_w, ln_spe_b, Abf);
  hipLaunchKernelGGL(gemm128_split, dim3(34, 8), dim3(256), 0, stream,
                     Abf, Wt_spei, z, xbcraw, dtraw,
                     1024, 4256, 1024, 2048, 4224);
  hipLaunchKernelGGL(conv_dtda, dim3(2304), dim3(256), 0, stream,
                     xbcraw, spe_conv_w, spe_conv_b, cv,
                     dtraw, spe_dt_b, spe_A_log, dtb, la,
                     8, 128, 2176, 32, 32768, 2176);
  // only chunk 0's state is needed (NC=2): hprev(c=1) = S_0
  hipLaunchKernelGGL(ssd_local, dim3(256), dim3(256), 0, stream,
                     cv, dtb, la, xbcraw, dtraw, 2, 1, 32, 2176, 2048);
  hipLaunchKernelGGL(ssd_out, dim3(512), dim3(256), 0, stream,
                     cv, dtb, la, xbcraw, spe_D, yb, 2, 32, 2176, 2048, 1);
  hipLaunchKernelGGL((gate_rms_bf16<8>), dim3(1024), dim3(256), 0, stream,
                     yb, z, spe_rms_w, Abf, 2048);
  hipLaunchKernelGGL((gemm_mfma<2>), dim3(16, 16), dim3(256), 0, stream,
                     Abf, Wt_speo, xspa, out, 1024, 1024, 2048);
}

// Round 10
// 199.027 us; speedup vs baseline: 1.1251x; 1.0135x over previous
//
#include <hip/hip_runtime.h>
#include <hip/hip_bf16.h>

#define EPSV 1e-5f

typedef __attribute__((ext_vector_type(8))) short short8v;   // 8 bf16 in 4 VGPRs
typedef __attribute__((ext_vector_type(4))) float f32x4;

__device__ inline unsigned short f2bf(float f) {
  __hip_bfloat16 h = __float2bfloat16(f);
  return *reinterpret_cast<unsigned short*>(&h);
}

__device__ inline float siluf(float x) { return x / (1.f + expf(-x)); }

// ---------------- block-wide sum (256 threads = 4 waves) ----------------
__device__ inline float block_sum(float v, float* lds) {
  #pragma unroll
  for (int o = 32; o; o >>= 1) v += __shfl_xor(v, o);
  int tid = threadIdx.x;
  if ((tid & 63) == 0) lds[tid >> 6] = v;
  __syncthreads();
  float r = lds[0] + lds[1] + lds[2] + lds[3];
  __syncthreads();
  return r;
}

// inclusive prefix sum over 64 lanes (call from wave 0 only)
__device__ inline float wave_prefix_incl(float v, int lane) {
  #pragma unroll
  for (int o = 1; o < 64; o <<= 1) {
    float u = __shfl_up(v, o);
    if (lane >= o) v += u;
  }
  return v;
}

// ------- weight transpose tile W[K][N] -> Wt[N][K] bf16 -------
__device__ inline void wtconv_tile(const float* __restrict__ W,
                                   unsigned short* __restrict__ Wt,
                                   int K, int N, int bx, int by) {
  __shared__ float tile[64][65];
  int n0 = bx * 64, k0 = by * 64;
  int tid = threadIdx.x;
  int r = tid >> 4, c4 = (tid & 15) * 4;
  #pragma unroll
  for (int i = 0; i < 4; i++) {
    int kk = r + i * 16;
    float4 v = make_float4(0.f, 0.f, 0.f, 0.f);
    if (n0 + c4 < N) v = *reinterpret_cast<const float4*>(&W[(long)(k0 + kk) * N + n0 + c4]);
    tile[kk][c4] = v.x; tile[kk][c4 + 1] = v.y; tile[kk][c4 + 2] = v.z; tile[kk][c4 + 3] = v.w;
  }
  __syncthreads();
  #pragma unroll
  for (int i = 0; i < 4; i++) {
    int nl = r + i * 16;
    if (n0 + nl < N) {
      ushort4 o;
      o.x = f2bf(tile[c4 + 0][nl]);
      o.y = f2bf(tile[c4 + 1][nl]);
      o.z = f2bf(tile[c4 + 2][nl]);
      o.w = f2bf(tile[c4 + 3][nl]);
      *reinterpret_cast<ushort4*>(&Wt[(long)(n0 + nl) * K + k0 + c4]) = o;
    }
  }
}

// ---- fused prologue: spa LN (2 rows/block, bf16 out) + all 4 weight transposes ----
__global__ __launch_bounds__(256) void ln_wt_fused(const float* __restrict__ x,
                                                   const float* __restrict__ w,
                                                   const float* __restrict__ bb,
                                                   unsigned short* __restrict__ outA,
                                                   const float* __restrict__ W0,
                                                   unsigned short* __restrict__ T0,
                                                   const float* __restrict__ W1,
                                                   unsigned short* __restrict__ T1,
                                                   const float* __restrict__ W2,
                                                   unsigned short* __restrict__ T2,
                                                   const float* __restrict__ W3,
                                                   unsigned short* __restrict__ T3) {
  int id = blockIdx.x;
  if (id < 4096) {
    int tid = threadIdx.x;
    __shared__ float lds[4];
    long row = (long)id * 2 + (tid >> 7);
    int lane = tid & 127;
    int base = (tid >> 7) << 1;
    float v = x[row * 128 + lane];
    float s = v;
    #pragma unroll
    for (int o = 32; o; o >>= 1) s += __shfl_xor(s, o);
    if ((tid & 63) == 0) lds[tid >> 6] = s;
    __syncthreads();
    float m = (lds[base] + lds[base + 1]) * (1.f / 128.f);
    float d = v - m;
    float q = d * d;
    #pragma unroll
    for (int o = 32; o; o >>= 1) q += __shfl_xor(q, o);
    __syncthreads();
    if ((tid & 63) == 0) lds[tid >> 6] = q;
    __syncthreads();
    float inv = rsqrtf((lds[base] + lds[base + 1]) * (1.f / 128.f) + EPSV);
    outA[row * 128 + lane] = f2bf(d * inv * w[lane] + bb[lane]);
  } else {
    id -= 4096;
    if (id < 22)        { int r = id;        wtconv_tile(W0, T0, 128,  644,  r % 11, r / 11); }
    else if (id < 30)   { int r = id - 22;   wtconv_tile(W1, T1, 256,  128,  r % 2,  r / 2); }
    else if (id < 1102) { int r = id - 30;   wtconv_tile(W2, T2, 1024, 4256, r % 67, r / 67); }
    else                { int r = id - 1102; wtconv_tile(W3, T3, 2048, 1024, r % 16, r / 16); }
  }
}

// ---- spe LN pass 2: finalize per-(b,ch) stats from GEMM partials,
//      normalize + transpose, emit bf16. part2: float2[(by*2+bx)*64 + cl]
__global__ __launch_bounds__(256) void spe_normT(const float* __restrict__ xspa,
                                                 const float* __restrict__ part2,
                                                 const float* __restrict__ w,
                                                 const float* __restrict__ bb,
                                                 unsigned short* __restrict__ out) {
  __shared__ float tile[128][65];
  int c0 = blockIdx.x * 64, l0 = blockIdx.y * 128, b = blockIdx.z;
  int tid = threadIdx.x;
  int rr = tid >> 4, c4 = (tid & 15) * 4;
  #pragma unroll
  for (int p = 0; p < 8; p++) {
    int l = rr + p * 16;
    f32x4 v = *reinterpret_cast<const f32x4*>(
        &xspa[((long)b * 1024 + l0 + l) * 128 + c0 + c4]);
    tile[l][c4] = v[0]; tile[l][c4 + 1] = v[1];
    tile[l][c4 + 2] = v[2]; tile[l][c4 + 3] = v[3];
  }
  __syncthreads();
  int ch = tid >> 2, lq = tid & 3;
  int gc = c0 + ch;                       // global channel 0..127
  int bx = gc >> 6, cl = gc & 63;
  float ssum = 0.f, qsum = 0.f;
  #pragma unroll
  for (int sub = 0; sub < 16; sub++) {
    int by = b * 16 + sub;
    float2 pq = *reinterpret_cast<const float2*>(&part2[(((by * 2 + bx) * 64) + cl) * 2]);
    ssum += pq.x; qsum += pq.y;
  }
  float mm = ssum * (1.f / 1024.f);
  float rstd = rsqrtf(qsum * (1.f / 1024.f) - mm * mm + EPSV);
  #pragma unroll
  for (int j = 0; j < 8; j++) {
    int qidx = lq + j * 4;
    int l = qidx * 4;
    float4 wv = *reinterpret_cast<const float4*>(&w[l0 + l]);
    float4 bv = *reinterpret_cast<const float4*>(&bb[l0 + l]);
    ushort4 o;
    o.x = f2bf((tile[l + 0][ch] - mm) * rstd * wv.x + bv.x);
    o.y = f2bf((tile[l + 1][ch] - mm) * rstd * wv.y + bv.y);
    o.z = f2bf((tile[l + 2][ch] - mm) * rstd * wv.z + bv.z);
    o.w = f2bf((tile[l + 3][ch] - mm) * rstd * wv.w + bv.w);
    *reinterpret_cast<ushort4*>(&out[((long)b * 128 + c0 + ch) * 1024 + l0 + l]) = o;
  }
}

// ------- 128x128-tile bf16 MFMA GEMM with column-split epilogue -------
__global__ __launch_bounds__(256) void gemm128_split(const unsigned short* __restrict__ A,
                                                     const unsigned short* __restrict__ Bt,
                                                     float* __restrict__ out,
                                                     float* __restrict__ o2,
                                                     float* __restrict__ o3,
                                                     int M, int N, int K,
                                                     int c1, int c2) {
  __shared__ unsigned short As[128 * 40];
  __shared__ unsigned short Bs[128 * 40];
  int tid = threadIdx.x;
  int lane = tid & 63, w = tid >> 6;
  int wr = (w >> 1) * 64, wc = (w & 1) * 64;
  int ln15 = lane & 15, kg = lane >> 4;
  int rowBase = blockIdx.y * 128, colBase = blockIdx.x * 128;
  int sr = tid >> 1, sk = (tid & 1) * 16;
  f32x4 acc[4][4] = {};
  for (int k0 = 0; k0 < K; k0 += 32) {
    {
      const unsigned short* ap = &A[(long)(rowBase + sr) * K + k0 + sk];
      short8v a0 = *reinterpret_cast<const short8v*>(ap);
      short8v a1 = *reinterpret_cast<const short8v*>(ap + 8);
      *reinterpret_cast<short8v*>(&As[sr * 40 + sk]) = a0;
      *reinterpret_cast<short8v*>(&As[sr * 40 + sk + 8]) = a1;
      int n = colBase + sr;
      short8v b0 = {0, 0, 0, 0, 0, 0, 0, 0}, b1 = b0;
      if (n < N) {
        const unsigned short* bp = &Bt[(long)n * K + k0 + sk];
        b0 = *reinterpret_cast<const short8v*>(bp);
        b1 = *reinterpret_cast<const short8v*>(bp + 8);
      }
      *reinterpret_cast<short8v*>(&Bs[sr * 40 + sk]) = b0;
      *reinterpret_cast<short8v*>(&Bs[sr * 40 + sk + 8]) = b1;
    }
    __syncthreads();
    short8v af[4], bfr[4];
    #pragma unroll
    for (int mt = 0; mt < 4; mt++)
      af[mt] = *reinterpret_cast<const short8v*>(&As[(wr + mt * 16 + ln15) * 40 + kg * 8]);
    #pragma unroll
    for (int nt = 0; nt < 4; nt++)
      bfr[nt] = *reinterpret_cast<const short8v*>(&Bs[(wc + nt * 16 + ln15) * 40 + kg * 8]);
    #pragma unroll
    for (int mt = 0; mt < 4; mt++)
      #pragma unroll
      for (int nt = 0; nt < 4; nt++)
        acc[mt][nt] = __builtin_amdgcn_mfma_f32_16x16x32_bf16(af[mt], bfr[nt], acc[mt][nt], 0, 0, 0);
    __syncthreads();
  }
  #pragma unroll
  for (int mt = 0; mt < 4; mt++)
    #pragma unroll
    for (int nt = 0; nt < 4; nt++)
      #pragma unroll
      for (int q = 0; q < 4; q++) {
        int r = rowBase + wr + mt * 16 + kg * 4 + q;
        int c = colBase + wc + nt * 16 + ln15;
        if (c < N) {
          float v = acc[mt][nt][q];
          if (c < c1) out[(long)r * c1 + c] = v;
          else if (c < c2) o2[(long)r * (c2 - c1) + (c - c1)] = v;
          else o3[(long)r * (N - c2) + (c - c2)] = v;
        }
      }
}

// ---------------- 64x64-tile bf16 MFMA GEMM (W_out epilogues) ----------------
// MODE 1: out = v + R; also emits deterministic per-block column {sum,sum^2}
//         partials of (v+R) into part2 (for the downstream transposed LN).
// MODE 2: transposed add (spe W_out): r=(b,ch) b=r>>7 ch=r&127;
//         out[b][c][ch] = v + R[b][c][ch].
template <int MODE>
__global__ __launch_bounds__(256) void gemm_mfma(const unsigned short* __restrict__ A,
                                                 const unsigned short* __restrict__ Bt,
                                                 const float* __restrict__ R,
                                                 float* __restrict__ out,
                                                 float* __restrict__ part2,
                                                 int M, int N, int K) {
  __shared__ unsigned short As[64 * 40];
  __shared__ unsigned short Bs[64 * 40];
  int tid = threadIdx.x;
  int lane = tid & 63, w = tid >> 6;
  int wr = (w >> 1) * 32, wc = (w & 1) * 32;
  int ln15 = lane & 15, kg = lane >> 4;
  int rowBase = blockIdx.y * 64, colBase = blockIdx.x * 64;
  int sm = tid >> 2, skb = (tid & 3) * 8;
  f32x4 acc[2][2] = {};
  for (int k0 = 0; k0 < K; k0 += 32) {
    {
      short8v av = *reinterpret_cast<const short8v*>(&A[(long)(rowBase + sm) * K + k0 + skb]);
      *reinterpret_cast<short8v*>(&As[sm * 40 + skb]) = av;
      int n = colBase + sm;
      short8v bv = {0, 0, 0, 0, 0, 0, 0, 0};
      if (n < N) bv = *reinterpret_cast<const short8v*>(&Bt[(long)n * K + k0 + skb]);
      *reinterpret_cast<short8v*>(&Bs[sm * 40 + skb]) = bv;
    }
    __syncthreads();
    short8v af[2], bfr[2];
    #pragma unroll
    for (int mt = 0; mt < 2; mt++)
      af[mt] = *reinterpret_cast<const short8v*>(&As[(wr + mt * 16 + ln15) * 40 + kg * 8]);
    #pragma unroll
    for (int nt = 0; nt < 2; nt++)
      bfr[nt] = *reinterpret_cast<const short8v*>(&Bs[(wc + nt * 16 + ln15) * 40 + kg * 8]);
    #pragma unroll
    for (int mt = 0; mt < 2; mt++)
      #pragma unroll
      for (int nt = 0; nt < 2; nt++)
        acc[mt][nt] = __builtin_amdgcn_mfma_f32_16x16x32_bf16(af[mt], bfr[nt], acc[mt][nt], 0, 0, 0);
    __syncthreads();
  }
  if (MODE == 1) {
    float sC[2] = {0.f, 0.f}, qC[2] = {0.f, 0.f};
    #pragma unroll
    for (int mt = 0; mt < 2; mt++)
      #pragma unroll
      for (int nt = 0; nt < 2; nt++)
        #pragma unroll
        for (int q = 0; q < 4; q++) {
          int r = rowBase + wr + mt * 16 + kg * 4 + q;
          int c = colBase + wc + nt * 16 + ln15;
          float v = acc[mt][nt][q] + R[(long)r * N + c];
          out[(long)r * N + c] = v;
          sC[nt] += v;
          qC[nt] += v * v;
        }
    // reduce over kg within wave (lanes 16,32 apart), deterministic order
    __shared__ float redS[4][32], redQ[4][32];
    #pragma unroll
    for (int nt = 0; nt < 2; nt++) {
      sC[nt] += __shfl_xor(sC[nt], 16);
      sC[nt] += __shfl_xor(sC[nt], 32);
      qC[nt] += __shfl_xor(qC[nt], 16);
      qC[nt] += __shfl_xor(qC[nt], 32);
    }
    if (lane < 16) {
      redS[w][ln15] = sC[0];       redQ[w][ln15] = qC[0];
      redS[w][16 + ln15] = sC[1];  redQ[w][16 + ln15] = qC[1];
    }
    __syncthreads();
    if (tid < 64) {
      int c = tid;
      int grp = c >> 5, lo = c & 31;   // waves {grp, grp+2} cover col c (rows 0-31, 32-63)
      float ss = redS[grp][lo] + redS[grp + 2][lo];
      float qq = redQ[grp][lo] + redQ[grp + 2][lo];
      long slot = ((long)(blockIdx.y * 2 + blockIdx.x) * 64 + c) * 2;
      part2[slot] = ss;
      part2[slot + 1] = qq;
    }
  } else {
    #pragma unroll
    for (int mt = 0; mt < 2; mt++)
      #pragma unroll
      for (int nt = 0; nt < 2; nt++)
        #pragma unroll
        for (int q = 0; q < 4; q++) {
          int r = rowBase + wr + mt * 16 + kg * 4 + q;
          int c = colBase + wc + nt * 16 + ln15;
          if (c < N) {
            int bb = r >> 7, ch = r & 127;
            out[(long)bb * 131072 + (long)c * 128 + ch] =
                acc[mt][nt][q] + R[((long)bb * 1024 + c) * 128 + ch];
          }
        }
  }
}

// ---- fused: causal depthwise conv (float4 channels) + bias + SiLU | dt/la ----
__global__ __launch_bounds__(256) void conv_dtda(const float* __restrict__ zx,
                                                 const float* __restrict__ cw,
                                                 const float* __restrict__ cb,
                                                 float* __restrict__ cout,
                                                 const float* __restrict__ raw,
                                                 const float* __restrict__ dtbias,
                                                 const float* __restrict__ alog,
                                                 float* __restrict__ dt,
                                                 float* __restrict__ la,
                                                 int Bb, int L, int conv_dim,
                                                 int H, int rowsH, int convBlocks) {
  int tid = threadIdx.x;
  if ((int)blockIdx.x < convBlocks) {
    long idx4 = (long)blockIdx.x * 256 + tid;
    int nch4 = conv_dim >> 2;
    long total4 = (long)Bb * L * nch4;
    if (idx4 >= total4) return;
    int ch = (int)(idx4 % nch4) << 2;
    long rt = idx4 / nch4;
    int t = (int)(rt % L);
    int b = (int)(rt / L);
    f32x4 acc = *reinterpret_cast<const f32x4*>(&cb[ch]);
    #pragma unroll
    for (int k = 0; k < 4; k++) {
      int tt = t + k - 3;
      if (tt >= 0) {
        f32x4 wv = *reinterpret_cast<const f32x4*>(&cw[k * conv_dim + ch]);
        f32x4 zv = *reinterpret_cast<const f32x4*>(
            &zx[((long)b * L + tt) * conv_dim + ch]);
        acc += wv * zv;
      }
    }
    f32x4 o;
    o[0] = siluf(acc[0]); o[1] = siluf(acc[1]);
    o[2] = siluf(acc[2]); o[3] = siluf(acc[3]);
    *reinterpret_cast<f32x4*>(&cout[rt * conv_dim + ch]) = o;
  } else {
    int idx = ((int)blockIdx.x - convBlocks) * 256 + tid;
    if (idx >= rowsH) return;
    int h = idx % H;
    float v = raw[idx] + dtbias[h];
    float sp = (v > 20.f) ? v : log1pf(expf(v));
    dt[idx] = sp;
    la[idx] = -expf(alog[h]) * sp;
  }
}

// ===================== chunked SSD (T=64 per chunk) =====================
// K1: chunk-state S_c[p,n]; grid = BH * nc_launch (c in [0, nc_launch))
__global__ __launch_bounds__(256) void ssd_local(const float* __restrict__ xbc,
                                                 const float* __restrict__ dtv,
                                                 const float* __restrict__ la,
                                                 float* __restrict__ Sc,
                                                 float* __restrict__ Aprod,
                                                 int NC, int nc_launch, int H,
                                                 int conv_dim, int d_inner) {
  int blk = blockIdx.x;
  int c = blk % nc_launch, bh = blk / nc_launch;
  int h = bh % H, b = bh / H;
  int tid = threadIdx.x;
  long row0 = ((long)(b * NC + c)) * 64;
  __shared__ float Xs[64][64];
  __shared__ float Bs[64][64];
  __shared__ float Ws[64];
  int tq = tid >> 4, cq = (tid & 15) << 2;
  #pragma unroll
  for (int i = 0; i < 4; i++) {
    int t = tq + i * 16;
    const float* rp = xbc + (row0 + t) * conv_dim;
    *reinterpret_cast<f32x4*>(&Xs[t][cq]) =
        *reinterpret_cast<const f32x4*>(rp + (h << 6) + cq);
    *reinterpret_cast<f32x4*>(&Bs[t][cq]) =
        *reinterpret_cast<const f32x4*>(rp + d_inner + cq);
  }
  if (tid < 64) {
    long r = (row0 + tid) * H + h;
    float cum = wave_prefix_incl(la[r], tid);
    float cT = __shfl(cum, 63);
    Ws[tid] = expf(cT - cum) * dtv[r];
    if (tid == 63) Aprod[(long)bh * NC + c] = expf(cT);
  }
  __syncthreads();
  int p0 = (tid >> 4) << 2, n0 = (tid & 15) << 2;
  f32x4 S0 = {0.f, 0.f, 0.f, 0.f}, S1 = S0, S2 = S0, S3 = S0;
  for (int t = 0; t < 64; t++) {
    float w = Ws[t];
    f32x4 xv = *reinterpret_cast<const f32x4*>(&Xs[t][p0]);
    f32x4 bv = *reinterpret_cast<const f32x4*>(&Bs[t][n0]);
    S0 += bv * (w * xv[0]);
    S1 += bv * (w * xv[1]);
    S2 += bv * (w * xv[2]);
    S3 += bv * (w * xv[3]);
  }
  float* base = Sc + ((long)bh * NC + c) * 4096;
  *reinterpret_cast<f32x4*>(&base[(p0 + 0) * 64 + n0]) = S0;
  *reinterpret_cast<f32x4*>(&base[(p0 + 1) * 64 + n0]) = S1;
  *reinterpret_cast<f32x4*>(&base[(p0 + 2) * 64 + n0]) = S2;
  *reinterpret_cast<f32x4*>(&base[(p0 + 3) * 64 + n0]) = S3;
}

// K3: outputs, with on-the-fly carry: h_prev = fold_{j<c} (h = A_j h + S_j)
// over RAW chunk states Sc. Bit-identical fold order to the old carry kernel.
__global__ __launch_bounds__(256) void ssd_out(const float* __restrict__ xbc,
                                               const float* __restrict__ dtv,
                                               const float* __restrict__ la,
                                               const float* __restrict__ Sc,
                                               const float* __restrict__ Aprod,
                                               const float* __restrict__ Dvec,
                                               float* __restrict__ y,
                                               int NC, int H, int conv_dim,
                                               int d_inner) {
  int blk = blockIdx.x;
  int c = blk % NC, bh = blk / NC;
  int h = bh % H, b = bh / H;
  int tid = threadIdx.x;
  long row0 = ((long)(b * NC + c)) * 64;
  __shared__ float CsT[64 * 68];   // [n][t]
  __shared__ float shB[64 * 68];   // BsT[n][s]  -> GmT[s][t]
  __shared__ float shX[64 * 68];   // Xs[s][p]   -> HpT[n][p]
  __shared__ float Cum[64], Dt[64];
  int tq = tid >> 4, cq = (tid & 15) << 2;
  #pragma unroll
  for (int i = 0; i < 4; i++) {
    int t = tq + i * 16;
    const float* rp = xbc + (row0 + t) * conv_dim;
    f32x4 cv = *reinterpret_cast<const f32x4*>(rp + d_inner + 64 + cq);
    f32x4 bv = *reinterpret_cast<const f32x4*>(rp + d_inner + cq);
    f32x4 xv = *reinterpret_cast<const f32x4*>(rp + (h << 6) + cq);
    #pragma unroll
    for (int j = 0; j < 4; j++) {
      CsT[(cq + j) * 68 + t] = cv[j];
      shB[(cq + j) * 68 + t] = bv[j];
    }
    *reinterpret_cast<f32x4*>(&shX[t * 68 + cq]) = xv;
  }
  // on-the-fly carry: registers in staging layout (rows tq+i*16, cols cq..cq+3)
  f32x4 hreg[4] = {};
  if (c > 0) {
    const float* ap = Aprod + (long)bh * NC;
    for (int j = 0; j < c; j++) {
      const float* sb = Sc + ((long)bh * NC + j) * 4096;
      float a = ap[j];
      #pragma unroll
      for (int i = 0; i < 4; i++) {
        int p = tq + i * 16;
        f32x4 sv = *reinterpret_cast<const f32x4*>(&sb[p * 64 + cq]);
        hreg[i] = hreg[i] * a + sv;
      }
    }
  }
  if (tid < 64) {
    long r = (row0 + tid) * H + h;
    Cum[tid] = wave_prefix_incl(la[r], tid);
    Dt[tid] = dtv[r];
  }
  __syncthreads();
  int t0 = (tid >> 4) << 2, q0 = (tid & 15) << 2;
  // Phase A: G[t,s] = sum_n C[t,n] B[s,n]
  f32x4 G0 = {0.f, 0.f, 0.f, 0.f}, G1 = G0, G2 = G0, G3 = G0;
  for (int n = 0; n < 64; n++) {
    f32x4 cv = *reinterpret_cast<const f32x4*>(&CsT[n * 68 + t0]);
    f32x4 bv = *reinterpret_cast<const f32x4*>(&shB[n * 68 + q0]);
    G0 += cv * bv[0];
    G1 += cv * bv[1];
    G2 += cv * bv[2];
    G3 += cv * bv[3];
  }
  f32x4 gm[4] = {G0, G1, G2, G3};
  #pragma unroll
  for (int j = 0; j < 4; j++) {
    int s = q0 + j;
    float ds = Dt[s], cs = Cum[s];
    #pragma unroll
    for (int i = 0; i < 4; i++) {
      int t = t0 + i;
      gm[j][i] = (s <= t) ? gm[j][i] * expf(Cum[t] - cs) * ds : 0.f;
    }
  }
  __syncthreads();
  #pragma unroll
  for (int j = 0; j < 4; j++)
    *reinterpret_cast<f32x4*>(&shB[(q0 + j) * 68 + t0]) = gm[j];
  __syncthreads();
  // Phase B: Y = Gm @ X
  f32x4 Y0 = {0.f, 0.f, 0.f, 0.f}, Y1 = Y0, Y2 = Y0, Y3 = Y0;
  for (int s = 0; s < 64; s++) {
    f32x4 g4 = *reinterpret_cast<const f32x4*>(&shB[s * 68 + t0]);
    f32x4 x4 = *reinterpret_cast<const f32x4*>(&shX[s * 68 + q0]);
    Y0 += x4 * g4[0];
    Y1 += x4 * g4[1];
    Y2 += x4 * g4[2];
    Y3 += x4 * g4[3];
  }
  f32x4 Z0 = {0.f, 0.f, 0.f, 0.f}, Z1 = Z0, Z2 = Z0, Z3 = Z0;
  if (c > 0) {
    __syncthreads();
    // write h_prev transposed into shX: HpT[n][p]
    #pragma unroll
    for (int i = 0; i < 4; i++) {
      int p = tq + i * 16;
      #pragma unroll
      for (int j = 0; j < 4; j++) shX[(cq + j) * 68 + p] = hreg[i][j];
    }
    __syncthreads();
    for (int n = 0; n < 64; n++) {
      f32x4 cv = *reinterpret_cast<const f32x4*>(&CsT[n * 68 + t0]);
      f32x4 hv = *reinterpret_cast<const f32x4*>(&shX[n * 68 + q0]);
      Z0 += hv * cv[0];
      Z1 += hv * cv[1];
      Z2 += hv * cv[2];
      Z3 += hv * cv[3];
    }
  }
  float Dv = Dvec[h];
  f32x4 Yv[4] = {Y0, Y1, Y2, Y3};
  f32x4 Zv[4] = {Z0, Z1, Z2, Z3};
  #pragma unroll
  for (int i = 0; i < 4; i++) {
    int t = t0 + i;
    float wB = expf(Cum[t]);
    const float* xp = xbc + (row0 + t) * conv_dim + (h << 6) + q0;
    f32x4 xg = *reinterpret_cast<const f32x4*>(xp);
    f32x4 o = Yv[i] + Zv[i] * wB + xg * Dv;
    *reinterpret_cast<f32x4*>(&y[(row0 + t) * d_inner + (h << 6) + q0]) = o;
  }
}

// --- g = y*silu(z); g *= rsqrt(mean(g^2)+eps)*rms_w; emit bf16 A directly ---
template <int NJ>
__global__ __launch_bounds__(256) void gate_rms_bf16(const float* __restrict__ y,
                                                     const float* __restrict__ z,
                                                     const float* __restrict__ rmsw,
                                                     unsigned short* __restrict__ ab,
                                                     int d_inner) {
  long row = blockIdx.x;
  const float* yr = y + row * d_inner;
  const float* zr = z + row * d_inner;
  __shared__ float lds[4];
  float g[NJ];
  float ss = 0.f;
  #pragma unroll
  for (int j = 0; j < NJ; j++) {
    int c = threadIdx.x + (j << 8);
    float gv = yr[c] * siluf(zr[c]);
    g[j] = gv;
    ss += gv * gv;
  }
  float tot = block_sum(ss, lds);
  float inv = rsqrtf(tot / (float)d_inner + EPSV);
  #pragma unroll
  for (int j = 0; j < NJ; j++) {
    int c = threadIdx.x + (j << 8);
    ab[row * d_inner + c] = f2bf(g[j] * inv * rmsw[c]);
  }
}

extern "C" void kernel_launch(void* const* d_in, const int* in_sizes, int n_in,
                              void* d_out, int out_size, void* d_ws,
                              size_t ws_size, hipStream_t stream) {
  const float* x        = (const float*)d_in[0];
  const float* ln_spa_w = (const float*)d_in[1];
  const float* ln_spa_b = (const float*)d_in[2];
  const float* ln_spe_w = (const float*)d_in[3];
  const float* ln_spe_b = (const float*)d_in[4];
  const float* spa_W_in   = (const float*)d_in[5];
  const float* spa_conv_w = (const float*)d_in[6];
  const float* spa_conv_b = (const float*)d_in[7];
  const float* spa_dt_b   = (const float*)d_in[8];
  const float* spa_A_log  = (const float*)d_in[9];
  const float* spa_D      = (const float*)d_in[10];
  const float* spa_rms_w  = (const float*)d_in[11];
  const float* spa_W_out  = (const float*)d_in[12];
  const float* spe_W_in   = (const float*)d_in[13];
  const float* spe_conv_w = (const float*)d_in[14];
  const float* spe_conv_b = (const float*)d_in[15];
  const float* spe_dt_b   = (const float*)d_in[16];
  const float* spe_A_log  = (const float*)d_in[17];
  const float* spe_D      = (const float*)d_in[18];
  const float* spe_rms_w  = (const float*)d_in[19];
  const float* spe_W_out  = (const float*)d_in[20];
  float* out = (float*)d_out;

  float* ws = (float*)d_ws;
  // layout (floats) — same proven 63.9 MB budget
  float* xspa   = ws;                 // 1,048,576
  float* z      = ws + 1048576;       // 2,097,152
  float* xbcraw = ws + 3145728;       // 3,145,728 (later Sc)
  float* dtraw  = ws + 6291456;       // 32,768    (later Aprod)
  float* cv     = ws + 6324224;       // 3,145,728
  float* dtb    = ws + 9469952;       // 32,768    (also spe LN partials: 256*64*2 fl)
  float* la     = ws + 9502720;       // 32,768
  float* yb     = ws + 9535488;       // 2,097,152
  unsigned short* Abf     = (unsigned short*)(ws + 11634688);  // 1,048,576 fl
  unsigned short* Wt_spai = (unsigned short*)(ws + 12683264);  // 41,216 fl
  unsigned short* Wt_spao = (unsigned short*)(ws + 12724480);  // 16,384 fl
  unsigned short* Wt_spei = (unsigned short*)(ws + 12740864);  // 2,179,072 fl
  unsigned short* Wt_speo = (unsigned short*)(ws + 14919936);  // 1,048,576 fl

  // 1. fused prologue: spa LN (blocks 0..4095) + all weight transposes
  hipLaunchKernelGGL(ln_wt_fused, dim3(5710), dim3(256), 0, stream,
                     x, ln_spa_w, ln_spa_b, Abf,
                     spa_W_in, Wt_spai, spa_W_out, Wt_spao,
                     spe_W_in, Wt_spei, spe_W_out, Wt_speo);

  // ================= spatial mamba (L=1024, d_model=128) =================
  hipLaunchKernelGGL(gemm128_split, dim3(6, 64), dim3(256), 0, stream,
                     Abf, Wt_spai, z, xbcraw, dtraw,
                     8192, 644, 128, 256, 640);
  hipLaunchKernelGGL(conv_dtda, dim3(3200), dim3(256), 0, stream,
                     xbcraw, spa_conv_w, spa_conv_b, cv,
                     dtraw, spa_dt_b, spa_A_log, dtb, la,
                     8, 1024, 384, 4, 32768, 3072);
  // chunk states (S_15 unused downstream -> launch 15 chunks), Sc raw
  hipLaunchKernelGGL(ssd_local, dim3(480), dim3(256), 0, stream,
                     cv, dtb, la, xbcraw, dtraw, 16, 15, 4, 384, 256);
  hipLaunchKernelGGL(ssd_out, dim3(512), dim3(256), 0, stream,
                     cv, dtb, la, xbcraw, dtraw, spa_D, yb, 16, 4, 384, 256);
  hipLaunchKernelGGL((gate_rms_bf16<1>), dim3(8192), dim3(256), 0, stream,
                     yb, z, spa_rms_w, Abf, 256);
  hipLaunchKernelGGL((gemm_mfma<1>), dim3(2, 128), dim3(256), 0, stream,
                     Abf, Wt_spao, x, xspa, dtb, 8192, 128, 256);

  // ================= spectral mamba (L=128, d_model=1024) =================
  hipLaunchKernelGGL(spe_normT, dim3(2, 8, 8), dim3(256), 0, stream,
                     xspa, dtb, ln_spe_w, ln_spe_b, Abf);
  hipLaunchKernelGGL(gemm128_split, dim3(34, 8), dim3(256), 0, stream,
                     Abf, Wt_spei, z, xbcraw, dtraw,
                     1024, 4256, 1024, 2048, 4224);
  hipLaunchKernelGGL(conv_dtda, dim3(2304), dim3(256), 0, stream,
                     xbcraw, spe_conv_w, spe_conv_b, cv,
                     dtraw, spe_dt_b, spe_A_log, dtb, la,
                     8, 128, 2176, 32, 32768, 2176);
  // only chunk 0's state is needed (NC=2): hprev(c=1) folds S_0
  hipLaunchKernelGGL(ssd_local, dim3(256), dim3(256), 0, stream,
                     cv, dtb, la, xbcraw, dtraw, 2, 1, 32, 2176, 2048);
  hipLaunchKernelGGL(ssd_out, dim3(512), dim3(256), 0, stream,
                     cv, dtb, la, xbcraw, dtraw, spe_D, yb, 2, 32, 2176, 2048);
  hipLaunchKernelGGL((gate_rms_bf16<8>), dim3(1024), dim3(256), 0, stream,
                     yb, z, spe_rms_w, Abf, 2048);
  hipLaunchKernelGGL((gemm_mfma<2>), dim3(16, 16), dim3(256), 0, stream,
                     Abf, Wt_speo, xspa, out, nullptr, 1024, 1024, 2048);
}

// Round 11
// 177.537 us; speedup vs baseline: 1.2613x; 1.1210x over previous
//
#include <hip/hip_runtime.h>
#include <hip/hip_bf16.h>

#define EPSV 1e-5f

typedef __attribute__((ext_vector_type(8))) short short8v;   // 8 bf16 in 4 VGPRs
typedef __attribute__((ext_vector_type(4))) float f32x4;

__device__ inline unsigned short f2bf(float f) {
  __hip_bfloat16 h = __float2bfloat16(f);
  return *reinterpret_cast<unsigned short*>(&h);
}

__device__ inline float siluf(float x) { return x / (1.f + expf(-x)); }

// ---------------- block-wide sum (256 threads = 4 waves) ----------------
__device__ inline float block_sum(float v, float* lds) {
  #pragma unroll
  for (int o = 32; o; o >>= 1) v += __shfl_xor(v, o);
  int tid = threadIdx.x;
  if ((tid & 63) == 0) lds[tid >> 6] = v;
  __syncthreads();
  float r = lds[0] + lds[1] + lds[2] + lds[3];
  __syncthreads();
  return r;
}

// inclusive prefix sum over 64 lanes (call from wave 0 only)
__device__ inline float wave_prefix_incl(float v, int lane) {
  #pragma unroll
  for (int o = 1; o < 64; o <<= 1) {
    float u = __shfl_up(v, o);
    if (lane >= o) v += u;
  }
  return v;
}

// ------- weight transpose tile W[K][N] -> Wt[N][K] bf16 -------
__device__ inline void wtconv_tile(const float* __restrict__ W,
                                   unsigned short* __restrict__ Wt,
                                   int K, int N, int bx, int by) {
  __shared__ float tile[64][65];
  int n0 = bx * 64, k0 = by * 64;
  int tid = threadIdx.x;
  int r = tid >> 4, c4 = (tid & 15) * 4;
  #pragma unroll
  for (int i = 0; i < 4; i++) {
    int kk = r + i * 16;
    float4 v = make_float4(0.f, 0.f, 0.f, 0.f);
    if (n0 + c4 < N) v = *reinterpret_cast<const float4*>(&W[(long)(k0 + kk) * N + n0 + c4]);
    tile[kk][c4] = v.x; tile[kk][c4 + 1] = v.y; tile[kk][c4 + 2] = v.z; tile[kk][c4 + 3] = v.w;
  }
  __syncthreads();
  #pragma unroll
  for (int i = 0; i < 4; i++) {
    int nl = r + i * 16;
    if (n0 + nl < N) {
      ushort4 o;
      o.x = f2bf(tile[c4 + 0][nl]);
      o.y = f2bf(tile[c4 + 1][nl]);
      o.z = f2bf(tile[c4 + 2][nl]);
      o.w = f2bf(tile[c4 + 3][nl]);
      *reinterpret_cast<ushort4*>(&Wt[(long)(n0 + nl) * K + k0 + c4]) = o;
    }
  }
}

// ---- fused prologue: spa LN (2 rows/block, bf16 out) + all 4 weight transposes ----
__global__ __launch_bounds__(256) void ln_wt_fused(const float* __restrict__ x,
                                                   const float* __restrict__ w,
                                                   const float* __restrict__ bb,
                                                   unsigned short* __restrict__ outA,
                                                   const float* __restrict__ W0,
                                                   unsigned short* __restrict__ T0,
                                                   const float* __restrict__ W1,
                                                   unsigned short* __restrict__ T1,
                                                   const float* __restrict__ W2,
                                                   unsigned short* __restrict__ T2,
                                                   const float* __restrict__ W3,
                                                   unsigned short* __restrict__ T3) {
  int id = blockIdx.x;
  if (id < 4096) {
    int tid = threadIdx.x;
    __shared__ float lds[4];
    long row = (long)id * 2 + (tid >> 7);
    int lane = tid & 127;
    int base = (tid >> 7) << 1;
    float v = x[row * 128 + lane];
    float s = v;
    #pragma unroll
    for (int o = 32; o; o >>= 1) s += __shfl_xor(s, o);
    if ((tid & 63) == 0) lds[tid >> 6] = s;
    __syncthreads();
    float m = (lds[base] + lds[base + 1]) * (1.f / 128.f);
    float d = v - m;
    float q = d * d;
    #pragma unroll
    for (int o = 32; o; o >>= 1) q += __shfl_xor(q, o);
    __syncthreads();
    if ((tid & 63) == 0) lds[tid >> 6] = q;
    __syncthreads();
    float inv = rsqrtf((lds[base] + lds[base + 1]) * (1.f / 128.f) + EPSV);
    outA[row * 128 + lane] = f2bf(d * inv * w[lane] + bb[lane]);
  } else {
    id -= 4096;
    if (id < 22)        { int r = id;        wtconv_tile(W0, T0, 128,  644,  r % 11, r / 11); }
    else if (id < 30)   { int r = id - 22;   wtconv_tile(W1, T1, 256,  128,  r % 2,  r / 2); }
    else if (id < 1102) { int r = id - 30;   wtconv_tile(W2, T2, 1024, 4256, r % 67, r / 67); }
    else                { int r = id - 1102; wtconv_tile(W3, T3, 2048, 1024, r % 16, r / 16); }
  }
}

// ---- spe LN pass 2: finalize per-(b,ch) stats from GEMM partials,
//      normalize + transpose, emit bf16. part2: float2[(by*2+bx)*64 + cl]
__global__ __launch_bounds__(256) void spe_normT(const float* __restrict__ xspa,
                                                 const float* __restrict__ part2,
                                                 const float* __restrict__ w,
                                                 const float* __restrict__ bb,
                                                 unsigned short* __restrict__ out) {
  __shared__ float tile[128][65];
  int c0 = blockIdx.x * 64, l0 = blockIdx.y * 128, b = blockIdx.z;
  int tid = threadIdx.x;
  int rr = tid >> 4, c4 = (tid & 15) * 4;
  #pragma unroll
  for (int p = 0; p < 8; p++) {
    int l = rr + p * 16;
    f32x4 v = *reinterpret_cast<const f32x4*>(
        &xspa[((long)b * 1024 + l0 + l) * 128 + c0 + c4]);
    tile[l][c4] = v[0]; tile[l][c4 + 1] = v[1];
    tile[l][c4 + 2] = v[2]; tile[l][c4 + 3] = v[3];
  }
  __syncthreads();
  int ch = tid >> 2, lq = tid & 3;
  int gc = c0 + ch;                       // global channel 0..127
  int bx = gc >> 6, cl = gc & 63;
  float ssum = 0.f, qsum = 0.f;
  #pragma unroll
  for (int sub = 0; sub < 16; sub++) {
    int by = b * 16 + sub;
    float2 pq = *reinterpret_cast<const float2*>(&part2[(((by * 2 + bx) * 64) + cl) * 2]);
    ssum += pq.x; qsum += pq.y;
  }
  float mm = ssum * (1.f / 1024.f);
  float rstd = rsqrtf(qsum * (1.f / 1024.f) - mm * mm + EPSV);
  #pragma unroll
  for (int j = 0; j < 8; j++) {
    int qidx = lq + j * 4;
    int l = qidx * 4;
    float4 wv = *reinterpret_cast<const float4*>(&w[l0 + l]);
    float4 bv = *reinterpret_cast<const float4*>(&bb[l0 + l]);
    ushort4 o;
    o.x = f2bf((tile[l + 0][ch] - mm) * rstd * wv.x + bv.x);
    o.y = f2bf((tile[l + 1][ch] - mm) * rstd * wv.y + bv.y);
    o.z = f2bf((tile[l + 2][ch] - mm) * rstd * wv.z + bv.z);
    o.w = f2bf((tile[l + 3][ch] - mm) * rstd * wv.w + bv.w);
    *reinterpret_cast<ushort4*>(&out[((long)b * 128 + c0 + ch) * 1024 + l0 + l]) = o;
  }
}

// ------- 128x128-tile bf16 MFMA GEMM with column-split epilogue -------
__global__ __launch_bounds__(256) void gemm128_split(const unsigned short* __restrict__ A,
                                                     const unsigned short* __restrict__ Bt,
                                                     float* __restrict__ out,
                                                     float* __restrict__ o2,
                                                     float* __restrict__ o3,
                                                     int M, int N, int K,
                                                     int c1, int c2) {
  __shared__ unsigned short As[128 * 40];
  __shared__ unsigned short Bs[128 * 40];
  int tid = threadIdx.x;
  int lane = tid & 63, w = tid >> 6;
  int wr = (w >> 1) * 64, wc = (w & 1) * 64;
  int ln15 = lane & 15, kg = lane >> 4;
  int rowBase = blockIdx.y * 128, colBase = blockIdx.x * 128;
  int sr = tid >> 1, sk = (tid & 1) * 16;
  f32x4 acc[4][4] = {};
  for (int k0 = 0; k0 < K; k0 += 32) {
    {
      const unsigned short* ap = &A[(long)(rowBase + sr) * K + k0 + sk];
      short8v a0 = *reinterpret_cast<const short8v*>(ap);
      short8v a1 = *reinterpret_cast<const short8v*>(ap + 8);
      *reinterpret_cast<short8v*>(&As[sr * 40 + sk]) = a0;
      *reinterpret_cast<short8v*>(&As[sr * 40 + sk + 8]) = a1;
      int n = colBase + sr;
      short8v b0 = {0, 0, 0, 0, 0, 0, 0, 0}, b1 = b0;
      if (n < N) {
        const unsigned short* bp = &Bt[(long)n * K + k0 + sk];
        b0 = *reinterpret_cast<const short8v*>(bp);
        b1 = *reinterpret_cast<const short8v*>(bp + 8);
      }
      *reinterpret_cast<short8v*>(&Bs[sr * 40 + sk]) = b0;
      *reinterpret_cast<short8v*>(&Bs[sr * 40 + sk + 8]) = b1;
    }
    __syncthreads();
    short8v af[4], bfr[4];
    #pragma unroll
    for (int mt = 0; mt < 4; mt++)
      af[mt] = *reinterpret_cast<const short8v*>(&As[(wr + mt * 16 + ln15) * 40 + kg * 8]);
    #pragma unroll
    for (int nt = 0; nt < 4; nt++)
      bfr[nt] = *reinterpret_cast<const short8v*>(&Bs[(wc + nt * 16 + ln15) * 40 + kg * 8]);
    #pragma unroll
    for (int mt = 0; mt < 4; mt++)
      #pragma unroll
      for (int nt = 0; nt < 4; nt++)
        acc[mt][nt] = __builtin_amdgcn_mfma_f32_16x16x32_bf16(af[mt], bfr[nt], acc[mt][nt], 0, 0, 0);
    __syncthreads();
  }
  #pragma unroll
  for (int mt = 0; mt < 4; mt++)
    #pragma unroll
    for (int nt = 0; nt < 4; nt++)
      #pragma unroll
      for (int q = 0; q < 4; q++) {
        int r = rowBase + wr + mt * 16 + kg * 4 + q;
        int c = colBase + wc + nt * 16 + ln15;
        if (c < N) {
          float v = acc[mt][nt][q];
          if (c < c1) out[(long)r * c1 + c] = v;
          else if (c < c2) o2[(long)r * (c2 - c1) + (c - c1)] = v;
          else o3[(long)r * (N - c2) + (c - c2)] = v;
        }
      }
}

// ---------------- 64x64-tile bf16 MFMA GEMM (W_out epilogues) ----------------
// MODE 1: out = v + R; also emits deterministic per-block column {sum,sum^2}
// MODE 2: transposed add (spe W_out)
template <int MODE>
__global__ __launch_bounds__(256) void gemm_mfma(const unsigned short* __restrict__ A,
                                                 const unsigned short* __restrict__ Bt,
                                                 const float* __restrict__ R,
                                                 float* __restrict__ out,
                                                 float* __restrict__ part2,
                                                 int M, int N, int K) {
  __shared__ unsigned short As[64 * 40];
  __shared__ unsigned short Bs[64 * 40];
  int tid = threadIdx.x;
  int lane = tid & 63, w = tid >> 6;
  int wr = (w >> 1) * 32, wc = (w & 1) * 32;
  int ln15 = lane & 15, kg = lane >> 4;
  int rowBase = blockIdx.y * 64, colBase = blockIdx.x * 64;
  int sm = tid >> 2, skb = (tid & 3) * 8;
  f32x4 acc[2][2] = {};
  for (int k0 = 0; k0 < K; k0 += 32) {
    {
      short8v av = *reinterpret_cast<const short8v*>(&A[(long)(rowBase + sm) * K + k0 + skb]);
      *reinterpret_cast<short8v*>(&As[sm * 40 + skb]) = av;
      int n = colBase + sm;
      short8v bv = {0, 0, 0, 0, 0, 0, 0, 0};
      if (n < N) bv = *reinterpret_cast<const short8v*>(&Bt[(long)n * K + k0 + skb]);
      *reinterpret_cast<short8v*>(&Bs[sm * 40 + skb]) = bv;
    }
    __syncthreads();
    short8v af[2], bfr[2];
    #pragma unroll
    for (int mt = 0; mt < 2; mt++)
      af[mt] = *reinterpret_cast<const short8v*>(&As[(wr + mt * 16 + ln15) * 40 + kg * 8]);
    #pragma unroll
    for (int nt = 0; nt < 2; nt++)
      bfr[nt] = *reinterpret_cast<const short8v*>(&Bs[(wc + nt * 16 + ln15) * 40 + kg * 8]);
    #pragma unroll
    for (int mt = 0; mt < 2; mt++)
      #pragma unroll
      for (int nt = 0; nt < 2; nt++)
        acc[mt][nt] = __builtin_amdgcn_mfma_f32_16x16x32_bf16(af[mt], bfr[nt], acc[mt][nt], 0, 0, 0);
    __syncthreads();
  }
  if (MODE == 1) {
    float sC[2] = {0.f, 0.f}, qC[2] = {0.f, 0.f};
    #pragma unroll
    for (int mt = 0; mt < 2; mt++)
      #pragma unroll
      for (int nt = 0; nt < 2; nt++)
        #pragma unroll
        for (int q = 0; q < 4; q++) {
          int r = rowBase + wr + mt * 16 + kg * 4 + q;
          int c = colBase + wc + nt * 16 + ln15;
          float v = acc[mt][nt][q] + R[(long)r * N + c];
          out[(long)r * N + c] = v;
          sC[nt] += v;
          qC[nt] += v * v;
        }
    __shared__ float redS[4][32], redQ[4][32];
    #pragma unroll
    for (int nt = 0; nt < 2; nt++) {
      sC[nt] += __shfl_xor(sC[nt], 16);
      sC[nt] += __shfl_xor(sC[nt], 32);
      qC[nt] += __shfl_xor(qC[nt], 16);
      qC[nt] += __shfl_xor(qC[nt], 32);
    }
    if (lane < 16) {
      redS[w][ln15] = sC[0];       redQ[w][ln15] = qC[0];
      redS[w][16 + ln15] = sC[1];  redQ[w][16 + ln15] = qC[1];
    }
    __syncthreads();
    if (tid < 64) {
      int c = tid;
      int grp = c >> 5, lo = c & 31;
      float ss = redS[grp][lo] + redS[grp + 2][lo];
      float qq = redQ[grp][lo] + redQ[grp + 2][lo];
      long slot = ((long)(blockIdx.y * 2 + blockIdx.x) * 64 + c) * 2;
      part2[slot] = ss;
      part2[slot + 1] = qq;
    }
  } else {
    #pragma unroll
    for (int mt = 0; mt < 2; mt++)
      #pragma unroll
      for (int nt = 0; nt < 2; nt++)
        #pragma unroll
        for (int q = 0; q < 4; q++) {
          int r = rowBase + wr + mt * 16 + kg * 4 + q;
          int c = colBase + wc + nt * 16 + ln15;
          if (c < N) {
            int bb = r >> 7, ch = r & 127;
            out[(long)bb * 131072 + (long)c * 128 + ch] =
                acc[mt][nt][q] + R[((long)bb * 1024 + c) * 128 + ch];
          }
        }
  }
}

// ---- fused: causal depthwise conv (float4 channels) + bias + SiLU | dt/la ----
__global__ __launch_bounds__(256) void conv_dtda(const float* __restrict__ zx,
                                                 const float* __restrict__ cw,
                                                 const float* __restrict__ cb,
                                                 float* __restrict__ cout,
                                                 const float* __restrict__ raw,
                                                 const float* __restrict__ dtbias,
                                                 const float* __restrict__ alog,
                                                 float* __restrict__ dt,
                                                 float* __restrict__ la,
                                                 int Bb, int L, int conv_dim,
                                                 int H, int rowsH, int convBlocks) {
  int tid = threadIdx.x;
  if ((int)blockIdx.x < convBlocks) {
    long idx4 = (long)blockIdx.x * 256 + tid;
    int nch4 = conv_dim >> 2;
    long total4 = (long)Bb * L * nch4;
    if (idx4 >= total4) return;
    int ch = (int)(idx4 % nch4) << 2;
    long rt = idx4 / nch4;
    int t = (int)(rt % L);
    int b = (int)(rt / L);
    f32x4 acc = *reinterpret_cast<const f32x4*>(&cb[ch]);
    #pragma unroll
    for (int k = 0; k < 4; k++) {
      int tt = t + k - 3;
      if (tt >= 0) {
        f32x4 wv = *reinterpret_cast<const f32x4*>(&cw[k * conv_dim + ch]);
        f32x4 zv = *reinterpret_cast<const f32x4*>(
            &zx[((long)b * L + tt) * conv_dim + ch]);
        acc += wv * zv;
      }
    }
    f32x4 o;
    o[0] = siluf(acc[0]); o[1] = siluf(acc[1]);
    o[2] = siluf(acc[2]); o[3] = siluf(acc[3]);
    *reinterpret_cast<f32x4*>(&cout[rt * conv_dim + ch]) = o;
  } else {
    int idx = ((int)blockIdx.x - convBlocks) * 256 + tid;
    if (idx >= rowsH) return;
    int h = idx % H;
    float v = raw[idx] + dtbias[h];
    float sp = (v > 20.f) ? v : log1pf(expf(v));
    dt[idx] = sp;
    la[idx] = -expf(alog[h]) * sp;
  }
}

// ===================== chunked SSD (T=64 per chunk), MFMA =====================
// K1: S[p,n] = sum_t (Ws[t]*X[t,p]) * B[t,n] via mfma: A=XpT[p][t], B=BT[n][t]
__global__ __launch_bounds__(256) void ssd_local(const float* __restrict__ xbc,
                                                 const float* __restrict__ dtv,
                                                 const float* __restrict__ la,
                                                 float* __restrict__ Sc,
                                                 float* __restrict__ Aprod,
                                                 int NC, int nc_launch, int H,
                                                 int conv_dim, int d_inner) {
  int blk = blockIdx.x;
  int c = blk % nc_launch, bh = blk / nc_launch;
  int h = bh % H, b = bh / H;
  int tid = threadIdx.x;
  long row0 = ((long)(b * NC + c)) * 64;
  __shared__ unsigned short XpT[64 * 72];   // [p][t] = bf16(Ws[t]*X[t][p])
  __shared__ unsigned short BT[64 * 72];    // [n][t]
  __shared__ float Ws[64];
  int tq = tid >> 4, cq = (tid & 15) << 2;
  f32x4 xr[4], br[4];
  #pragma unroll
  for (int i = 0; i < 4; i++) {
    int t = tq + i * 16;
    const float* rp = xbc + (row0 + t) * conv_dim;
    xr[i] = *reinterpret_cast<const f32x4*>(rp + (h << 6) + cq);
    br[i] = *reinterpret_cast<const f32x4*>(rp + d_inner + cq);
  }
  if (tid < 64) {
    long r = (row0 + tid) * H + h;
    float cum = wave_prefix_incl(la[r], tid);
    float cT = __shfl(cum, 63);
    Ws[tid] = expf(cT - cum) * dtv[r];
    if (tid == 63) Aprod[(long)bh * NC + c] = expf(cT);
  }
  __syncthreads();
  #pragma unroll
  for (int i = 0; i < 4; i++) {
    int t = tq + i * 16;
    float wv = Ws[t];
    #pragma unroll
    for (int j = 0; j < 4; j++) {
      XpT[(cq + j) * 72 + t] = f2bf(wv * xr[i][j]);
      BT[(cq + j) * 72 + t] = f2bf(br[i][j]);
    }
  }
  __syncthreads();
  int lane = tid & 63, wv2 = tid >> 6;
  int wr = (wv2 >> 1) * 32, wc = (wv2 & 1) * 32;
  int ln15 = lane & 15, kg = lane >> 4;
  f32x4 acc[2][2] = {};
  #pragma unroll
  for (int ks = 0; ks < 2; ks++) {
    short8v af[2], bq[2];
    #pragma unroll
    for (int mt = 0; mt < 2; mt++)
      af[mt] = *reinterpret_cast<const short8v*>(&XpT[(wr + mt * 16 + ln15) * 72 + ks * 32 + kg * 8]);
    #pragma unroll
    for (int nt = 0; nt < 2; nt++)
      bq[nt] = *reinterpret_cast<const short8v*>(&BT[(wc + nt * 16 + ln15) * 72 + ks * 32 + kg * 8]);
    #pragma unroll
    for (int mt = 0; mt < 2; mt++)
      #pragma unroll
      for (int nt = 0; nt < 2; nt++)
        acc[mt][nt] = __builtin_amdgcn_mfma_f32_16x16x32_bf16(af[mt], bq[nt], acc[mt][nt], 0, 0, 0);
  }
  float* base = Sc + ((long)bh * NC + c) * 4096;
  #pragma unroll
  for (int mt = 0; mt < 2; mt++)
    #pragma unroll
    for (int nt = 0; nt < 2; nt++)
      #pragma unroll
      for (int q = 0; q < 4; q++) {
        int p = wr + mt * 16 + kg * 4 + q;
        int n = wc + nt * 16 + ln15;
        base[p * 64 + n] = acc[mt][nt][q];
      }
}

// K3: MFMA phases: G=C·B^T (masked) ; Y=Gm·X ; Z=C·h^T ; y = Y + e^cum·Z + D·x
__global__ __launch_bounds__(256) void ssd_out(const float* __restrict__ xbc,
                                               const float* __restrict__ dtv,
                                               const float* __restrict__ la,
                                               const float* __restrict__ Sc,
                                               const float* __restrict__ Aprod,
                                               const float* __restrict__ Dvec,
                                               float* __restrict__ y,
                                               int NC, int H, int conv_dim,
                                               int d_inner) {
  int blk = blockIdx.x;
  int c = blk % NC, bh = blk / NC;
  int h = bh % H, b = bh / H;
  int tid = threadIdx.x;
  long row0 = ((long)(b * NC + c)) * 64;
  __shared__ unsigned short Cb[64 * 72];   // C[t][n]
  __shared__ unsigned short Bb[64 * 72];   // B[s][n]  -> after phase A: Gm[t][s]
  __shared__ unsigned short XT[64 * 72];   // X^T[p][s]
  __shared__ unsigned short hb[64 * 72];   // hprev[p][n]
  __shared__ float Cum[64], Dt[64];
  int tq = tid >> 4, cq = (tid & 15) << 2;
  #pragma unroll
  for (int i = 0; i < 4; i++) {
    int t = tq + i * 16;
    const float* rp = xbc + (row0 + t) * conv_dim;
    f32x4 cvv = *reinterpret_cast<const f32x4*>(rp + d_inner + 64 + cq);
    f32x4 bvv = *reinterpret_cast<const f32x4*>(rp + d_inner + cq);
    f32x4 xvv = *reinterpret_cast<const f32x4*>(rp + (h << 6) + cq);
    ushort4 co, bo;
    co.x = f2bf(cvv[0]); co.y = f2bf(cvv[1]); co.z = f2bf(cvv[2]); co.w = f2bf(cvv[3]);
    bo.x = f2bf(bvv[0]); bo.y = f2bf(bvv[1]); bo.z = f2bf(bvv[2]); bo.w = f2bf(bvv[3]);
    *reinterpret_cast<ushort4*>(&Cb[t * 72 + cq]) = co;
    *reinterpret_cast<ushort4*>(&Bb[t * 72 + cq]) = bo;
    #pragma unroll
    for (int j = 0; j < 4; j++) XT[(cq + j) * 72 + t] = f2bf(xvv[j]);
  }
  // carry fold in fp32 (bit-identical order), then stage h[p][n] as bf16
  if (c > 0) {
    f32x4 hreg[4] = {};
    const float* ap = Aprod + (long)bh * NC;
    for (int j = 0; j < c; j++) {
      const float* sb = Sc + ((long)bh * NC + j) * 4096;
      float a = ap[j];
      #pragma unroll
      for (int i = 0; i < 4; i++) {
        int p = tq + i * 16;
        f32x4 sv = *reinterpret_cast<const f32x4*>(&sb[p * 64 + cq]);
        hreg[i] = hreg[i] * a + sv;
      }
    }
    #pragma unroll
    for (int i = 0; i < 4; i++) {
      int p = tq + i * 16;
      ushort4 ho;
      ho.x = f2bf(hreg[i][0]); ho.y = f2bf(hreg[i][1]);
      ho.z = f2bf(hreg[i][2]); ho.w = f2bf(hreg[i][3]);
      *reinterpret_cast<ushort4*>(&hb[p * 72 + cq]) = ho;
    }
  }
  if (tid < 64) {
    long r = (row0 + tid) * H + h;
    Cum[tid] = wave_prefix_incl(la[r], tid);
    Dt[tid] = dtv[r];
  }
  __syncthreads();
  int lane = tid & 63, wv2 = tid >> 6;
  int wr = (wv2 >> 1) * 32, wc = (wv2 & 1) * 32;
  int ln15 = lane & 15, kg = lane >> 4;
  // ---- Phase A: G[t][s] = sum_n C[t,n] B[s,n]
  f32x4 accA[2][2] = {};
  #pragma unroll
  for (int ks = 0; ks < 2; ks++) {
    short8v af[2], bq[2];
    #pragma unroll
    for (int mt = 0; mt < 2; mt++)
      af[mt] = *reinterpret_cast<const short8v*>(&Cb[(wr + mt * 16 + ln15) * 72 + ks * 32 + kg * 8]);
    #pragma unroll
    for (int nt = 0; nt < 2; nt++)
      bq[nt] = *reinterpret_cast<const short8v*>(&Bb[(wc + nt * 16 + ln15) * 72 + ks * 32 + kg * 8]);
    #pragma unroll
    for (int mt = 0; mt < 2; mt++)
      #pragma unroll
      for (int nt = 0; nt < 2; nt++)
        accA[mt][nt] = __builtin_amdgcn_mfma_f32_16x16x32_bf16(af[mt], bq[nt], accA[mt][nt], 0, 0, 0);
  }
  // mask + weight in registers
  unsigned short gmb[2][2][4];
  #pragma unroll
  for (int mt = 0; mt < 2; mt++)
    #pragma unroll
    for (int nt = 0; nt < 2; nt++)
      #pragma unroll
      for (int q = 0; q < 4; q++) {
        int t = wr + mt * 16 + kg * 4 + q;
        int s = wc + nt * 16 + ln15;
        float v = (s <= t) ? accA[mt][nt][q] * expf(Cum[t] - Cum[s]) * Dt[s] : 0.f;
        gmb[mt][nt][q] = f2bf(v);
      }
  __syncthreads();   // all waves done reading Bb
  #pragma unroll
  for (int mt = 0; mt < 2; mt++)
    #pragma unroll
    for (int nt = 0; nt < 2; nt++)
      #pragma unroll
      for (int q = 0; q < 4; q++)
        Bb[(wr + mt * 16 + kg * 4 + q) * 72 + wc + nt * 16 + ln15] = gmb[mt][nt][q];
  __syncthreads();
  // ---- Phase B: Y[t][p] = sum_s Gm[t,s] X[s,p] ; Phase C: Z[t][p] = sum_n C[t,n] h[p,n]
  f32x4 accY[2][2] = {}, accZ[2][2] = {};
  #pragma unroll
  for (int ks = 0; ks < 2; ks++) {
    short8v af[2], bq[2];
    #pragma unroll
    for (int mt = 0; mt < 2; mt++)
      af[mt] = *reinterpret_cast<const short8v*>(&Bb[(wr + mt * 16 + ln15) * 72 + ks * 32 + kg * 8]);
    #pragma unroll
    for (int nt = 0; nt < 2; nt++)
      bq[nt] = *reinterpret_cast<const short8v*>(&XT[(wc + nt * 16 + ln15) * 72 + ks * 32 + kg * 8]);
    #pragma unroll
    for (int mt = 0; mt < 2; mt++)
      #pragma unroll
      for (int nt = 0; nt < 2; nt++)
        accY[mt][nt] = __builtin_amdgcn_mfma_f32_16x16x32_bf16(af[mt], bq[nt], accY[mt][nt], 0, 0, 0);
  }
  if (c > 0) {
    #pragma unroll
    for (int ks = 0; ks < 2; ks++) {
      short8v af[2], bq[2];
      #pragma unroll
      for (int mt = 0; mt < 2; mt++)
        af[mt] = *reinterpret_cast<const short8v*>(&Cb[(wr + mt * 16 + ln15) * 72 + ks * 32 + kg * 8]);
      #pragma unroll
      for (int nt = 0; nt < 2; nt++)
        bq[nt] = *reinterpret_cast<const short8v*>(&hb[(wc + nt * 16 + ln15) * 72 + ks * 32 + kg * 8]);
      #pragma unroll
      for (int mt = 0; mt < 2; mt++)
        #pragma unroll
        for (int nt = 0; nt < 2; nt++)
          accZ[mt][nt] = __builtin_amdgcn_mfma_f32_16x16x32_bf16(af[mt], bq[nt], accZ[mt][nt], 0, 0, 0);
    }
  }
  float Dv = Dvec[h];
  #pragma unroll
  for (int mt = 0; mt < 2; mt++)
    #pragma unroll
    for (int q = 0; q < 4; q++) {
      int t = wr + mt * 16 + kg * 4 + q;
      float wB = expf(Cum[t]);
      const float* xp = xbc + (row0 + t) * conv_dim + (h << 6);
      float* yp = y + (row0 + t) * d_inner + (h << 6);
      #pragma unroll
      for (int nt = 0; nt < 2; nt++) {
        int p = wc + nt * 16 + ln15;
        yp[p] = accY[mt][nt][q] + accZ[mt][nt][q] * wB + xp[p] * Dv;
      }
    }
}

// --- g = y*silu(z); g *= rsqrt(mean(g^2)+eps)*rms_w; emit bf16 A directly ---
template <int NJ>
__global__ __launch_bounds__(256) void gate_rms_bf16(const float* __restrict__ y,
                                                     const float* __restrict__ z,
                                                     const float* __restrict__ rmsw,
                                                     unsigned short* __restrict__ ab,
                                                     int d_inner) {
  long row = blockIdx.x;
  const float* yr = y + row * d_inner;
  const float* zr = z + row * d_inner;
  __shared__ float lds[4];
  float g[NJ];
  float ss = 0.f;
  #pragma unroll
  for (int j = 0; j < NJ; j++) {
    int c = threadIdx.x + (j << 8);
    float gv = yr[c] * siluf(zr[c]);
    g[j] = gv;
    ss += gv * gv;
  }
  float tot = block_sum(ss, lds);
  float inv = rsqrtf(tot / (float)d_inner + EPSV);
  #pragma unroll
  for (int j = 0; j < NJ; j++) {
    int c = threadIdx.x + (j << 8);
    ab[row * d_inner + c] = f2bf(g[j] * inv * rmsw[c]);
  }
}

extern "C" void kernel_launch(void* const* d_in, const int* in_sizes, int n_in,
                              void* d_out, int out_size, void* d_ws,
                              size_t ws_size, hipStream_t stream) {
  const float* x        = (const float*)d_in[0];
  const float* ln_spa_w = (const float*)d_in[1];
  const float* ln_spa_b = (const float*)d_in[2];
  const float* ln_spe_w = (const float*)d_in[3];
  const float* ln_spe_b = (const float*)d_in[4];
  const float* spa_W_in   = (const float*)d_in[5];
  const float* spa_conv_w = (const float*)d_in[6];
  const float* spa_conv_b = (const float*)d_in[7];
  const float* spa_dt_b   = (const float*)d_in[8];
  const float* spa_A_log  = (const float*)d_in[9];
  const float* spa_D      = (const float*)d_in[10];
  const float* spa_rms_w  = (const float*)d_in[11];
  const float* spa_W_out  = (const float*)d_in[12];
  const float* spe_W_in   = (const float*)d_in[13];
  const float* spe_conv_w = (const float*)d_in[14];
  const float* spe_conv_b = (const float*)d_in[15];
  const float* spe_dt_b   = (const float*)d_in[16];
  const float* spe_A_log  = (const float*)d_in[17];
  const float* spe_D      = (const float*)d_in[18];
  const float* spe_rms_w  = (const float*)d_in[19];
  const float* spe_W_out  = (const float*)d_in[20];
  float* out = (float*)d_out;

  float* ws = (float*)d_ws;
  // layout (floats) — same proven 63.9 MB budget
  float* xspa   = ws;                 // 1,048,576
  float* z      = ws + 1048576;       // 2,097,152
  float* xbcraw = ws + 3145728;       // 3,145,728 (later Sc)
  float* dtraw  = ws + 6291456;       // 32,768    (later Aprod)
  float* cv     = ws + 6324224;       // 3,145,728
  float* dtb    = ws + 9469952;       // 32,768    (also spe LN partials)
  float* la     = ws + 9502720;       // 32,768
  float* yb     = ws + 9535488;       // 2,097,152
  unsigned short* Abf     = (unsigned short*)(ws + 11634688);  // 1,048,576 fl
  unsigned short* Wt_spai = (unsigned short*)(ws + 12683264);  // 41,216 fl
  unsigned short* Wt_spao = (unsigned short*)(ws + 12724480);  // 16,384 fl
  unsigned short* Wt_spei = (unsigned short*)(ws + 12740864);  // 2,179,072 fl
  unsigned short* Wt_speo = (unsigned short*)(ws + 14919936);  // 1,048,576 fl

  // 1. fused prologue: spa LN (blocks 0..4095) + all weight transposes
  hipLaunchKernelGGL(ln_wt_fused, dim3(5710), dim3(256), 0, stream,
                     x, ln_spa_w, ln_spa_b, Abf,
                     spa_W_in, Wt_spai, spa_W_out, Wt_spao,
                     spe_W_in, Wt_spei, spe_W_out, Wt_speo);

  // ================= spatial mamba (L=1024, d_model=128) =================
  hipLaunchKernelGGL(gemm128_split, dim3(6, 64), dim3(256), 0, stream,
                     Abf, Wt_spai, z, xbcraw, dtraw,
                     8192, 644, 128, 256, 640);
  hipLaunchKernelGGL(conv_dtda, dim3(3200), dim3(256), 0, stream,
                     xbcraw, spa_conv_w, spa_conv_b, cv,
                     dtraw, spa_dt_b, spa_A_log, dtb, la,
                     8, 1024, 384, 4, 32768, 3072);
  hipLaunchKernelGGL(ssd_local, dim3(480), dim3(256), 0, stream,
                     cv, dtb, la, xbcraw, dtraw, 16, 15, 4, 384, 256);
  hipLaunchKernelGGL(ssd_out, dim3(512), dim3(256), 0, stream,
                     cv, dtb, la, xbcraw, dtraw, spa_D, yb, 16, 4, 384, 256);
  hipLaunchKernelGGL((gate_rms_bf16<1>), dim3(8192), dim3(256), 0, stream,
                     yb, z, spa_rms_w, Abf, 256);
  hipLaunchKernelGGL((gemm_mfma<1>), dim3(2, 128), dim3(256), 0, stream,
                     Abf, Wt_spao, x, xspa, dtb, 8192, 128, 256);

  // ================= spectral mamba (L=128, d_model=1024) =================
  hipLaunchKernelGGL(spe_normT, dim3(2, 8, 8), dim3(256), 0, stream,
                     xspa, dtb, ln_spe_w, ln_spe_b, Abf);
  hipLaunchKernelGGL(gemm128_split, dim3(34, 8), dim3(256), 0, stream,
                     Abf, Wt_spei, z, xbcraw, dtraw,
                     1024, 4256, 1024, 2048, 4224);
  hipLaunchKernelGGL(conv_dtda, dim3(2304), dim3(256), 0, stream,
                     xbcraw, spe_conv_w, spe_conv_b, cv,
                     dtraw, spe_dt_b, spe_A_log, dtb, la,
                     8, 128, 2176, 32, 32768, 2176);
  hipLaunchKernelGGL(ssd_local, dim3(256), dim3(256), 0, stream,
                     cv, dtb, la, xbcraw, dtraw, 2, 1, 32, 2176, 2048);
  hipLaunchKernelGGL(ssd_out, dim3(512), dim3(256), 0, stream,
                     cv, dtb, la, xbcraw, dtraw, spe_D, yb, 2, 32, 2176, 2048);
  hipLaunchKernelGGL((gate_rms_bf16<8>), dim3(1024), dim3(256), 0, stream,
                     yb, z, spe_rms_w, Abf, 2048);
  hipLaunchKernelGGL((gemm_mfma<2>), dim3(16, 16), dim3(256), 0, stream,
                     Abf, Wt_speo, xspa, out, nullptr, 1024, 1024, 2048);
}

// Round 12
// 173.678 us; speedup vs baseline: 1.2893x; 1.0222x over previous
//
#include <hip/hip_runtime.h>
#include <hip/hip_bf16.h>

#define EPSV 1e-5f

typedef __attribute__((ext_vector_type(8))) short short8v;   // 8 bf16 in 4 VGPRs
typedef __attribute__((ext_vector_type(4))) float f32x4;

__device__ inline unsigned short f2bf(float f) {
  __hip_bfloat16 h = __float2bfloat16(f);
  return *reinterpret_cast<unsigned short*>(&h);
}

__device__ inline float bf2f(unsigned short u) {
  return __uint_as_float(((unsigned int)u) << 16);
}

__device__ inline float siluf(float x) { return x / (1.f + expf(-x)); }

// direct global->LDS 16B async copy (lane-linear dest: base + lane*16)
__device__ inline void gload_lds16(const void* g, void* l) {
  __builtin_amdgcn_global_load_lds(
      (const __attribute__((address_space(1))) void*)g,
      (__attribute__((address_space(3))) void*)l, 16, 0, 0);
}

// ---------------- block-wide sum (256 threads = 4 waves) ----------------
__device__ inline float block_sum(float v, float* lds) {
  #pragma unroll
  for (int o = 32; o; o >>= 1) v += __shfl_xor(v, o);
  int tid = threadIdx.x;
  if ((tid & 63) == 0) lds[tid >> 6] = v;
  __syncthreads();
  float r = lds[0] + lds[1] + lds[2] + lds[3];
  __syncthreads();
  return r;
}

// inclusive prefix sum over 64 lanes (call from wave 0 only)
__device__ inline float wave_prefix_incl(float v, int lane) {
  #pragma unroll
  for (int o = 1; o < 64; o <<= 1) {
    float u = __shfl_up(v, o);
    if (lane >= o) v += u;
  }
  return v;
}

// ------- weight transpose tile W[K][N] -> Wt[N][K] bf16 -------
__device__ inline void wtconv_tile(const float* __restrict__ W,
                                   unsigned short* __restrict__ Wt,
                                   int K, int N, int bx, int by) {
  __shared__ float tile[64][65];
  int n0 = bx * 64, k0 = by * 64;
  int tid = threadIdx.x;
  int r = tid >> 4, c4 = (tid & 15) * 4;
  #pragma unroll
  for (int i = 0; i < 4; i++) {
    int kk = r + i * 16;
    float4 v = make_float4(0.f, 0.f, 0.f, 0.f);
    if (n0 + c4 < N) v = *reinterpret_cast<const float4*>(&W[(long)(k0 + kk) * N + n0 + c4]);
    tile[kk][c4] = v.x; tile[kk][c4 + 1] = v.y; tile[kk][c4 + 2] = v.z; tile[kk][c4 + 3] = v.w;
  }
  __syncthreads();
  #pragma unroll
  for (int i = 0; i < 4; i++) {
    int nl = r + i * 16;
    if (n0 + nl < N) {
      ushort4 o;
      o.x = f2bf(tile[c4 + 0][nl]);
      o.y = f2bf(tile[c4 + 1][nl]);
      o.z = f2bf(tile[c4 + 2][nl]);
      o.w = f2bf(tile[c4 + 3][nl]);
      *reinterpret_cast<ushort4*>(&Wt[(long)(n0 + nl) * K + k0 + c4]) = o;
    }
  }
}

// ---- fused prologue: spa LN (2 rows/block, bf16 out) + all 4 weight transposes ----
__global__ __launch_bounds__(256) void ln_wt_fused(const float* __restrict__ x,
                                                   const float* __restrict__ w,
                                                   const float* __restrict__ bb,
                                                   unsigned short* __restrict__ outA,
                                                   const float* __restrict__ W0,
                                                   unsigned short* __restrict__ T0,
                                                   const float* __restrict__ W1,
                                                   unsigned short* __restrict__ T1,
                                                   const float* __restrict__ W2,
                                                   unsigned short* __restrict__ T2,
                                                   const float* __restrict__ W3,
                                                   unsigned short* __restrict__ T3) {
  int id = blockIdx.x;
  if (id < 4096) {
    int tid = threadIdx.x;
    __shared__ float lds[4];
    long row = (long)id * 2 + (tid >> 7);
    int lane = tid & 127;
    int base = (tid >> 7) << 1;
    float v = x[row * 128 + lane];
    float s = v;
    #pragma unroll
    for (int o = 32; o; o >>= 1) s += __shfl_xor(s, o);
    if ((tid & 63) == 0) lds[tid >> 6] = s;
    __syncthreads();
    float m = (lds[base] + lds[base + 1]) * (1.f / 128.f);
    float d = v - m;
    float q = d * d;
    #pragma unroll
    for (int o = 32; o; o >>= 1) q += __shfl_xor(q, o);
    __syncthreads();
    if ((tid & 63) == 0) lds[tid >> 6] = q;
    __syncthreads();
    float inv = rsqrtf((lds[base] + lds[base + 1]) * (1.f / 128.f) + EPSV);
    outA[row * 128 + lane] = f2bf(d * inv * w[lane] + bb[lane]);
  } else {
    id -= 4096;
    if (id < 22)        { int r = id;        wtconv_tile(W0, T0, 128,  644,  r % 11, r / 11); }
    else if (id < 30)   { int r = id - 22;   wtconv_tile(W1, T1, 256,  128,  r % 2,  r / 2); }
    else if (id < 1102) { int r = id - 30;   wtconv_tile(W2, T2, 1024, 4256, r % 67, r / 67); }
    else                { int r = id - 1102; wtconv_tile(W3, T3, 2048, 1024, r % 16, r / 16); }
  }
}

// ---- spe LN pass 2: finalize per-(b,ch) stats from GEMM partials,
//      normalize + transpose, emit bf16. part2: float2[(by*2+bx)*64 + cl]
__global__ __launch_bounds__(256) void spe_normT(const float* __restrict__ xspa,
                                                 const float* __restrict__ part2,
                                                 const float* __restrict__ w,
                                                 const float* __restrict__ bb,
                                                 unsigned short* __restrict__ out) {
  __shared__ float tile[128][65];
  int c0 = blockIdx.x * 64, l0 = blockIdx.y * 128, b = blockIdx.z;
  int tid = threadIdx.x;
  int rr = tid >> 4, c4 = (tid & 15) * 4;
  #pragma unroll
  for (int p = 0; p < 8; p++) {
    int l = rr + p * 16;
    f32x4 v = *reinterpret_cast<const f32x4*>(
        &xspa[((long)b * 1024 + l0 + l) * 128 + c0 + c4]);
    tile[l][c4] = v[0]; tile[l][c4 + 1] = v[1];
    tile[l][c4 + 2] = v[2]; tile[l][c4 + 3] = v[3];
  }
  __syncthreads();
  int ch = tid >> 2, lq = tid & 3;
  int gc = c0 + ch;
  int bx = gc >> 6, cl = gc & 63;
  float ssum = 0.f, qsum = 0.f;
  #pragma unroll
  for (int sub = 0; sub < 16; sub++) {
    int by = b * 16 + sub;
    float2 pq = *reinterpret_cast<const float2*>(&part2[(((by * 2 + bx) * 64) + cl) * 2]);
    ssum += pq.x; qsum += pq.y;
  }
  float mm = ssum * (1.f / 1024.f);
  float rstd = rsqrtf(qsum * (1.f / 1024.f) - mm * mm + EPSV);
  #pragma unroll
  for (int j = 0; j < 8; j++) {
    int qidx = lq + j * 4;
    int l = qidx * 4;
    float4 wv = *reinterpret_cast<const float4*>(&w[l0 + l]);
    float4 bv = *reinterpret_cast<const float4*>(&bb[l0 + l]);
    ushort4 o;
    o.x = f2bf((tile[l + 0][ch] - mm) * rstd * wv.x + bv.x);
    o.y = f2bf((tile[l + 1][ch] - mm) * rstd * wv.y + bv.y);
    o.z = f2bf((tile[l + 2][ch] - mm) * rstd * wv.z + bv.z);
    o.w = f2bf((tile[l + 3][ch] - mm) * rstd * wv.w + bv.w);
    *reinterpret_cast<ushort4*>(&out[((long)b * 128 + c0 + ch) * 1024 + l0 + l]) = o;
  }
}

// ------- 128x128-tile bf16 MFMA GEMM, global_load_lds staging (m97-style) -------
// column-split epilogue: c<c1 -> zout (bf16, ld c1); c<c2 -> o2 (f32); else o3 (f32)
__global__ __launch_bounds__(256) void gemm128_split(const unsigned short* __restrict__ A,
                                                     const unsigned short* __restrict__ Bt,
                                                     unsigned short* __restrict__ zout,
                                                     float* __restrict__ o2,
                                                     float* __restrict__ o3,
                                                     int M, int N, int K,
                                                     int c1, int c2) {
  __shared__ unsigned short As[128 * 32];   // linear, no pad (global_load_lds dest)
  __shared__ unsigned short Bs[128 * 32];
  int tid = threadIdx.x;
  int lane = tid & 63, w = tid >> 6;
  int wr = (w >> 1) * 64, wc = (w & 1) * 64;
  int ln15 = lane & 15, kg = lane >> 4;
  int rowBase = blockIdx.y * 128, colBase = blockIdx.x * 128;
  // staging: wave w covers rows w*32 .. w*32+31 of each tile, 2 issues of 16 rows
  int srow = w * 32 + (lane >> 2);
  int scol = (lane & 3) * 8;
  f32x4 acc[4][4] = {};
  for (int k0 = 0; k0 < K; k0 += 32) {
    gload_lds16(&A[(long)(rowBase + srow) * K + k0 + scol], &As[(w * 32) * 32]);
    gload_lds16(&A[(long)(rowBase + srow + 16) * K + k0 + scol], &As[(w * 32 + 16) * 32]);
    gload_lds16(&Bt[(long)(colBase + srow) * K + k0 + scol], &Bs[(w * 32) * 32]);
    gload_lds16(&Bt[(long)(colBase + srow + 16) * K + k0 + scol], &Bs[(w * 32 + 16) * 32]);
    __syncthreads();
    short8v af[4], bfr[4];
    #pragma unroll
    for (int mt = 0; mt < 4; mt++)
      af[mt] = *reinterpret_cast<const short8v*>(&As[(wr + mt * 16 + ln15) * 32 + kg * 8]);
    #pragma unroll
    for (int nt = 0; nt < 4; nt++)
      bfr[nt] = *reinterpret_cast<const short8v*>(&Bs[(wc + nt * 16 + ln15) * 32 + kg * 8]);
    #pragma unroll
    for (int mt = 0; mt < 4; mt++)
      #pragma unroll
      for (int nt = 0; nt < 4; nt++)
        acc[mt][nt] = __builtin_amdgcn_mfma_f32_16x16x32_bf16(af[mt], bfr[nt], acc[mt][nt], 0, 0, 0);
    __syncthreads();
  }
  #pragma unroll
  for (int mt = 0; mt < 4; mt++)
    #pragma unroll
    for (int nt = 0; nt < 4; nt++)
      #pragma unroll
      for (int q = 0; q < 4; q++) {
        int r = rowBase + wr + mt * 16 + kg * 4 + q;
        int c = colBase + wc + nt * 16 + ln15;
        if (c < N) {
          float v = acc[mt][nt][q];
          if (c < c1) zout[(long)r * c1 + c] = f2bf(v);
          else if (c < c2) o2[(long)r * (c2 - c1) + (c - c1)] = v;
          else o3[(long)r * (N - c2) + (c - c2)] = v;
        }
      }
}

// ---------------- 64x64-tile bf16 MFMA GEMM (W_out epilogues) ----------------
// MODE 1: out = v + R; also emits deterministic per-block column {sum,sum^2}
// MODE 2: transposed add (spe W_out)
template <int MODE>
__global__ __launch_bounds__(256) void gemm_mfma(const unsigned short* __restrict__ A,
                                                 const unsigned short* __restrict__ Bt,
                                                 const float* __restrict__ R,
                                                 float* __restrict__ out,
                                                 float* __restrict__ part2,
                                                 int M, int N, int K) {
  __shared__ unsigned short As[64 * 40];
  __shared__ unsigned short Bs[64 * 40];
  int tid = threadIdx.x;
  int lane = tid & 63, w = tid >> 6;
  int wr = (w >> 1) * 32, wc = (w & 1) * 32;
  int ln15 = lane & 15, kg = lane >> 4;
  int rowBase = blockIdx.y * 64, colBase = blockIdx.x * 64;
  int sm = tid >> 2, skb = (tid & 3) * 8;
  f32x4 acc[2][2] = {};
  for (int k0 = 0; k0 < K; k0 += 32) {
    {
      short8v av = *reinterpret_cast<const short8v*>(&A[(long)(rowBase + sm) * K + k0 + skb]);
      *reinterpret_cast<short8v*>(&As[sm * 40 + skb]) = av;
      int n = colBase + sm;
      short8v bv = {0, 0, 0, 0, 0, 0, 0, 0};
      if (n < N) bv = *reinterpret_cast<const short8v*>(&Bt[(long)n * K + k0 + skb]);
      *reinterpret_cast<short8v*>(&Bs[sm * 40 + skb]) = bv;
    }
    __syncthreads();
    short8v af[2], bfr[2];
    #pragma unroll
    for (int mt = 0; mt < 2; mt++)
      af[mt] = *reinterpret_cast<const short8v*>(&As[(wr + mt * 16 + ln15) * 40 + kg * 8]);
    #pragma unroll
    for (int nt = 0; nt < 2; nt++)
      bfr[nt] = *reinterpret_cast<const short8v*>(&Bs[(wc + nt * 16 + ln15) * 40 + kg * 8]);
    #pragma unroll
    for (int mt = 0; mt < 2; mt++)
      #pragma unroll
      for (int nt = 0; nt < 2; nt++)
        acc[mt][nt] = __builtin_amdgcn_mfma_f32_16x16x32_bf16(af[mt], bfr[nt], acc[mt][nt], 0, 0, 0);
    __syncthreads();
  }
  if (MODE == 1) {
    float sC[2] = {0.f, 0.f}, qC[2] = {0.f, 0.f};
    #pragma unroll
    for (int mt = 0; mt < 2; mt++)
      #pragma unroll
      for (int nt = 0; nt < 2; nt++)
        #pragma unroll
        for (int q = 0; q < 4; q++) {
          int r = rowBase + wr + mt * 16 + kg * 4 + q;
          int c = colBase + wc + nt * 16 + ln15;
          float v = acc[mt][nt][q] + R[(long)r * N + c];
          out[(long)r * N + c] = v;
          sC[nt] += v;
          qC[nt] += v * v;
        }
    __shared__ float redS[4][32], redQ[4][32];
    #pragma unroll
    for (int nt = 0; nt < 2; nt++) {
      sC[nt] += __shfl_xor(sC[nt], 16);
      sC[nt] += __shfl_xor(sC[nt], 32);
      qC[nt] += __shfl_xor(qC[nt], 16);
      qC[nt] += __shfl_xor(qC[nt], 32);
    }
    if (lane < 16) {
      redS[w][ln15] = sC[0];       redQ[w][ln15] = qC[0];
      redS[w][16 + ln15] = sC[1];  redQ[w][16 + ln15] = qC[1];
    }
    __syncthreads();
    if (tid < 64) {
      int c = tid;
      int grp = c >> 5, lo = c & 31;
      float ss = redS[grp][lo] + redS[grp + 2][lo];
      float qq = redQ[grp][lo] + redQ[grp + 2][lo];
      long slot = ((long)(blockIdx.y * 2 + blockIdx.x) * 64 + c) * 2;
      part2[slot] = ss;
      part2[slot + 1] = qq;
    }
  } else {
    #pragma unroll
    for (int mt = 0; mt < 2; mt++)
      #pragma unroll
      for (int nt = 0; nt < 2; nt++)
        #pragma unroll
        for (int q = 0; q < 4; q++) {
          int r = rowBase + wr + mt * 16 + kg * 4 + q;
          int c = colBase + wc + nt * 16 + ln15;
          if (c < N) {
            int bb = r >> 7, ch = r & 127;
            out[(long)bb * 131072 + (long)c * 128 + ch] =
                acc[mt][nt][q] + R[((long)bb * 1024 + c) * 128 + ch];
          }
        }
  }
}

// ---- fused: causal depthwise conv + bias + SiLU (bf16 out) | dt/la ----
__global__ __launch_bounds__(256) void conv_dtda(const float* __restrict__ zx,
                                                 const float* __restrict__ cw,
                                                 const float* __restrict__ cb,
                                                 unsigned short* __restrict__ cout,
                                                 const float* __restrict__ raw,
                                                 const float* __restrict__ dtbias,
                                                 const float* __restrict__ alog,
                                                 float* __restrict__ dt,
                                                 float* __restrict__ la,
                                                 int Bb, int L, int conv_dim,
                                                 int H, int rowsH, int convBlocks) {
  int tid = threadIdx.x;
  if ((int)blockIdx.x < convBlocks) {
    long idx4 = (long)blockIdx.x * 256 + tid;
    int nch4 = conv_dim >> 2;
    long total4 = (long)Bb * L * nch4;
    if (idx4 >= total4) return;
    int ch = (int)(idx4 % nch4) << 2;
    long rt = idx4 / nch4;
    int t = (int)(rt % L);
    int b = (int)(rt / L);
    f32x4 acc = *reinterpret_cast<const f32x4*>(&cb[ch]);
    #pragma unroll
    for (int k = 0; k < 4; k++) {
      int tt = t + k - 3;
      if (tt >= 0) {
        f32x4 wv = *reinterpret_cast<const f32x4*>(&cw[k * conv_dim + ch]);
        f32x4 zv = *reinterpret_cast<const f32x4*>(
            &zx[((long)b * L + tt) * conv_dim + ch]);
        acc += wv * zv;
      }
    }
    ushort4 o;
    o.x = f2bf(siluf(acc[0])); o.y = f2bf(siluf(acc[1]));
    o.z = f2bf(siluf(acc[2])); o.w = f2bf(siluf(acc[3]));
    *reinterpret_cast<ushort4*>(&cout[rt * conv_dim + ch]) = o;
  } else {
    int idx = ((int)blockIdx.x - convBlocks) * 256 + tid;
    if (idx >= rowsH) return;
    int h = idx % H;
    float v = raw[idx] + dtbias[h];
    float sp = (v > 20.f) ? v : log1pf(expf(v));
    dt[idx] = sp;
    la[idx] = -expf(alog[h]) * sp;
  }
}

// ===================== chunked SSD (T=64 per chunk), MFMA, bf16 inputs =====================
// K1: S[p,n] = sum_t (Ws[t]*X[t,p]) * B[t,n]
__global__ __launch_bounds__(256) void ssd_local(const unsigned short* __restrict__ xbc,
                                                 const float* __restrict__ dtv,
                                                 const float* __restrict__ la,
                                                 float* __restrict__ Sc,
                                                 float* __restrict__ Aprod,
                                                 int NC, int nc_launch, int H,
                                                 int conv_dim, int d_inner) {
  int blk = blockIdx.x;
  int c = blk % nc_launch, bh = blk / nc_launch;
  int h = bh % H, b = bh / H;
  int tid = threadIdx.x;
  long row0 = ((long)(b * NC + c)) * 64;
  __shared__ unsigned short XpT[64 * 72];   // [p][t] = bf16(Ws[t]*X[t][p])
  __shared__ unsigned short BT[64 * 72];    // [n][t]
  __shared__ float Ws[64];
  int tq = tid >> 4, cq = (tid & 15) << 2;
  ushort4 xr[4], br[4];
  #pragma unroll
  for (int i = 0; i < 4; i++) {
    int t = tq + i * 16;
    const unsigned short* rp = xbc + (row0 + t) * conv_dim;
    xr[i] = *reinterpret_cast<const ushort4*>(rp + (h << 6) + cq);
    br[i] = *reinterpret_cast<const ushort4*>(rp + d_inner + cq);
  }
  if (tid < 64) {
    long r = (row0 + tid) * H + h;
    float cum = wave_prefix_incl(la[r], tid);
    float cT = __shfl(cum, 63);
    Ws[tid] = expf(cT - cum) * dtv[r];
    if (tid == 63) Aprod[(long)bh * NC + c] = expf(cT);
  }
  __syncthreads();
  #pragma unroll
  for (int i = 0; i < 4; i++) {
    int t = tq + i * 16;
    float wv = Ws[t];
    XpT[(cq + 0) * 72 + t] = f2bf(wv * bf2f(xr[i].x));
    XpT[(cq + 1) * 72 + t] = f2bf(wv * bf2f(xr[i].y));
    XpT[(cq + 2) * 72 + t] = f2bf(wv * bf2f(xr[i].z));
    XpT[(cq + 3) * 72 + t] = f2bf(wv * bf2f(xr[i].w));
    BT[(cq + 0) * 72 + t] = br[i].x;
    BT[(cq + 1) * 72 + t] = br[i].y;
    BT[(cq + 2) * 72 + t] = br[i].z;
    BT[(cq + 3) * 72 + t] = br[i].w;
  }
  __syncthreads();
  int lane = tid & 63, wv2 = tid >> 6;
  int wr = (wv2 >> 1) * 32, wc = (wv2 & 1) * 32;
  int ln15 = lane & 15, kg = lane >> 4;
  f32x4 acc[2][2] = {};
  #pragma unroll
  for (int ks = 0; ks < 2; ks++) {
    short8v af[2], bq[2];
    #pragma unroll
    for (int mt = 0; mt < 2; mt++)
      af[mt] = *reinterpret_cast<const short8v*>(&XpT[(wr + mt * 16 + ln15) * 72 + ks * 32 + kg * 8]);
    #pragma unroll
    for (int nt = 0; nt < 2; nt++)
      bq[nt] = *reinterpret_cast<const short8v*>(&BT[(wc + nt * 16 + ln15) * 72 + ks * 32 + kg * 8]);
    #pragma unroll
    for (int mt = 0; mt < 2; mt++)
      #pragma unroll
      for (int nt = 0; nt < 2; nt++)
        acc[mt][nt] = __builtin_amdgcn_mfma_f32_16x16x32_bf16(af[mt], bq[nt], acc[mt][nt], 0, 0, 0);
  }
  float* base = Sc + ((long)bh * NC + c) * 4096;
  #pragma unroll
  for (int mt = 0; mt < 2; mt++)
    #pragma unroll
    for (int nt = 0; nt < 2; nt++)
      #pragma unroll
      for (int q = 0; q < 4; q++) {
        int p = wr + mt * 16 + kg * 4 + q;
        int n = wc + nt * 16 + ln15;
        base[p * 64 + n] = acc[mt][nt][q];
      }
}

// K3: MFMA phases: G=C·B^T (masked) ; Y=Gm·X ; Z=C·h^T ; y = Y + e^cum·Z + D·x (bf16 y)
__global__ __launch_bounds__(256) void ssd_out(const unsigned short* __restrict__ xbc,
                                               const float* __restrict__ dtv,
                                               const float* __restrict__ la,
                                               const float* __restrict__ Sc,
                                               const float* __restrict__ Aprod,
                                               const float* __restrict__ Dvec,
                                               unsigned short* __restrict__ y,
                                               int NC, int H, int conv_dim,
                                               int d_inner) {
  int blk = blockIdx.x;
  int c = blk % NC, bh = blk / NC;
  int h = bh % H, b = bh / H;
  int tid = threadIdx.x;
  long row0 = ((long)(b * NC + c)) * 64;
  __shared__ unsigned short Cb[64 * 72];   // C[t][n]
  __shared__ unsigned short Bb[64 * 72];   // B[s][n]  -> after phase A: Gm[t][s]
  __shared__ unsigned short XT[64 * 72];   // X^T[p][s]
  __shared__ unsigned short hb[64 * 72];   // hprev[p][n]
  __shared__ float Cum[64], Dt[64];
  int tq = tid >> 4, cq = (tid & 15) << 2;
  #pragma unroll
  for (int i = 0; i < 4; i++) {
    int t = tq + i * 16;
    const unsigned short* rp = xbc + (row0 + t) * conv_dim;
    ushort4 cu = *reinterpret_cast<const ushort4*>(rp + d_inner + 64 + cq);
    ushort4 bu = *reinterpret_cast<const ushort4*>(rp + d_inner + cq);
    ushort4 xu = *reinterpret_cast<const ushort4*>(rp + (h << 6) + cq);
    *reinterpret_cast<ushort4*>(&Cb[t * 72 + cq]) = cu;
    *reinterpret_cast<ushort4*>(&Bb[t * 72 + cq]) = bu;
    XT[(cq + 0) * 72 + t] = xu.x;
    XT[(cq + 1) * 72 + t] = xu.y;
    XT[(cq + 2) * 72 + t] = xu.z;
    XT[(cq + 3) * 72 + t] = xu.w;
  }
  // carry fold in fp32 (bit-identical order), then stage h[p][n] as bf16
  if (c > 0) {
    f32x4 hreg[4] = {};
    const float* ap = Aprod + (long)bh * NC;
    for (int j = 0; j < c; j++) {
      const float* sb = Sc + ((long)bh * NC + j) * 4096;
      float a = ap[j];
      #pragma unroll
      for (int i = 0; i < 4; i++) {
        int p = tq + i * 16;
        f32x4 sv = *reinterpret_cast<const f32x4*>(&sb[p * 64 + cq]);
        hreg[i] = hreg[i] * a + sv;
      }
    }
    #pragma unroll
    for (int i = 0; i < 4; i++) {
      int p = tq + i * 16;
      ushort4 ho;
      ho.x = f2bf(hreg[i][0]); ho.y = f2bf(hreg[i][1]);
      ho.z = f2bf(hreg[i][2]); ho.w = f2bf(hreg[i][3]);
      *reinterpret_cast<ushort4*>(&hb[p * 72 + cq]) = ho;
    }
  }
  if (tid < 64) {
    long r = (row0 + tid) * H + h;
    Cum[tid] = wave_prefix_incl(la[r], tid);
    Dt[tid] = dtv[r];
  }
  __syncthreads();
  int lane = tid & 63, wv2 = tid >> 6;
  int wr = (wv2 >> 1) * 32, wc = (wv2 & 1) * 32;
  int ln15 = lane & 15, kg = lane >> 4;
  // ---- Phase A: G[t][s] = sum_n C[t,n] B[s,n]
  f32x4 accA[2][2] = {};
  #pragma unroll
  for (int ks = 0; ks < 2; ks++) {
    short8v af[2], bq[2];
    #pragma unroll
    for (int mt = 0; mt < 2; mt++)
      af[mt] = *reinterpret_cast<const short8v*>(&Cb[(wr + mt * 16 + ln15) * 72 + ks * 32 + kg * 8]);
    #pragma unroll
    for (int nt = 0; nt < 2; nt++)
      bq[nt] = *reinterpret_cast<const short8v*>(&Bb[(wc + nt * 16 + ln15) * 72 + ks * 32 + kg * 8]);
    #pragma unroll
    for (int mt = 0; mt < 2; mt++)
      #pragma unroll
      for (int nt = 0; nt < 2; nt++)
        accA[mt][nt] = __builtin_amdgcn_mfma_f32_16x16x32_bf16(af[mt], bq[nt], accA[mt][nt], 0, 0, 0);
  }
  // mask + weight in registers
  unsigned short gmb[2][2][4];
  #pragma unroll
  for (int mt = 0; mt < 2; mt++)
    #pragma unroll
    for (int nt = 0; nt < 2; nt++)
      #pragma unroll
      for (int q = 0; q < 4; q++) {
        int t = wr + mt * 16 + kg * 4 + q;
        int s = wc + nt * 16 + ln15;
        float v = (s <= t) ? accA[mt][nt][q] * expf(Cum[t] - Cum[s]) * Dt[s] : 0.f;
        gmb[mt][nt][q] = f2bf(v);
      }
  __syncthreads();   // all waves done reading Bb
  #pragma unroll
  for (int mt = 0; mt < 2; mt++)
    #pragma unroll
    for (int nt = 0; nt < 2; nt++)
      #pragma unroll
      for (int q = 0; q < 4; q++)
        Bb[(wr + mt * 16 + kg * 4 + q) * 72 + wc + nt * 16 + ln15] = gmb[mt][nt][q];
  __syncthreads();
  // ---- Phase B: Y[t][p] = sum_s Gm[t,s] X[s,p] ; Phase C: Z[t][p] = sum_n C[t,n] h[p,n]
  f32x4 accY[2][2] = {}, accZ[2][2] = {};
  #pragma unroll
  for (int ks = 0; ks < 2; ks++) {
    short8v af[2], bq[2];
    #pragma unroll
    for (int mt = 0; mt < 2; mt++)
      af[mt] = *reinterpret_cast<const short8v*>(&Bb[(wr + mt * 16 + ln15) * 72 + ks * 32 + kg * 8]);
    #pragma unroll
    for (int nt = 0; nt < 2; nt++)
      bq[nt] = *reinterpret_cast<const short8v*>(&XT[(wc + nt * 16 + ln15) * 72 + ks * 32 + kg * 8]);
    #pragma unroll
    for (int mt = 0; mt < 2; mt++)
      #pragma unroll
      for (int nt = 0; nt < 2; nt++)
        accY[mt][nt] = __builtin_amdgcn_mfma_f32_16x16x32_bf16(af[mt], bq[nt], accY[mt][nt], 0, 0, 0);
  }
  if (c > 0) {
    #pragma unroll
    for (int ks = 0; ks < 2; ks++) {
      short8v af[2], bq[2];
      #pragma unroll
      for (int mt = 0; mt < 2; mt++)
        af[mt] = *reinterpret_cast<const short8v*>(&Cb[(wr + mt * 16 + ln15) * 72 + ks * 32 + kg * 8]);
      #pragma unroll
      for (int nt = 0; nt < 2; nt++)
        bq[nt] = *reinterpret_cast<const short8v*>(&hb[(wc + nt * 16 + ln15) * 72 + ks * 32 + kg * 8]);
      #pragma unroll
      for (int mt = 0; mt < 2; mt++)
        #pragma unroll
        for (int nt = 0; nt < 2; nt++)
          accZ[mt][nt] = __builtin_amdgcn_mfma_f32_16x16x32_bf16(af[mt], bq[nt], accZ[mt][nt], 0, 0, 0);
    }
  }
  float Dv = Dvec[h];
  #pragma unroll
  for (int mt = 0; mt < 2; mt++)
    #pragma unroll
    for (int q = 0; q < 4; q++) {
      int t = wr + mt * 16 + kg * 4 + q;
      float wB = expf(Cum[t]);
      const unsigned short* xp = xbc + (row0 + t) * conv_dim + (h << 6);
      unsigned short* yp = y + (row0 + t) * d_inner + (h << 6);
      #pragma unroll
      for (int nt = 0; nt < 2; nt++) {
        int p = wc + nt * 16 + ln15;
        yp[p] = f2bf(accY[mt][nt][q] + accZ[mt][nt][q] * wB + bf2f(xp[p]) * Dv);
      }
    }
}

// --- wave-per-row: g = y*silu(z); g *= rsqrt(mean(g^2)+eps)*rms_w; bf16 out ---
// CPL = elems per lane = d_inner/64 (multiple of 4). grid = rows/4, 256 threads.
template <int CPL>
__global__ __launch_bounds__(256) void gate_rms_bf16(const unsigned short* __restrict__ y,
                                                     const unsigned short* __restrict__ z,
                                                     const float* __restrict__ rmsw,
                                                     unsigned short* __restrict__ ab,
                                                     int d_inner) {
  long row = (long)blockIdx.x * 4 + (threadIdx.x >> 6);
  int lane = threadIdx.x & 63;
  const unsigned short* yr = y + row * d_inner;
  const unsigned short* zr = z + row * d_inner;
  float g[CPL];
  float ss = 0.f;
  #pragma unroll
  for (int j = 0; j < CPL / 4; j++) {
    int c = j * 256 + lane * 4;
    ushort4 yv = *reinterpret_cast<const ushort4*>(&yr[c]);
    ushort4 zv = *reinterpret_cast<const ushort4*>(&zr[c]);
    float g0 = bf2f(yv.x) * siluf(bf2f(zv.x));
    float g1 = bf2f(yv.y) * siluf(bf2f(zv.y));
    float g2 = bf2f(yv.z) * siluf(bf2f(zv.z));
    float g3 = bf2f(yv.w) * siluf(bf2f(zv.w));
    g[j * 4 + 0] = g0; g[j * 4 + 1] = g1; g[j * 4 + 2] = g2; g[j * 4 + 3] = g3;
    ss += g0 * g0 + g1 * g1 + g2 * g2 + g3 * g3;
  }
  #pragma unroll
  for (int o = 32; o; o >>= 1) ss += __shfl_xor(ss, o);
  float inv = rsqrtf(ss / (float)d_inner + EPSV);
  #pragma unroll
  for (int j = 0; j < CPL / 4; j++) {
    int c = j * 256 + lane * 4;
    float4 wv = *reinterpret_cast<const float4*>(&rmsw[c]);
    ushort4 o;
    o.x = f2bf(g[j * 4 + 0] * inv * wv.x);
    o.y = f2bf(g[j * 4 + 1] * inv * wv.y);
    o.z = f2bf(g[j * 4 + 2] * inv * wv.z);
    o.w = f2bf(g[j * 4 + 3] * inv * wv.w);
    *reinterpret_cast<ushort4*>(&ab[row * d_inner + c]) = o;
  }
}

extern "C" void kernel_launch(void* const* d_in, const int* in_sizes, int n_in,
                              void* d_out, int out_size, void* d_ws,
                              size_t ws_size, hipStream_t stream) {
  const float* x        = (const float*)d_in[0];
  const float* ln_spa_w = (const float*)d_in[1];
  const float* ln_spa_b = (const float*)d_in[2];
  const float* ln_spe_w = (const float*)d_in[3];
  const float* ln_spe_b = (const float*)d_in[4];
  const float* spa_W_in   = (const float*)d_in[5];
  const float* spa_conv_w = (const float*)d_in[6];
  const float* spa_conv_b = (const float*)d_in[7];
  const float* spa_dt_b   = (const float*)d_in[8];
  const float* spa_A_log  = (const float*)d_in[9];
  const float* spa_D      = (const float*)d_in[10];
  const float* spa_rms_w  = (const float*)d_in[11];
  const float* spa_W_out  = (const float*)d_in[12];
  const float* spe_W_in   = (const float*)d_in[13];
  const float* spe_conv_w = (const float*)d_in[14];
  const float* spe_conv_b = (const float*)d_in[15];
  const float* spe_dt_b   = (const float*)d_in[16];
  const float* spe_A_log  = (const float*)d_in[17];
  const float* spe_D      = (const float*)d_in[18];
  const float* spe_rms_w  = (const float*)d_in[19];
  const float* spe_W_out  = (const float*)d_in[20];
  float* out = (float*)d_out;

  float* ws = (float*)d_ws;
  // layout (floats) — same proven 63.9 MB budget; z/cv/yb now hold bf16 (half used)
  float* xspa   = ws;                 // 1,048,576
  unsigned short* z = (unsigned short*)(ws + 1048576);   // ≤2,097,152 u16
  float* xbcraw = ws + 3145728;       // 3,145,728 (later Sc)
  float* dtraw  = ws + 6291456;       // 32,768    (later Aprod)
  unsigned short* cv = (unsigned short*)(ws + 6324224);  // ≤4,456,448 u16 (in 3,145,728 fl)
  float* dtb    = ws + 9469952;       // 32,768    (also spe LN partials)
  float* la     = ws + 9502720;       // 32,768
  unsigned short* yb = (unsigned short*)(ws + 9535488);  // ≤2,097,152 u16
  unsigned short* Abf     = (unsigned short*)(ws + 11634688);  // 1,048,576 fl
  unsigned short* Wt_spai = (unsigned short*)(ws + 12683264);  // 41,216 fl
  unsigned short* Wt_spao = (unsigned short*)(ws + 12724480);  // 16,384 fl
  unsigned short* Wt_spei = (unsigned short*)(ws + 12740864);  // 2,179,072 fl
  unsigned short* Wt_speo = (unsigned short*)(ws + 14919936);  // 1,048,576 fl

  // 1. fused prologue: spa LN (blocks 0..4095) + all weight transposes
  hipLaunchKernelGGL(ln_wt_fused, dim3(5710), dim3(256), 0, stream,
                     x, ln_spa_w, ln_spa_b, Abf,
                     spa_W_in, Wt_spai, spa_W_out, Wt_spao,
                     spe_W_in, Wt_spei, spe_W_out, Wt_speo);

  // ================= spatial mamba (L=1024, d_model=128) =================
  hipLaunchKernelGGL(gemm128_split, dim3(6, 64), dim3(256), 0, stream,
                     Abf, Wt_spai, z, xbcraw, dtraw,
                     8192, 644, 128, 256, 640);
  hipLaunchKernelGGL(conv_dtda, dim3(3200), dim3(256), 0, stream,
                     xbcraw, spa_conv_w, spa_conv_b, cv,
                     dtraw, spa_dt_b, spa_A_log, dtb, la,
                     8, 1024, 384, 4, 32768, 3072);
  hipLaunchKernelGGL(ssd_local, dim3(480), dim3(256), 0, stream,
                     cv, dtb, la, xbcraw, dtraw, 16, 15, 4, 384, 256);
  hipLaunchKernelGGL(ssd_out, dim3(512), dim3(256), 0, stream,
                     cv, dtb, la, xbcraw, dtraw, spa_D, yb, 16, 4, 384, 256);
  hipLaunchKernelGGL((gate_rms_bf16<4>), dim3(2048), dim3(256), 0, stream,
                     yb, z, spa_rms_w, Abf, 256);
  hipLaunchKernelGGL((gemm_mfma<1>), dim3(2, 128), dim3(256), 0, stream,
                     Abf, Wt_spao, x, xspa, dtb, 8192, 128, 256);

  // ================= spectral mamba (L=128, d_model=1024) =================
  hipLaunchKernelGGL(spe_normT, dim3(2, 8, 8), dim3(256), 0, stream,
                     xspa, dtb, ln_spe_w, ln_spe_b, Abf);
  hipLaunchKernelGGL(gemm128_split, dim3(34, 8), dim3(256), 0, stream,
                     Abf, Wt_spei, z, xbcraw, dtraw,
                     1024, 4256, 1024, 2048, 4224);
  hipLaunchKernelGGL(conv_dtda, dim3(2304), dim3(256), 0, stream,
                     xbcraw, spe_conv_w, spe_conv_b, cv,
                     dtraw, spe_dt_b, spe_A_log, dtb, la,
                     8, 128, 2176, 32, 32768, 2176);
  hipLaunchKernelGGL(ssd_local, dim3(256), dim3(256), 0, stream,
                     cv, dtb, la, xbcraw, dtraw, 2, 1, 32, 2176, 2048);
  hipLaunchKernelGGL(ssd_out, dim3(512), dim3(256), 0, stream,
                     cv, dtb, la, xbcraw, dtraw, spe_D, yb, 2, 32, 2176, 2048);
  hipLaunchKernelGGL((gate_rms_bf16<32>), dim3(256), dim3(256), 0, stream,
                     yb, z, spe_rms_w, Abf, 2048);
  hipLaunchKernelGGL((gemm_mfma<2>), dim3(16, 16), dim3(256), 0, stream,
                     Abf, Wt_speo, xspa, out, nullptr, 1024, 1024, 2048);
}

// Round 13
// 166.643 us; speedup vs baseline: 1.3438x; 1.0422x over previous
//
#include <hip/hip_runtime.h>
#include <hip/hip_bf16.h>

#define EPSV 1e-5f

typedef __attribute__((ext_vector_type(8))) short short8v;   // 8 bf16 in 4 VGPRs
typedef __attribute__((ext_vector_type(4))) float f32x4;

__device__ inline unsigned short f2bf(float f) {
  __hip_bfloat16 h = __float2bfloat16(f);
  return *reinterpret_cast<unsigned short*>(&h);
}

__device__ inline float bf2f(unsigned short u) {
  return __uint_as_float(((unsigned int)u) << 16);
}

__device__ inline float siluf(float x) { return x / (1.f + expf(-x)); }

// direct global->LDS 16B async copy (lane-linear dest: base + lane*16)
__device__ inline void gload_lds16(const void* g, void* l) {
  __builtin_amdgcn_global_load_lds(
      (const __attribute__((address_space(1))) void*)g,
      (__attribute__((address_space(3))) void*)l, 16, 0, 0);
}

// ---------------- block-wide sum (256 threads = 4 waves) ----------------
__device__ inline float block_sum(float v, float* lds) {
  #pragma unroll
  for (int o = 32; o; o >>= 1) v += __shfl_xor(v, o);
  int tid = threadIdx.x;
  if ((tid & 63) == 0) lds[tid >> 6] = v;
  __syncthreads();
  float r = lds[0] + lds[1] + lds[2] + lds[3];
  __syncthreads();
  return r;
}

// inclusive prefix sum over 64 lanes (call from wave 0 only)
__device__ inline float wave_prefix_incl(float v, int lane) {
  #pragma unroll
  for (int o = 1; o < 64; o <<= 1) {
    float u = __shfl_up(v, o);
    if (lane >= o) v += u;
  }
  return v;
}

// ------- weight transpose tile W[K][N] -> Wt[N][K] bf16 -------
__device__ inline void wtconv_tile(const float* __restrict__ W,
                                   unsigned short* __restrict__ Wt,
                                   int K, int N, int bx, int by) {
  __shared__ float tile[64][65];
  int n0 = bx * 64, k0 = by * 64;
  int tid = threadIdx.x;
  int r = tid >> 4, c4 = (tid & 15) * 4;
  #pragma unroll
  for (int i = 0; i < 4; i++) {
    int kk = r + i * 16;
    float4 v = make_float4(0.f, 0.f, 0.f, 0.f);
    if (n0 + c4 < N) v = *reinterpret_cast<const float4*>(&W[(long)(k0 + kk) * N + n0 + c4]);
    tile[kk][c4] = v.x; tile[kk][c4 + 1] = v.y; tile[kk][c4 + 2] = v.z; tile[kk][c4 + 3] = v.w;
  }
  __syncthreads();
  #pragma unroll
  for (int i = 0; i < 4; i++) {
    int nl = r + i * 16;
    if (n0 + nl < N) {
      ushort4 o;
      o.x = f2bf(tile[c4 + 0][nl]);
      o.y = f2bf(tile[c4 + 1][nl]);
      o.z = f2bf(tile[c4 + 2][nl]);
      o.w = f2bf(tile[c4 + 3][nl]);
      *reinterpret_cast<ushort4*>(&Wt[(long)(n0 + nl) * K + k0 + c4]) = o;
    }
  }
}

// ---- fused prologue: spa LN (2 rows/block, bf16 out) + all 4 weight transposes ----
__global__ __launch_bounds__(256) void ln_wt_fused(const float* __restrict__ x,
                                                   const float* __restrict__ w,
                                                   const float* __restrict__ bb,
                                                   unsigned short* __restrict__ outA,
                                                   const float* __restrict__ W0,
                                                   unsigned short* __restrict__ T0,
                                                   const float* __restrict__ W1,
                                                   unsigned short* __restrict__ T1,
                                                   const float* __restrict__ W2,
                                                   unsigned short* __restrict__ T2,
                                                   const float* __restrict__ W3,
                                                   unsigned short* __restrict__ T3) {
  int id = blockIdx.x;
  if (id < 4096) {
    int tid = threadIdx.x;
    __shared__ float lds[4];
    long row = (long)id * 2 + (tid >> 7);
    int lane = tid & 127;
    int base = (tid >> 7) << 1;
    float v = x[row * 128 + lane];
    float s = v;
    #pragma unroll
    for (int o = 32; o; o >>= 1) s += __shfl_xor(s, o);
    if ((tid & 63) == 0) lds[tid >> 6] = s;
    __syncthreads();
    float m = (lds[base] + lds[base + 1]) * (1.f / 128.f);
    float d = v - m;
    float q = d * d;
    #pragma unroll
    for (int o = 32; o; o >>= 1) q += __shfl_xor(q, o);
    __syncthreads();
    if ((tid & 63) == 0) lds[tid >> 6] = q;
    __syncthreads();
    float inv = rsqrtf((lds[base] + lds[base + 1]) * (1.f / 128.f) + EPSV);
    outA[row * 128 + lane] = f2bf(d * inv * w[lane] + bb[lane]);
  } else {
    id -= 4096;
    if (id < 22)        { int r = id;        wtconv_tile(W0, T0, 128,  644,  r % 11, r / 11); }
    else if (id < 30)   { int r = id - 22;   wtconv_tile(W1, T1, 256,  128,  r % 2,  r / 2); }
    else if (id < 1102) { int r = id - 30;   wtconv_tile(W2, T2, 1024, 4256, r % 67, r / 67); }
    else                { int r = id - 1102; wtconv_tile(W3, T3, 2048, 1024, r % 16, r / 16); }
  }
}

// ---- spe LN pass 2: finalize per-(b,ch) stats from GEMM partials,
//      normalize + transpose, emit bf16. part2: float2[(by*2+bx)*64 + cl]
__global__ __launch_bounds__(256) void spe_normT(const float* __restrict__ xspa,
                                                 const float* __restrict__ part2,
                                                 const float* __restrict__ w,
                                                 const float* __restrict__ bb,
                                                 unsigned short* __restrict__ out) {
  __shared__ float tile[128][65];
  int c0 = blockIdx.x * 64, l0 = blockIdx.y * 128, b = blockIdx.z;
  int tid = threadIdx.x;
  int rr = tid >> 4, c4 = (tid & 15) * 4;
  #pragma unroll
  for (int p = 0; p < 8; p++) {
    int l = rr + p * 16;
    f32x4 v = *reinterpret_cast<const f32x4*>(
        &xspa[((long)b * 1024 + l0 + l) * 128 + c0 + c4]);
    tile[l][c4] = v[0]; tile[l][c4 + 1] = v[1];
    tile[l][c4 + 2] = v[2]; tile[l][c4 + 3] = v[3];
  }
  __syncthreads();
  int ch = tid >> 2, lq = tid & 3;
  int gc = c0 + ch;
  int bx = gc >> 6, cl = gc & 63;
  float ssum = 0.f, qsum = 0.f;
  #pragma unroll
  for (int sub = 0; sub < 16; sub++) {
    int by = b * 16 + sub;
    float2 pq = *reinterpret_cast<const float2*>(&part2[(((by * 2 + bx) * 64) + cl) * 2]);
    ssum += pq.x; qsum += pq.y;
  }
  float mm = ssum * (1.f / 1024.f);
  float rstd = rsqrtf(qsum * (1.f / 1024.f) - mm * mm + EPSV);
  #pragma unroll
  for (int j = 0; j < 8; j++) {
    int qidx = lq + j * 4;
    int l = qidx * 4;
    float4 wv = *reinterpret_cast<const float4*>(&w[l0 + l]);
    float4 bv = *reinterpret_cast<const float4*>(&bb[l0 + l]);
    ushort4 o;
    o.x = f2bf((tile[l + 0][ch] - mm) * rstd * wv.x + bv.x);
    o.y = f2bf((tile[l + 1][ch] - mm) * rstd * wv.y + bv.y);
    o.z = f2bf((tile[l + 2][ch] - mm) * rstd * wv.z + bv.z);
    o.w = f2bf((tile[l + 3][ch] - mm) * rstd * wv.w + bv.w);
    *reinterpret_cast<ushort4*>(&out[((long)b * 128 + c0 + ch) * 1024 + l0 + l]) = o;
  }
}

// ------- 128x128-tile bf16 MFMA GEMM, global_load_lds staging (m97-style) -------
// column-split epilogue: c<c1 -> zout (bf16, ld c1); c<c2 -> o2 (bf16); else o3 (f32)
__global__ __launch_bounds__(256) void gemm128_split(const unsigned short* __restrict__ A,
                                                     const unsigned short* __restrict__ Bt,
                                                     unsigned short* __restrict__ zout,
                                                     unsigned short* __restrict__ o2,
                                                     float* __restrict__ o3,
                                                     int M, int N, int K,
                                                     int c1, int c2) {
  __shared__ unsigned short As[128 * 32];   // linear, no pad (global_load_lds dest)
  __shared__ unsigned short Bs[128 * 32];
  int tid = threadIdx.x;
  int lane = tid & 63, w = tid >> 6;
  int wr = (w >> 1) * 64, wc = (w & 1) * 64;
  int ln15 = lane & 15, kg = lane >> 4;
  int rowBase = blockIdx.y * 128, colBase = blockIdx.x * 128;
  int srow = w * 32 + (lane >> 2);
  int scol = (lane & 3) * 8;
  f32x4 acc[4][4] = {};
  for (int k0 = 0; k0 < K; k0 += 32) {
    gload_lds16(&A[(long)(rowBase + srow) * K + k0 + scol], &As[(w * 32) * 32]);
    gload_lds16(&A[(long)(rowBase + srow + 16) * K + k0 + scol], &As[(w * 32 + 16) * 32]);
    gload_lds16(&Bt[(long)(colBase + srow) * K + k0 + scol], &Bs[(w * 32) * 32]);
    gload_lds16(&Bt[(long)(colBase + srow + 16) * K + k0 + scol], &Bs[(w * 32 + 16) * 32]);
    __syncthreads();
    short8v af[4], bfr[4];
    #pragma unroll
    for (int mt = 0; mt < 4; mt++)
      af[mt] = *reinterpret_cast<const short8v*>(&As[(wr + mt * 16 + ln15) * 32 + kg * 8]);
    #pragma unroll
    for (int nt = 0; nt < 4; nt++)
      bfr[nt] = *reinterpret_cast<const short8v*>(&Bs[(wc + nt * 16 + ln15) * 32 + kg * 8]);
    #pragma unroll
    for (int mt = 0; mt < 4; mt++)
      #pragma unroll
      for (int nt = 0; nt < 4; nt++)
        acc[mt][nt] = __builtin_amdgcn_mfma_f32_16x16x32_bf16(af[mt], bfr[nt], acc[mt][nt], 0, 0, 0);
    __syncthreads();
  }
  #pragma unroll
  for (int mt = 0; mt < 4; mt++)
    #pragma unroll
    for (int nt = 0; nt < 4; nt++)
      #pragma unroll
      for (int q = 0; q < 4; q++) {
        int r = rowBase + wr + mt * 16 + kg * 4 + q;
        int c = colBase + wc + nt * 16 + ln15;
        if (c < N) {
          float v = acc[mt][nt][q];
          if (c < c1) zout[(long)r * c1 + c] = f2bf(v);
          else if (c < c2) o2[(long)r * (c2 - c1) + (c - c1)] = f2bf(v);
          else o3[(long)r * (N - c2) + (c - c2)] = v;
        }
      }
}

// ------- 128(rows)x64(cols)-tile GEMM, gload_lds staging, transposed-add -------
// out[bb][c][ch] = acc + R[bb][c][ch] with r=(bb,ch): bb=r>>7, ch=r&127.
__global__ __launch_bounds__(256) void gemm128x64_t(const unsigned short* __restrict__ A,
                                                    const unsigned short* __restrict__ Bt,
                                                    const float* __restrict__ R,
                                                    float* __restrict__ out,
                                                    int M, int N, int K) {
  __shared__ unsigned short As[128 * 32];
  __shared__ unsigned short Bs[64 * 32];
  int tid = threadIdx.x;
  int lane = tid & 63, w = tid >> 6;
  int wr = w * 32;                     // wave covers rows wr..wr+31, all 64 cols
  int ln15 = lane & 15, kg = lane >> 4;
  int rowBase = blockIdx.y * 128, colBase = blockIdx.x * 64;
  int arow = w * 32 + (lane >> 2);
  int brow = w * 16 + (lane >> 2);
  int scol = (lane & 3) * 8;
  f32x4 acc[2][4] = {};
  for (int k0 = 0; k0 < K; k0 += 32) {
    gload_lds16(&A[(long)(rowBase + arow) * K + k0 + scol], &As[(w * 32) * 32]);
    gload_lds16(&A[(long)(rowBase + arow + 16) * K + k0 + scol], &As[(w * 32 + 16) * 32]);
    gload_lds16(&Bt[(long)(colBase + brow) * K + k0 + scol], &Bs[(w * 16) * 32]);
    __syncthreads();
    short8v af[2], bfr[4];
    #pragma unroll
    for (int mt = 0; mt < 2; mt++)
      af[mt] = *reinterpret_cast<const short8v*>(&As[(wr + mt * 16 + ln15) * 32 + kg * 8]);
    #pragma unroll
    for (int nt = 0; nt < 4; nt++)
      bfr[nt] = *reinterpret_cast<const short8v*>(&Bs[(nt * 16 + ln15) * 32 + kg * 8]);
    #pragma unroll
    for (int mt = 0; mt < 2; mt++)
      #pragma unroll
      for (int nt = 0; nt < 4; nt++)
        acc[mt][nt] = __builtin_amdgcn_mfma_f32_16x16x32_bf16(af[mt], bfr[nt], acc[mt][nt], 0, 0, 0);
    __syncthreads();
  }
  #pragma unroll
  for (int mt = 0; mt < 2; mt++)
    #pragma unroll
    for (int nt = 0; nt < 4; nt++)
      #pragma unroll
      for (int q = 0; q < 4; q++) {
        int r = rowBase + wr + mt * 16 + kg * 4 + q;
        int c = colBase + nt * 16 + ln15;
        int bb = r >> 7, ch = r & 127;
        out[(long)bb * 131072 + (long)c * 128 + ch] =
            acc[mt][nt][q] + R[((long)bb * 1024 + c) * 128 + ch];
      }
}

// ---------------- 64x64-tile bf16 MFMA GEMM (spa W_out epilogue) ----------------
// out = v + R; also emits deterministic per-block column {sum,sum^2} partials.
__global__ __launch_bounds__(256) void gemm_mfma1(const unsigned short* __restrict__ A,
                                                  const unsigned short* __restrict__ Bt,
                                                  const float* __restrict__ R,
                                                  float* __restrict__ out,
                                                  float* __restrict__ part2,
                                                  int M, int N, int K) {
  __shared__ unsigned short As[64 * 40];
  __shared__ unsigned short Bs[64 * 40];
  int tid = threadIdx.x;
  int lane = tid & 63, w = tid >> 6;
  int wr = (w >> 1) * 32, wc = (w & 1) * 32;
  int ln15 = lane & 15, kg = lane >> 4;
  int rowBase = blockIdx.y * 64, colBase = blockIdx.x * 64;
  int sm = tid >> 2, skb = (tid & 3) * 8;
  f32x4 acc[2][2] = {};
  for (int k0 = 0; k0 < K; k0 += 32) {
    {
      short8v av = *reinterpret_cast<const short8v*>(&A[(long)(rowBase + sm) * K + k0 + skb]);
      *reinterpret_cast<short8v*>(&As[sm * 40 + skb]) = av;
      int n = colBase + sm;
      short8v bv = {0, 0, 0, 0, 0, 0, 0, 0};
      if (n < N) bv = *reinterpret_cast<const short8v*>(&Bt[(long)n * K + k0 + skb]);
      *reinterpret_cast<short8v*>(&Bs[sm * 40 + skb]) = bv;
    }
    __syncthreads();
    short8v af[2], bfr[2];
    #pragma unroll
    for (int mt = 0; mt < 2; mt++)
      af[mt] = *reinterpret_cast<const short8v*>(&As[(wr + mt * 16 + ln15) * 40 + kg * 8]);
    #pragma unroll
    for (int nt = 0; nt < 2; nt++)
      bfr[nt] = *reinterpret_cast<const short8v*>(&Bs[(wc + nt * 16 + ln15) * 40 + kg * 8]);
    #pragma unroll
    for (int mt = 0; mt < 2; mt++)
      #pragma unroll
      for (int nt = 0; nt < 2; nt++)
        acc[mt][nt] = __builtin_amdgcn_mfma_f32_16x16x32_bf16(af[mt], bfr[nt], acc[mt][nt], 0, 0, 0);
    __syncthreads();
  }
  float sC[2] = {0.f, 0.f}, qC[2] = {0.f, 0.f};
  #pragma unroll
  for (int mt = 0; mt < 2; mt++)
    #pragma unroll
    for (int nt = 0; nt < 2; nt++)
      #pragma unroll
      for (int q = 0; q < 4; q++) {
        int r = rowBase + wr + mt * 16 + kg * 4 + q;
        int c = colBase + wc + nt * 16 + ln15;
        float v = acc[mt][nt][q] + R[(long)r * N + c];
        out[(long)r * N + c] = v;
        sC[nt] += v;
        qC[nt] += v * v;
      }
  __shared__ float redS[4][32], redQ[4][32];
  #pragma unroll
  for (int nt = 0; nt < 2; nt++) {
    sC[nt] += __shfl_xor(sC[nt], 16);
    sC[nt] += __shfl_xor(sC[nt], 32);
    qC[nt] += __shfl_xor(qC[nt], 16);
    qC[nt] += __shfl_xor(qC[nt], 32);
  }
  if (lane < 16) {
    redS[w][ln15] = sC[0];       redQ[w][ln15] = qC[0];
    redS[w][16 + ln15] = sC[1];  redQ[w][16 + ln15] = qC[1];
  }
  __syncthreads();
  if (tid < 64) {
    int c = tid;
    int grp = c >> 5, lo = c & 31;
    float ss = redS[grp][lo] + redS[grp + 2][lo];
    float qq = redQ[grp][lo] + redQ[grp + 2][lo];
    long slot = ((long)(blockIdx.y * 2 + blockIdx.x) * 64 + c) * 2;
    part2[slot] = ss;
    part2[slot + 1] = qq;
  }
}

// ---- fused: causal depthwise conv (bf16 in, bf16 out) + bias + SiLU | dt/la ----
__global__ __launch_bounds__(256) void conv_dtda(const unsigned short* __restrict__ zx,
                                                 const float* __restrict__ cw,
                                                 const float* __restrict__ cb,
                                                 unsigned short* __restrict__ cout,
                                                 const float* __restrict__ raw,
                                                 const float* __restrict__ dtbias,
                                                 const float* __restrict__ alog,
                                                 float* __restrict__ dt,
                                                 float* __restrict__ la,
                                                 int Bb, int L, int conv_dim,
                                                 int H, int rowsH, int convBlocks) {
  int tid = threadIdx.x;
  if ((int)blockIdx.x < convBlocks) {
    long idx4 = (long)blockIdx.x * 256 + tid;
    int nch4 = conv_dim >> 2;
    long total4 = (long)Bb * L * nch4;
    if (idx4 >= total4) return;
    int ch = (int)(idx4 % nch4) << 2;
    long rt = idx4 / nch4;
    int t = (int)(rt % L);
    int b = (int)(rt / L);
    f32x4 acc = *reinterpret_cast<const f32x4*>(&cb[ch]);
    #pragma unroll
    for (int k = 0; k < 4; k++) {
      int tt = t + k - 3;
      if (tt >= 0) {
        f32x4 wv = *reinterpret_cast<const f32x4*>(&cw[k * conv_dim + ch]);
        ushort4 zu = *reinterpret_cast<const ushort4*>(
            &zx[((long)b * L + tt) * conv_dim + ch]);
        acc[0] += wv[0] * bf2f(zu.x);
        acc[1] += wv[1] * bf2f(zu.y);
        acc[2] += wv[2] * bf2f(zu.z);
        acc[3] += wv[3] * bf2f(zu.w);
      }
    }
    ushort4 o;
    o.x = f2bf(siluf(acc[0])); o.y = f2bf(siluf(acc[1]));
    o.z = f2bf(siluf(acc[2])); o.w = f2bf(siluf(acc[3]));
    *reinterpret_cast<ushort4*>(&cout[rt * conv_dim + ch]) = o;
  } else {
    int idx = ((int)blockIdx.x - convBlocks) * 256 + tid;
    if (idx >= rowsH) return;
    int h = idx % H;
    float v = raw[idx] + dtbias[h];
    float sp = (v > 20.f) ? v : log1pf(expf(v));
    dt[idx] = sp;
    la[idx] = -expf(alog[h]) * sp;
  }
}

// ===================== chunked SSD (T=64 per chunk), MFMA, bf16 inputs =====================
// K1: S[p,n] = sum_t (Ws[t]*X[t,p]) * B[t,n]
__global__ __launch_bounds__(256) void ssd_local(const unsigned short* __restrict__ xbc,
                                                 const float* __restrict__ dtv,
                                                 const float* __restrict__ la,
                                                 float* __restrict__ Sc,
                                                 float* __restrict__ Aprod,
                                                 int NC, int nc_launch, int H,
                                                 int conv_dim, int d_inner) {
  int blk = blockIdx.x;
  int c = blk % nc_launch, bh = blk / nc_launch;
  int h = bh % H, b = bh / H;
  int tid = threadIdx.x;
  long row0 = ((long)(b * NC + c)) * 64;
  __shared__ unsigned short XpT[64 * 72];   // [p][t] = bf16(Ws[t]*X[t][p])
  __shared__ unsigned short BT[64 * 72];    // [n][t]
  __shared__ float Ws[64];
  int tq = tid >> 4, cq = (tid & 15) << 2;
  ushort4 xr[4], br[4];
  #pragma unroll
  for (int i = 0; i < 4; i++) {
    int t = tq + i * 16;
    const unsigned short* rp = xbc + (row0 + t) * conv_dim;
    xr[i] = *reinterpret_cast<const ushort4*>(rp + (h << 6) + cq);
    br[i] = *reinterpret_cast<const ushort4*>(rp + d_inner + cq);
  }
  if (tid < 64) {
    long r = (row0 + tid) * H + h;
    float cum = wave_prefix_incl(la[r], tid);
    float cT = __shfl(cum, 63);
    Ws[tid] = expf(cT - cum) * dtv[r];
    if (tid == 63) Aprod[(long)bh * NC + c] = expf(cT);
  }
  __syncthreads();
  #pragma unroll
  for (int i = 0; i < 4; i++) {
    int t = tq + i * 16;
    float wv = Ws[t];
    XpT[(cq + 0) * 72 + t] = f2bf(wv * bf2f(xr[i].x));
    XpT[(cq + 1) * 72 + t] = f2bf(wv * bf2f(xr[i].y));
    XpT[(cq + 2) * 72 + t] = f2bf(wv * bf2f(xr[i].z));
    XpT[(cq + 3) * 72 + t] = f2bf(wv * bf2f(xr[i].w));
    BT[(cq + 0) * 72 + t] = br[i].x;
    BT[(cq + 1) * 72 + t] = br[i].y;
    BT[(cq + 2) * 72 + t] = br[i].z;
    BT[(cq + 3) * 72 + t] = br[i].w;
  }
  __syncthreads();
  int lane = tid & 63, wv2 = tid >> 6;
  int wr = (wv2 >> 1) * 32, wc = (wv2 & 1) * 32;
  int ln15 = lane & 15, kg = lane >> 4;
  f32x4 acc[2][2] = {};
  #pragma unroll
  for (int ks = 0; ks < 2; ks++) {
    short8v af[2], bq[2];
    #pragma unroll
    for (int mt = 0; mt < 2; mt++)
      af[mt] = *reinterpret_cast<const short8v*>(&XpT[(wr + mt * 16 + ln15) * 72 + ks * 32 + kg * 8]);
    #pragma unroll
    for (int nt = 0; nt < 2; nt++)
      bq[nt] = *reinterpret_cast<const short8v*>(&BT[(wc + nt * 16 + ln15) * 72 + ks * 32 + kg * 8]);
    #pragma unroll
    for (int mt = 0; mt < 2; mt++)
      #pragma unroll
      for (int nt = 0; nt < 2; nt++)
        acc[mt][nt] = __builtin_amdgcn_mfma_f32_16x16x32_bf16(af[mt], bq[nt], acc[mt][nt], 0, 0, 0);
  }
  float* base = Sc + ((long)bh * NC + c) * 4096;
  #pragma unroll
  for (int mt = 0; mt < 2; mt++)
    #pragma unroll
    for (int nt = 0; nt < 2; nt++)
      #pragma unroll
      for (int q = 0; q < 4; q++) {
        int p = wr + mt * 16 + kg * 4 + q;
        int n = wc + nt * 16 + ln15;
        base[p * 64 + n] = acc[mt][nt][q];
      }
}

// K3: MFMA phases: G=C·B^T (masked) ; Y=Gm·X ; Z=C·h^T ; y = Y + e^cum·Z + D·x (bf16 y)
__global__ __launch_bounds__(256) void ssd_out(const unsigned short* __restrict__ xbc,
                                               const float* __restrict__ dtv,
                                               const float* __restrict__ la,
                                               const float* __restrict__ Sc,
                                               const float* __restrict__ Aprod,
                                               const float* __restrict__ Dvec,
                                               unsigned short* __restrict__ y,
                                               int NC, int H, int conv_dim,
                                               int d_inner) {
  int blk = blockIdx.x;
  int c = blk % NC, bh = blk / NC;
  int h = bh % H, b = bh / H;
  int tid = threadIdx.x;
  long row0 = ((long)(b * NC + c)) * 64;
  __shared__ unsigned short Cb[64 * 72];   // C[t][n]
  __shared__ unsigned short Bb[64 * 72];   // B[s][n]  -> after phase A: Gm[t][s]
  __shared__ unsigned short XT[64 * 72];   // X^T[p][s]
  __shared__ unsigned short hb[64 * 72];   // hprev[p][n]
  __shared__ float Cum[64], Dt[64];
  int tq = tid >> 4, cq = (tid & 15) << 2;
  #pragma unroll
  for (int i = 0; i < 4; i++) {
    int t = tq + i * 16;
    const unsigned short* rp = xbc + (row0 + t) * conv_dim;
    ushort4 cu = *reinterpret_cast<const ushort4*>(rp + d_inner + 64 + cq);
    ushort4 bu = *reinterpret_cast<const ushort4*>(rp + d_inner + cq);
    ushort4 xu = *reinterpret_cast<const ushort4*>(rp + (h << 6) + cq);
    *reinterpret_cast<ushort4*>(&Cb[t * 72 + cq]) = cu;
    *reinterpret_cast<ushort4*>(&Bb[t * 72 + cq]) = bu;
    XT[(cq + 0) * 72 + t] = xu.x;
    XT[(cq + 1) * 72 + t] = xu.y;
    XT[(cq + 2) * 72 + t] = xu.z;
    XT[(cq + 3) * 72 + t] = xu.w;
  }
  // carry fold in fp32 (bit-identical order), then stage h[p][n] as bf16
  if (c > 0) {
    f32x4 hreg[4] = {};
    const float* ap = Aprod + (long)bh * NC;
    for (int j = 0; j < c; j++) {
      const float* sb = Sc + ((long)bh * NC + j) * 4096;
      float a = ap[j];
      #pragma unroll
      for (int i = 0; i < 4; i++) {
        int p = tq + i * 16;
        f32x4 sv = *reinterpret_cast<const f32x4*>(&sb[p * 64 + cq]);
        hreg[i] = hreg[i] * a + sv;
      }
    }
    #pragma unroll
    for (int i = 0; i < 4; i++) {
      int p = tq + i * 16;
      ushort4 ho;
      ho.x = f2bf(hreg[i][0]); ho.y = f2bf(hreg[i][1]);
      ho.z = f2bf(hreg[i][2]); ho.w = f2bf(hreg[i][3]);
      *reinterpret_cast<ushort4*>(&hb[p * 72 + cq]) = ho;
    }
  }
  if (tid < 64) {
    long r = (row0 + tid) * H + h;
    Cum[tid] = wave_prefix_incl(la[r], tid);
    Dt[tid] = dtv[r];
  }
  __syncthreads();
  int lane = tid & 63, wv2 = tid >> 6;
  int wr = (wv2 >> 1) * 32, wc = (wv2 & 1) * 32;
  int ln15 = lane & 15, kg = lane >> 4;
  // ---- Phase A: G[t][s] = sum_n C[t,n] B[s,n]
  f32x4 accA[2][2] = {};
  #pragma unroll
  for (int ks = 0; ks < 2; ks++) {
    short8v af[2], bq[2];
    #pragma unroll
    for (int mt = 0; mt < 2; mt++)
      af[mt] = *reinterpret_cast<const short8v*>(&Cb[(wr + mt * 16 + ln15) * 72 + ks * 32 + kg * 8]);
    #pragma unroll
    for (int nt = 0; nt < 2; nt++)
      bq[nt] = *reinterpret_cast<const short8v*>(&Bb[(wc + nt * 16 + ln15) * 72 + ks * 32 + kg * 8]);
    #pragma unroll
    for (int mt = 0; mt < 2; mt++)
      #pragma unroll
      for (int nt = 0; nt < 2; nt++)
        accA[mt][nt] = __builtin_amdgcn_mfma_f32_16x16x32_bf16(af[mt], bq[nt], accA[mt][nt], 0, 0, 0);
  }
  // mask + weight in registers
  unsigned short gmb[2][2][4];
  #pragma unroll
  for (int mt = 0; mt < 2; mt++)
    #pragma unroll
    for (int nt = 0; nt < 2; nt++)
      #pragma unroll
      for (int q = 0; q < 4; q++) {
        int t = wr + mt * 16 + kg * 4 + q;
        int s = wc + nt * 16 + ln15;
        float v = (s <= t) ? accA[mt][nt][q] * expf(Cum[t] - Cum[s]) * Dt[s] : 0.f;
        gmb[mt][nt][q] = f2bf(v);
      }
  __syncthreads();   // all waves done reading Bb
  #pragma unroll
  for (int mt = 0; mt < 2; mt++)
    #pragma unroll
    for (int nt = 0; nt < 2; nt++)
      #pragma unroll
      for (int q = 0; q < 4; q++)
        Bb[(wr + mt * 16 + kg * 4 + q) * 72 + wc + nt * 16 + ln15] = gmb[mt][nt][q];
  __syncthreads();
  // ---- Phase B: Y[t][p] = sum_s Gm[t,s] X[s,p] ; Phase C: Z[t][p] = sum_n C[t,n] h[p,n]
  f32x4 accY[2][2] = {}, accZ[2][2] = {};
  #pragma unroll
  for (int ks = 0; ks < 2; ks++) {
    short8v af[2], bq[2];
    #pragma unroll
    for (int mt = 0; mt < 2; mt++)
      af[mt] = *reinterpret_cast<const short8v*>(&Bb[(wr + mt * 16 + ln15) * 72 + ks * 32 + kg * 8]);
    #pragma unroll
    for (int nt = 0; nt < 2; nt++)
      bq[nt] = *reinterpret_cast<const short8v*>(&XT[(wc + nt * 16 + ln15) * 72 + ks * 32 + kg * 8]);
    #pragma unroll
    for (int mt = 0; mt < 2; mt++)
      #pragma unroll
      for (int nt = 0; nt < 2; nt++)
        accY[mt][nt] = __builtin_amdgcn_mfma_f32_16x16x32_bf16(af[mt], bq[nt], accY[mt][nt], 0, 0, 0);
  }
  if (c > 0) {
    #pragma unroll
    for (int ks = 0; ks < 2; ks++) {
      short8v af[2], bq[2];
      #pragma unroll
      for (int mt = 0; mt < 2; mt++)
        af[mt] = *reinterpret_cast<const short8v*>(&Cb[(wr + mt * 16 + ln15) * 72 + ks * 32 + kg * 8]);
      #pragma unroll
      for (int nt = 0; nt < 2; nt++)
        bq[nt] = *reinterpret_cast<const short8v*>(&hb[(wc + nt * 16 + ln15) * 72 + ks * 32 + kg * 8]);
      #pragma unroll
      for (int mt = 0; mt < 2; mt++)
        #pragma unroll
        for (int nt = 0; nt < 2; nt++)
          accZ[mt][nt] = __builtin_amdgcn_mfma_f32_16x16x32_bf16(af[mt], bq[nt], accZ[mt][nt], 0, 0, 0);
    }
  }
  float Dv = Dvec[h];
  #pragma unroll
  for (int mt = 0; mt < 2; mt++)
    #pragma unroll
    for (int q = 0; q < 4; q++) {
      int t = wr + mt * 16 + kg * 4 + q;
      float wB = expf(Cum[t]);
      const unsigned short* xp = xbc + (row0 + t) * conv_dim + (h << 6);
      unsigned short* yp = y + (row0 + t) * d_inner + (h << 6);
      #pragma unroll
      for (int nt = 0; nt < 2; nt++) {
        int p = wc + nt * 16 + ln15;
        yp[p] = f2bf(accY[mt][nt][q] + accZ[mt][nt][q] * wB + bf2f(xp[p]) * Dv);
      }
    }
}

// --- wave-per-row: g = y*silu(z); g *= rsqrt(mean(g^2)+eps)*rms_w; bf16 out ---
template <int CPL>
__global__ __launch_bounds__(256) void gate_rms_bf16(const unsigned short* __restrict__ y,
                                                     const unsigned short* __restrict__ z,
                                                     const float* __restrict__ rmsw,
                                                     unsigned short* __restrict__ ab,
                                                     int d_inner) {
  long row = (long)blockIdx.x * 4 + (threadIdx.x >> 6);
  int lane = threadIdx.x & 63;
  const unsigned short* yr = y + row * d_inner;
  const unsigned short* zr = z + row * d_inner;
  float g[CPL];
  float ss = 0.f;
  #pragma unroll
  for (int j = 0; j < CPL / 4; j++) {
    int c = j * 256 + lane * 4;
    ushort4 yv = *reinterpret_cast<const ushort4*>(&yr[c]);
    ushort4 zv = *reinterpret_cast<const ushort4*>(&zr[c]);
    float g0 = bf2f(yv.x) * siluf(bf2f(zv.x));
    float g1 = bf2f(yv.y) * siluf(bf2f(zv.y));
    float g2 = bf2f(yv.z) * siluf(bf2f(zv.z));
    float g3 = bf2f(yv.w) * siluf(bf2f(zv.w));
    g[j * 4 + 0] = g0; g[j * 4 + 1] = g1; g[j * 4 + 2] = g2; g[j * 4 + 3] = g3;
    ss += g0 * g0 + g1 * g1 + g2 * g2 + g3 * g3;
  }
  #pragma unroll
  for (int o = 32; o; o >>= 1) ss += __shfl_xor(ss, o);
  float inv = rsqrtf(ss / (float)d_inner + EPSV);
  #pragma unroll
  for (int j = 0; j < CPL / 4; j++) {
    int c = j * 256 + lane * 4;
    float4 wv = *reinterpret_cast<const float4*>(&rmsw[c]);
    ushort4 o;
    o.x = f2bf(g[j * 4 + 0] * inv * wv.x);
    o.y = f2bf(g[j * 4 + 1] * inv * wv.y);
    o.z = f2bf(g[j * 4 + 2] * inv * wv.z);
    o.w = f2bf(g[j * 4 + 3] * inv * wv.w);
    *reinterpret_cast<ushort4*>(&ab[row * d_inner + c]) = o;
  }
}

extern "C" void kernel_launch(void* const* d_in, const int* in_sizes, int n_in,
                              void* d_out, int out_size, void* d_ws,
                              size_t ws_size, hipStream_t stream) {
  const float* x        = (const float*)d_in[0];
  const float* ln_spa_w = (const float*)d_in[1];
  const float* ln_spa_b = (const float*)d_in[2];
  const float* ln_spe_w = (const float*)d_in[3];
  const float* ln_spe_b = (const float*)d_in[4];
  const float* spa_W_in   = (const float*)d_in[5];
  const float* spa_conv_w = (const float*)d_in[6];
  const float* spa_conv_b = (const float*)d_in[7];
  const float* spa_dt_b   = (const float*)d_in[8];
  const float* spa_A_log  = (const float*)d_in[9];
  const float* spa_D      = (const float*)d_in[10];
  const float* spa_rms_w  = (const float*)d_in[11];
  const float* spa_W_out  = (const float*)d_in[12];
  const float* spe_W_in   = (const float*)d_in[13];
  const float* spe_conv_w = (const float*)d_in[14];
  const float* spe_conv_b = (const float*)d_in[15];
  const float* spe_dt_b   = (const float*)d_in[16];
  const float* spe_A_log  = (const float*)d_in[17];
  const float* spe_D      = (const float*)d_in[18];
  const float* spe_rms_w  = (const float*)d_in[19];
  const float* spe_W_out  = (const float*)d_in[20];
  float* out = (float*)d_out;

  float* ws = (float*)d_ws;
  // layout (floats) — same proven 63.9 MB budget
  float* xspa   = ws;                 // 1,048,576
  unsigned short* z = (unsigned short*)(ws + 1048576);   // ≤2,097,152 u16
  unsigned short* xbcraw = (unsigned short*)(ws + 3145728);  // raw xBC bf16 (dead after conv)
  float* Sc     = ws + 3145728;       // chunk states overlay (after xbcraw dies)
  float* dtraw  = ws + 6291456;       // 32,768 (later Aprod)
  unsigned short* cv = (unsigned short*)(ws + 6324224);
  float* dtb    = ws + 9469952;       // 32,768 (also spe LN partials)
  float* la     = ws + 9502720;       // 32,768
  unsigned short* yb = (unsigned short*)(ws + 9535488);
  unsigned short* Abf     = (unsigned short*)(ws + 11634688);
  unsigned short* Wt_spai = (unsigned short*)(ws + 12683264);
  unsigned short* Wt_spao = (unsigned short*)(ws + 12724480);
  unsigned short* Wt_spei = (unsigned short*)(ws + 12740864);
  unsigned short* Wt_speo = (unsigned short*)(ws + 14919936);

  // 1. fused prologue: spa LN (blocks 0..4095) + all weight transposes
  hipLaunchKernelGGL(ln_wt_fused, dim3(5710), dim3(256), 0, stream,
                     x, ln_spa_w, ln_spa_b, Abf,
                     spa_W_in, Wt_spai, spa_W_out, Wt_spao,
                     spe_W_in, Wt_spei, spe_W_out, Wt_speo);

  // ================= spatial mamba (L=1024, d_model=128) =================
  hipLaunchKernelGGL(gemm128_split, dim3(6, 64), dim3(256), 0, stream,
                     Abf, Wt_spai, z, xbcraw, dtraw,
                     8192, 644, 128, 256, 640);
  hipLaunchKernelGGL(conv_dtda, dim3(3200), dim3(256), 0, stream,
                     xbcraw, spa_conv_w, spa_conv_b, cv,
                     dtraw, spa_dt_b, spa_A_log, dtb, la,
                     8, 1024, 384, 4, 32768, 3072);
  hipLaunchKernelGGL(ssd_local, dim3(480), dim3(256), 0, stream,
                     cv, dtb, la, Sc, dtraw, 16, 15, 4, 384, 256);
  hipLaunchKernelGGL(ssd_out, dim3(512), dim3(256), 0, stream,
                     cv, dtb, la, Sc, dtraw, spa_D, yb, 16, 4, 384, 256);
  hipLaunchKernelGGL((gate_rms_bf16<4>), dim3(2048), dim3(256), 0, stream,
                     yb, z, spa_rms_w, Abf, 256);
  hipLaunchKernelGGL(gemm_mfma1, dim3(2, 128), dim3(256), 0, stream,
                     Abf, Wt_spao, x, xspa, dtb, 8192, 128, 256);

  // ================= spectral mamba (L=128, d_model=1024) =================
  hipLaunchKernelGGL(spe_normT, dim3(2, 8, 8), dim3(256), 0, stream,
                     xspa, dtb, ln_spe_w, ln_spe_b, Abf);
  hipLaunchKernelGGL(gemm128_split, dim3(34, 8), dim3(256), 0, stream,
                     Abf, Wt_spei, z, xbcraw, dtraw,
                     1024, 4256, 1024, 2048, 4224);
  hipLaunchKernelGGL(conv_dtda, dim3(2304), dim3(256), 0, stream,
                     xbcraw, spe_conv_w, spe_conv_b, cv,
                     dtraw, spe_dt_b, spe_A_log, dtb, la,
                     8, 128, 2176, 32, 32768, 2176);
  hipLaunchKernelGGL(ssd_local, dim3(256), dim3(256), 0, stream,
                     cv, dtb, la, Sc, dtraw, 2, 1, 32, 2176, 2048);
  hipLaunchKernelGGL(ssd_out, dim3(512), dim3(256), 0, stream,
                     cv, dtb, la, Sc, dtraw, spe_D, yb, 2, 32, 2176, 2048);
  hipLaunchKernelGGL((gate_rms_bf16<32>), dim3(256), dim3(256), 0, stream,
                     yb, z, spe_rms_w, Abf, 2048);
  hipLaunchKernelGGL(gemm128x64_t, dim3(16, 8), dim3(256), 0, stream,
                     Abf, Wt_speo, xspa, out, 1024, 1024, 2048);
}

// Round 14
// 163.813 us; speedup vs baseline: 1.3670x; 1.0173x over previous
//
#include <hip/hip_runtime.h>
#include <hip/hip_bf16.h>

#define EPSV 1e-5f

typedef __attribute__((ext_vector_type(8))) short short8v;   // 8 bf16 in 4 VGPRs
typedef __attribute__((ext_vector_type(4))) float f32x4;

__device__ inline unsigned short f2bf(float f) {
  __hip_bfloat16 h = __float2bfloat16(f);
  return *reinterpret_cast<unsigned short*>(&h);
}

__device__ inline float bf2f(unsigned short u) {
  return __uint_as_float(((unsigned int)u) << 16);
}

__device__ inline float siluf(float x) { return x / (1.f + expf(-x)); }

// direct global->LDS 16B async copy (lane-linear dest: base + lane*16)
__device__ inline void gload_lds16(const void* g, void* l) {
  __builtin_amdgcn_global_load_lds(
      (const __attribute__((address_space(1))) void*)g,
      (__attribute__((address_space(3))) void*)l, 16, 0, 0);
}

// ---------------- block-wide sum (256 threads = 4 waves) ----------------
__device__ inline float block_sum(float v, float* lds) {
  #pragma unroll
  for (int o = 32; o; o >>= 1) v += __shfl_xor(v, o);
  int tid = threadIdx.x;
  if ((tid & 63) == 0) lds[tid >> 6] = v;
  __syncthreads();
  float r = lds[0] + lds[1] + lds[2] + lds[3];
  __syncthreads();
  return r;
}

// inclusive prefix sum over 64 lanes (call from wave 0 only)
__device__ inline float wave_prefix_incl(float v, int lane) {
  #pragma unroll
  for (int o = 1; o < 64; o <<= 1) {
    float u = __shfl_up(v, o);
    if (lane >= o) v += u;
  }
  return v;
}

// ------- weight transpose tile W[K][N] -> Wt[N][K] bf16 -------
__device__ inline void wtconv_tile(const float* __restrict__ W,
                                   unsigned short* __restrict__ Wt,
                                   int K, int N, int bx, int by) {
  __shared__ float tile[64][65];
  int n0 = bx * 64, k0 = by * 64;
  int tid = threadIdx.x;
  int r = tid >> 4, c4 = (tid & 15) * 4;
  #pragma unroll
  for (int i = 0; i < 4; i++) {
    int kk = r + i * 16;
    float4 v = make_float4(0.f, 0.f, 0.f, 0.f);
    if (n0 + c4 < N) v = *reinterpret_cast<const float4*>(&W[(long)(k0 + kk) * N + n0 + c4]);
    tile[kk][c4] = v.x; tile[kk][c4 + 1] = v.y; tile[kk][c4 + 2] = v.z; tile[kk][c4 + 3] = v.w;
  }
  __syncthreads();
  #pragma unroll
  for (int i = 0; i < 4; i++) {
    int nl = r + i * 16;
    if (n0 + nl < N) {
      ushort4 o;
      o.x = f2bf(tile[c4 + 0][nl]);
      o.y = f2bf(tile[c4 + 1][nl]);
      o.z = f2bf(tile[c4 + 2][nl]);
      o.w = f2bf(tile[c4 + 3][nl]);
      *reinterpret_cast<ushort4*>(&Wt[(long)(n0 + nl) * K + k0 + c4]) = o;
    }
  }
}

// ---- fused prologue: spa LN (2 rows/block, bf16 out) + all 4 weight transposes ----
__global__ __launch_bounds__(256) void ln_wt_fused(const float* __restrict__ x,
                                                   const float* __restrict__ w,
                                                   const float* __restrict__ bb,
                                                   unsigned short* __restrict__ outA,
                                                   const float* __restrict__ W0,
                                                   unsigned short* __restrict__ T0,
                                                   const float* __restrict__ W1,
                                                   unsigned short* __restrict__ T1,
                                                   const float* __restrict__ W2,
                                                   unsigned short* __restrict__ T2,
                                                   const float* __restrict__ W3,
                                                   unsigned short* __restrict__ T3) {
  int id = blockIdx.x;
  if (id < 4096) {
    int tid = threadIdx.x;
    __shared__ float lds[4];
    long row = (long)id * 2 + (tid >> 7);
    int lane = tid & 127;
    int base = (tid >> 7) << 1;
    float v = x[row * 128 + lane];
    float s = v;
    #pragma unroll
    for (int o = 32; o; o >>= 1) s += __shfl_xor(s, o);
    if ((tid & 63) == 0) lds[tid >> 6] = s;
    __syncthreads();
    float m = (lds[base] + lds[base + 1]) * (1.f / 128.f);
    float d = v - m;
    float q = d * d;
    #pragma unroll
    for (int o = 32; o; o >>= 1) q += __shfl_xor(q, o);
    __syncthreads();
    if ((tid & 63) == 0) lds[tid >> 6] = q;
    __syncthreads();
    float inv = rsqrtf((lds[base] + lds[base + 1]) * (1.f / 128.f) + EPSV);
    outA[row * 128 + lane] = f2bf(d * inv * w[lane] + bb[lane]);
  } else {
    id -= 4096;
    if (id < 22)        { int r = id;        wtconv_tile(W0, T0, 128,  644,  r % 11, r / 11); }
    else if (id < 30)   { int r = id - 22;   wtconv_tile(W1, T1, 256,  128,  r % 2,  r / 2); }
    else if (id < 1102) { int r = id - 30;   wtconv_tile(W2, T2, 1024, 4256, r % 67, r / 67); }
    else                { int r = id - 1102; wtconv_tile(W3, T3, 2048, 1024, r % 16, r / 16); }
  }
}

// ---- spe LN pass 2: finalize per-(b,ch) stats from GEMM partials,
//      normalize + transpose, emit bf16. part2: float2[(by*2+bx)*64 + cl]
__global__ __launch_bounds__(256) void spe_normT(const float* __restrict__ xspa,
                                                 const float* __restrict__ part2,
                                                 const float* __restrict__ w,
                                                 const float* __restrict__ bb,
                                                 unsigned short* __restrict__ out) {
  __shared__ float tile[128][65];
  int c0 = blockIdx.x * 64, l0 = blockIdx.y * 128, b = blockIdx.z;
  int tid = threadIdx.x;
  int rr = tid >> 4, c4 = (tid & 15) * 4;
  #pragma unroll
  for (int p = 0; p < 8; p++) {
    int l = rr + p * 16;
    f32x4 v = *reinterpret_cast<const f32x4*>(
        &xspa[((long)b * 1024 + l0 + l) * 128 + c0 + c4]);
    tile[l][c4] = v[0]; tile[l][c4 + 1] = v[1];
    tile[l][c4 + 2] = v[2]; tile[l][c4 + 3] = v[3];
  }
  __syncthreads();
  int ch = tid >> 2, lq = tid & 3;
  int gc = c0 + ch;
  int bx = gc >> 6, cl = gc & 63;
  float ssum = 0.f, qsum = 0.f;
  #pragma unroll
  for (int sub = 0; sub < 16; sub++) {
    int by = b * 16 + sub;
    float2 pq = *reinterpret_cast<const float2*>(&part2[(((by * 2 + bx) * 64) + cl) * 2]);
    ssum += pq.x; qsum += pq.y;
  }
  float mm = ssum * (1.f / 1024.f);
  float rstd = rsqrtf(qsum * (1.f / 1024.f) - mm * mm + EPSV);
  #pragma unroll
  for (int j = 0; j < 8; j++) {
    int qidx = lq + j * 4;
    int l = qidx * 4;
    float4 wv = *reinterpret_cast<const float4*>(&w[l0 + l]);
    float4 bv = *reinterpret_cast<const float4*>(&bb[l0 + l]);
    ushort4 o;
    o.x = f2bf((tile[l + 0][ch] - mm) * rstd * wv.x + bv.x);
    o.y = f2bf((tile[l + 1][ch] - mm) * rstd * wv.y + bv.y);
    o.z = f2bf((tile[l + 2][ch] - mm) * rstd * wv.z + bv.z);
    o.w = f2bf((tile[l + 3][ch] - mm) * rstd * wv.w + bv.w);
    *reinterpret_cast<ushort4*>(&out[((long)b * 128 + c0 + ch) * 1024 + l0 + l]) = o;
  }
}

// ------- 128x128-tile bf16 MFMA GEMM, DOUBLE-BUFFERED gload_lds staging -------
// column-split epilogue: c<c1 -> zout (bf16, ld c1); c<c2 -> o2 (bf16); else o3 (f32)
__global__ __launch_bounds__(256) void gemm128_split(const unsigned short* __restrict__ A,
                                                     const unsigned short* __restrict__ Bt,
                                                     unsigned short* __restrict__ zout,
                                                     unsigned short* __restrict__ o2,
                                                     float* __restrict__ o3,
                                                     int M, int N, int K,
                                                     int c1, int c2) {
  __shared__ unsigned short As[2][128 * 32];   // linear, no pad (gload_lds dest)
  __shared__ unsigned short Bs[2][128 * 32];
  int tid = threadIdx.x;
  int lane = tid & 63, w = tid >> 6;
  int wr = (w >> 1) * 64, wc = (w & 1) * 64;
  int ln15 = lane & 15, kg = lane >> 4;
  int rowBase = blockIdx.y * 128, colBase = blockIdx.x * 128;
  int srow = w * 32 + (lane >> 2);
  int scol = (lane & 3) * 8;
  f32x4 acc[4][4] = {};
  auto stage = [&](int buf, int k0) {
    gload_lds16(&A[(long)(rowBase + srow) * K + k0 + scol], &As[buf][(w * 32) * 32]);
    gload_lds16(&A[(long)(rowBase + srow + 16) * K + k0 + scol], &As[buf][(w * 32 + 16) * 32]);
    gload_lds16(&Bt[(long)(colBase + srow) * K + k0 + scol], &Bs[buf][(w * 32) * 32]);
    gload_lds16(&Bt[(long)(colBase + srow + 16) * K + k0 + scol], &Bs[buf][(w * 32 + 16) * 32]);
  };
  stage(0, 0);
  __syncthreads();           // vmcnt(0) drain by compiler: buf0 ready
  int cur = 0;
  for (int k0 = 0; k0 < K; k0 += 32) {
    if (k0 + 32 < K) stage(cur ^ 1, k0 + 32);   // in flight during compute
    short8v af[4], bfr[4];
    #pragma unroll
    for (int mt = 0; mt < 4; mt++)
      af[mt] = *reinterpret_cast<const short8v*>(&As[cur][(wr + mt * 16 + ln15) * 32 + kg * 8]);
    #pragma unroll
    for (int nt = 0; nt < 4; nt++)
      bfr[nt] = *reinterpret_cast<const short8v*>(&Bs[cur][(wc + nt * 16 + ln15) * 32 + kg * 8]);
    #pragma unroll
    for (int mt = 0; mt < 4; mt++)
      #pragma unroll
      for (int nt = 0; nt < 4; nt++)
        acc[mt][nt] = __builtin_amdgcn_mfma_f32_16x16x32_bf16(af[mt], bfr[nt], acc[mt][nt], 0, 0, 0);
    __syncthreads();         // drains vmcnt(0): next buffer ready, cur free
    cur ^= 1;
  }
  #pragma unroll
  for (int mt = 0; mt < 4; mt++)
    #pragma unroll
    for (int nt = 0; nt < 4; nt++)
      #pragma unroll
      for (int q = 0; q < 4; q++) {
        int r = rowBase + wr + mt * 16 + kg * 4 + q;
        int c = colBase + wc + nt * 16 + ln15;
        if (c < N) {
          float v = acc[mt][nt][q];
          if (c < c1) zout[(long)r * c1 + c] = f2bf(v);
          else if (c < c2) o2[(long)r * (c2 - c1) + (c - c1)] = f2bf(v);
          else o3[(long)r * (N - c2) + (c - c2)] = v;
        }
      }
}

// ------- 128(rows)x64(cols)-tile GEMM, dbuf gload_lds, transposed-add -------
__global__ __launch_bounds__(256) void gemm128x64_t(const unsigned short* __restrict__ A,
                                                    const unsigned short* __restrict__ Bt,
                                                    const float* __restrict__ R,
                                                    float* __restrict__ out,
                                                    int M, int N, int K) {
  __shared__ unsigned short As[2][128 * 32];
  __shared__ unsigned short Bs[2][64 * 32];
  int tid = threadIdx.x;
  int lane = tid & 63, w = tid >> 6;
  int wr = w * 32;
  int ln15 = lane & 15, kg = lane >> 4;
  int rowBase = blockIdx.y * 128, colBase = blockIdx.x * 64;
  int arow = w * 32 + (lane >> 2);
  int brow = w * 16 + (lane >> 2);
  int scol = (lane & 3) * 8;
  f32x4 acc[2][4] = {};
  auto stage = [&](int buf, int k0) {
    gload_lds16(&A[(long)(rowBase + arow) * K + k0 + scol], &As[buf][(w * 32) * 32]);
    gload_lds16(&A[(long)(rowBase + arow + 16) * K + k0 + scol], &As[buf][(w * 32 + 16) * 32]);
    gload_lds16(&Bt[(long)(colBase + brow) * K + k0 + scol], &Bs[buf][(w * 16) * 32]);
  };
  stage(0, 0);
  __syncthreads();
  int cur = 0;
  for (int k0 = 0; k0 < K; k0 += 32) {
    if (k0 + 32 < K) stage(cur ^ 1, k0 + 32);
    short8v af[2], bfr[4];
    #pragma unroll
    for (int mt = 0; mt < 2; mt++)
      af[mt] = *reinterpret_cast<const short8v*>(&As[cur][(wr + mt * 16 + ln15) * 32 + kg * 8]);
    #pragma unroll
    for (int nt = 0; nt < 4; nt++)
      bfr[nt] = *reinterpret_cast<const short8v*>(&Bs[cur][(nt * 16 + ln15) * 32 + kg * 8]);
    #pragma unroll
    for (int mt = 0; mt < 2; mt++)
      #pragma unroll
      for (int nt = 0; nt < 4; nt++)
        acc[mt][nt] = __builtin_amdgcn_mfma_f32_16x16x32_bf16(af[mt], bfr[nt], acc[mt][nt], 0, 0, 0);
    __syncthreads();
    cur ^= 1;
  }
  #pragma unroll
  for (int mt = 0; mt < 2; mt++)
    #pragma unroll
    for (int nt = 0; nt < 4; nt++)
      #pragma unroll
      for (int q = 0; q < 4; q++) {
        int r = rowBase + wr + mt * 16 + kg * 4 + q;
        int c = colBase + nt * 16 + ln15;
        int bb = r >> 7, ch = r & 127;
        out[(long)bb * 131072 + (long)c * 128 + ch] =
            acc[mt][nt][q] + R[((long)bb * 1024 + c) * 128 + ch];
      }
}

// ---------------- 64x64-tile bf16 MFMA GEMM (spa W_out epilogue) ----------------
// out = v + R; also emits deterministic per-block column {sum,sum^2} partials.
__global__ __launch_bounds__(256) void gemm_mfma1(const unsigned short* __restrict__ A,
                                                  const unsigned short* __restrict__ Bt,
                                                  const float* __restrict__ R,
                                                  float* __restrict__ out,
                                                  float* __restrict__ part2,
                                                  int M, int N, int K) {
  __shared__ unsigned short As[64 * 40];
  __shared__ unsigned short Bs[64 * 40];
  int tid = threadIdx.x;
  int lane = tid & 63, w = tid >> 6;
  int wr = (w >> 1) * 32, wc = (w & 1) * 32;
  int ln15 = lane & 15, kg = lane >> 4;
  int rowBase = blockIdx.y * 64, colBase = blockIdx.x * 64;
  int sm = tid >> 2, skb = (tid & 3) * 8;
  f32x4 acc[2][2] = {};
  for (int k0 = 0; k0 < K; k0 += 32) {
    {
      short8v av = *reinterpret_cast<const short8v*>(&A[(long)(rowBase + sm) * K + k0 + skb]);
      *reinterpret_cast<short8v*>(&As[sm * 40 + skb]) = av;
      int n = colBase + sm;
      short8v bv = {0, 0, 0, 0, 0, 0, 0, 0};
      if (n < N) bv = *reinterpret_cast<const short8v*>(&Bt[(long)n * K + k0 + skb]);
      *reinterpret_cast<short8v*>(&Bs[sm * 40 + skb]) = bv;
    }
    __syncthreads();
    short8v af[2], bfr[2];
    #pragma unroll
    for (int mt = 0; mt < 2; mt++)
      af[mt] = *reinterpret_cast<const short8v*>(&As[(wr + mt * 16 + ln15) * 40 + kg * 8]);
    #pragma unroll
    for (int nt = 0; nt < 2; nt++)
      bfr[nt] = *reinterpret_cast<const short8v*>(&Bs[(wc + nt * 16 + ln15) * 40 + kg * 8]);
    #pragma unroll
    for (int mt = 0; mt < 2; mt++)
      #pragma unroll
      for (int nt = 0; nt < 2; nt++)
        acc[mt][nt] = __builtin_amdgcn_mfma_f32_16x16x32_bf16(af[mt], bfr[nt], acc[mt][nt], 0, 0, 0);
    __syncthreads();
  }
  float sC[2] = {0.f, 0.f}, qC[2] = {0.f, 0.f};
  #pragma unroll
  for (int mt = 0; mt < 2; mt++)
    #pragma unroll
    for (int nt = 0; nt < 2; nt++)
      #pragma unroll
      for (int q = 0; q < 4; q++) {
        int r = rowBase + wr + mt * 16 + kg * 4 + q;
        int c = colBase + wc + nt * 16 + ln15;
        float v = acc[mt][nt][q] + R[(long)r * N + c];
        out[(long)r * N + c] = v;
        sC[nt] += v;
        qC[nt] += v * v;
      }
  __shared__ float redS[4][32], redQ[4][32];
  #pragma unroll
  for (int nt = 0; nt < 2; nt++) {
    sC[nt] += __shfl_xor(sC[nt], 16);
    sC[nt] += __shfl_xor(sC[nt], 32);
    qC[nt] += __shfl_xor(qC[nt], 16);
    qC[nt] += __shfl_xor(qC[nt], 32);
  }
  if (lane < 16) {
    redS[w][ln15] = sC[0];       redQ[w][ln15] = qC[0];
    redS[w][16 + ln15] = sC[1];  redQ[w][16 + ln15] = qC[1];
  }
  __syncthreads();
  if (tid < 64) {
    int c = tid;
    int grp = c >> 5, lo = c & 31;
    float ss = redS[grp][lo] + redS[grp + 2][lo];
    float qq = redQ[grp][lo] + redQ[grp + 2][lo];
    long slot = ((long)(blockIdx.y * 2 + blockIdx.x) * 64 + c) * 2;
    part2[slot] = ss;
    part2[slot + 1] = qq;
  }
}

// ---- fused: causal depthwise conv (bf16 in, bf16 out) + bias + SiLU | dt/la ----
__global__ __launch_bounds__(256) void conv_dtda(const unsigned short* __restrict__ zx,
                                                 const float* __restrict__ cw,
                                                 const float* __restrict__ cb,
                                                 unsigned short* __restrict__ cout,
                                                 const float* __restrict__ raw,
                                                 const float* __restrict__ dtbias,
                                                 const float* __restrict__ alog,
                                                 float* __restrict__ dt,
                                                 float* __restrict__ la,
                                                 int Bb, int L, int conv_dim,
                                                 int H, int rowsH, int convBlocks) {
  int tid = threadIdx.x;
  if ((int)blockIdx.x < convBlocks) {
    long idx4 = (long)blockIdx.x * 256 + tid;
    int nch4 = conv_dim >> 2;
    long total4 = (long)Bb * L * nch4;
    if (idx4 >= total4) return;
    int ch = (int)(idx4 % nch4) << 2;
    long rt = idx4 / nch4;
    int t = (int)(rt % L);
    int b = (int)(rt / L);
    f32x4 acc = *reinterpret_cast<const f32x4*>(&cb[ch]);
    #pragma unroll
    for (int k = 0; k < 4; k++) {
      int tt = t + k - 3;
      if (tt >= 0) {
        f32x4 wv = *reinterpret_cast<const f32x4*>(&cw[k * conv_dim + ch]);
        ushort4 zu = *reinterpret_cast<const ushort4*>(
            &zx[((long)b * L + tt) * conv_dim + ch]);
        acc[0] += wv[0] * bf2f(zu.x);
        acc[1] += wv[1] * bf2f(zu.y);
        acc[2] += wv[2] * bf2f(zu.z);
        acc[3] += wv[3] * bf2f(zu.w);
      }
    }
    ushort4 o;
    o.x = f2bf(siluf(acc[0])); o.y = f2bf(siluf(acc[1]));
    o.z = f2bf(siluf(acc[2])); o.w = f2bf(siluf(acc[3]));
    *reinterpret_cast<ushort4*>(&cout[rt * conv_dim + ch]) = o;
  } else {
    int idx = ((int)blockIdx.x - convBlocks) * 256 + tid;
    if (idx >= rowsH) return;
    int h = idx % H;
    float v = raw[idx] + dtbias[h];
    float sp = (v > 20.f) ? v : log1pf(expf(v));
    dt[idx] = sp;
    la[idx] = -expf(alog[h]) * sp;
  }
}

// ===================== chunked SSD (T=64 per chunk), MFMA, bf16 inputs =====================
// K1: S[p,n] = sum_t (Ws[t]*X[t,p]) * B[t,n]
__global__ __launch_bounds__(256) void ssd_local(const unsigned short* __restrict__ xbc,
                                                 const float* __restrict__ dtv,
                                                 const float* __restrict__ la,
                                                 float* __restrict__ Sc,
                                                 float* __restrict__ Aprod,
                                                 int NC, int nc_launch, int H,
                                                 int conv_dim, int d_inner) {
  int blk = blockIdx.x;
  int c = blk % nc_launch, bh = blk / nc_launch;
  int h = bh % H, b = bh / H;
  int tid = threadIdx.x;
  long row0 = ((long)(b * NC + c)) * 64;
  __shared__ unsigned short XpT[64 * 72];   // [p][t] = bf16(Ws[t]*X[t][p])
  __shared__ unsigned short BT[64 * 72];    // [n][t]
  __shared__ float Ws[64];
  int tq = tid >> 4, cq = (tid & 15) << 2;
  ushort4 xr[4], br[4];
  #pragma unroll
  for (int i = 0; i < 4; i++) {
    int t = tq + i * 16;
    const unsigned short* rp = xbc + (row0 + t) * conv_dim;
    xr[i] = *reinterpret_cast<const ushort4*>(rp + (h << 6) + cq);
    br[i] = *reinterpret_cast<const ushort4*>(rp + d_inner + cq);
  }
  if (tid < 64) {
    long r = (row0 + tid) * H + h;
    float cum = wave_prefix_incl(la[r], tid);
    float cT = __shfl(cum, 63);
    Ws[tid] = expf(cT - cum) * dtv[r];
    if (tid == 63) Aprod[(long)bh * NC + c] = expf(cT);
  }
  __syncthreads();
  #pragma unroll
  for (int i = 0; i < 4; i++) {
    int t = tq + i * 16;
    float wv = Ws[t];
    XpT[(cq + 0) * 72 + t] = f2bf(wv * bf2f(xr[i].x));
    XpT[(cq + 1) * 72 + t] = f2bf(wv * bf2f(xr[i].y));
    XpT[(cq + 2) * 72 + t] = f2bf(wv * bf2f(xr[i].z));
    XpT[(cq + 3) * 72 + t] = f2bf(wv * bf2f(xr[i].w));
    BT[(cq + 0) * 72 + t] = br[i].x;
    BT[(cq + 1) * 72 + t] = br[i].y;
    BT[(cq + 2) * 72 + t] = br[i].z;
    BT[(cq + 3) * 72 + t] = br[i].w;
  }
  __syncthreads();
  int lane = tid & 63, wv2 = tid >> 6;
  int wr = (wv2 >> 1) * 32, wc = (wv2 & 1) * 32;
  int ln15 = lane & 15, kg = lane >> 4;
  f32x4 acc[2][2] = {};
  #pragma unroll
  for (int ks = 0; ks < 2; ks++) {
    short8v af[2], bq[2];
    #pragma unroll
    for (int mt = 0; mt < 2; mt++)
      af[mt] = *reinterpret_cast<const short8v*>(&XpT[(wr + mt * 16 + ln15) * 72 + ks * 32 + kg * 8]);
    #pragma unroll
    for (int nt = 0; nt < 2; nt++)
      bq[nt] = *reinterpret_cast<const short8v*>(&BT[(wc + nt * 16 + ln15) * 72 + ks * 32 + kg * 8]);
    #pragma unroll
    for (int mt = 0; mt < 2; mt++)
      #pragma unroll
      for (int nt = 0; nt < 2; nt++)
        acc[mt][nt] = __builtin_amdgcn_mfma_f32_16x16x32_bf16(af[mt], bq[nt], acc[mt][nt], 0, 0, 0);
  }
  float* base = Sc + ((long)bh * NC + c) * 4096;
  #pragma unroll
  for (int mt = 0; mt < 2; mt++)
    #pragma unroll
    for (int nt = 0; nt < 2; nt++)
      #pragma unroll
      for (int q = 0; q < 4; q++) {
        int p = wr + mt * 16 + kg * 4 + q;
        int n = wc + nt * 16 + ln15;
        base[p * 64 + n] = acc[mt][nt][q];
      }
}

// K3: MFMA phases: G=C·B^T (masked) ; Y=Gm·X ; Z=C·h^T ; y = Y + e^cum·Z + D·x (bf16 y)
__global__ __launch_bounds__(256) void ssd_out(const unsigned short* __restrict__ xbc,
                                               const float* __restrict__ dtv,
                                               const float* __restrict__ la,
                                               const float* __restrict__ Sc,
                                               const float* __restrict__ Aprod,
                                               const float* __restrict__ Dvec,
                                               unsigned short* __restrict__ y,
                                               int NC, int H, int conv_dim,
                                               int d_inner) {
  int blk = blockIdx.x;
  int c = blk % NC, bh = blk / NC;
  int h = bh % H, b = bh / H;
  int tid = threadIdx.x;
  long row0 = ((long)(b * NC + c)) * 64;
  __shared__ unsigned short Cb[64 * 72];   // C[t][n]
  __shared__ unsigned short Bb[64 * 72];   // B[s][n]  -> after phase A: Gm[t][s]
  __shared__ unsigned short XT[64 * 72];   // X^T[p][s]
  __shared__ unsigned short hb[64 * 72];   // hprev[p][n]
  __shared__ float Cum[64], Dt[64];
  int tq = tid >> 4, cq = (tid & 15) << 2;
  #pragma unroll
  for (int i = 0; i < 4; i++) {
    int t = tq + i * 16;
    const unsigned short* rp = xbc + (row0 + t) * conv_dim;
    ushort4 cu = *reinterpret_cast<const ushort4*>(rp + d_inner + 64 + cq);
    ushort4 bu = *reinterpret_cast<const ushort4*>(rp + d_inner + cq);
    ushort4 xu = *reinterpret_cast<const ushort4*>(rp + (h << 6) + cq);
    *reinterpret_cast<ushort4*>(&Cb[t * 72 + cq]) = cu;
    *reinterpret_cast<ushort4*>(&Bb[t * 72 + cq]) = bu;
    XT[(cq + 0) * 72 + t] = xu.x;
    XT[(cq + 1) * 72 + t] = xu.y;
    XT[(cq + 2) * 72 + t] = xu.z;
    XT[(cq + 3) * 72 + t] = xu.w;
  }
  // carry fold in fp32 (bit-identical order), then stage h[p][n] as bf16
  if (c > 0) {
    f32x4 hreg[4] = {};
    const float* ap = Aprod + (long)bh * NC;
    for (int j = 0; j < c; j++) {
      const float* sb = Sc + ((long)bh * NC + j) * 4096;
      float a = ap[j];
      #pragma unroll
      for (int i = 0; i < 4; i++) {
        int p = tq + i * 16;
        f32x4 sv = *reinterpret_cast<const f32x4*>(&sb[p * 64 + cq]);
        hreg[i] = hreg[i] * a + sv;
      }
    }
    #pragma unroll
    for (int i = 0; i < 4; i++) {
      int p = tq + i * 16;
      ushort4 ho;
      ho.x = f2bf(hreg[i][0]); ho.y = f2bf(hreg[i][1]);
      ho.z = f2bf(hreg[i][2]); ho.w = f2bf(hreg[i][3]);
      *reinterpret_cast<ushort4*>(&hb[p * 72 + cq]) = ho;
    }
  }
  if (tid < 64) {
    long r = (row0 + tid) * H + h;
    Cum[tid] = wave_prefix_incl(la[r], tid);
    Dt[tid] = dtv[r];
  }
  __syncthreads();
  int lane = tid & 63, wv2 = tid >> 6;
  int wr = (wv2 >> 1) * 32, wc = (wv2 & 1) * 32;
  int ln15 = lane & 15, kg = lane >> 4;
  // ---- Phase A: G[t][s] = sum_n C[t,n] B[s,n]
  f32x4 accA[2][2] = {};
  #pragma unroll
  for (int ks = 0; ks < 2; ks++) {
    short8v af[2], bq[2];
    #pragma unroll
    for (int mt = 0; mt < 2; mt++)
      af[mt] = *reinterpret_cast<const short8v*>(&Cb[(wr + mt * 16 + ln15) * 72 + ks * 32 + kg * 8]);
    #pragma unroll
    for (int nt = 0; nt < 2; nt++)
      bq[nt] = *reinterpret_cast<const short8v*>(&Bb[(wc + nt * 16 + ln15) * 72 + ks * 32 + kg * 8]);
    #pragma unroll
    for (int mt = 0; mt < 2; mt++)
      #pragma unroll
      for (int nt = 0; nt < 2; nt++)
        accA[mt][nt] = __builtin_amdgcn_mfma_f32_16x16x32_bf16(af[mt], bq[nt], accA[mt][nt], 0, 0, 0);
  }
  // mask + weight in registers
  unsigned short gmb[2][2][4];
  #pragma unroll
  for (int mt = 0; mt < 2; mt++)
    #pragma unroll
    for (int nt = 0; nt < 2; nt++)
      #pragma unroll
      for (int q = 0; q < 4; q++) {
        int t = wr + mt * 16 + kg * 4 + q;
        int s = wc + nt * 16 + ln15;
        float v = (s <= t) ? accA[mt][nt][q] * expf(Cum[t] - Cum[s]) * Dt[s] : 0.f;
        gmb[mt][nt][q] = f2bf(v);
      }
  __syncthreads();   // all waves done reading Bb
  #pragma unroll
  for (int mt = 0; mt < 2; mt++)
    #pragma unroll
    for (int nt = 0; nt < 2; nt++)
      #pragma unroll
      for (int q = 0; q < 4; q++)
        Bb[(wr + mt * 16 + kg * 4 + q) * 72 + wc + nt * 16 + ln15] = gmb[mt][nt][q];
  __syncthreads();
  // ---- Phase B: Y[t][p] = sum_s Gm[t,s] X[s,p] ; Phase C: Z[t][p] = sum_n C[t,n] h[p,n]
  f32x4 accY[2][2] = {}, accZ[2][2] = {};
  #pragma unroll
  for (int ks = 0; ks < 2; ks++) {
    short8v af[2], bq[2];
    #pragma unroll
    for (int mt = 0; mt < 2; mt++)
      af[mt] = *reinterpret_cast<const short8v*>(&Bb[(wr + mt * 16 + ln15) * 72 + ks * 32 + kg * 8]);
    #pragma unroll
    for (int nt = 0; nt < 2; nt++)
      bq[nt] = *reinterpret_cast<const short8v*>(&XT[(wc + nt * 16 + ln15) * 72 + ks * 32 + kg * 8]);
    #pragma unroll
    for (int mt = 0; mt < 2; mt++)
      #pragma unroll
      for (int nt = 0; nt < 2; nt++)
        accY[mt][nt] = __builtin_amdgcn_mfma_f32_16x16x32_bf16(af[mt], bq[nt], accY[mt][nt], 0, 0, 0);
  }
  if (c > 0) {
    #pragma unroll
    for (int ks = 0; ks < 2; ks++) {
      short8v af[2], bq[2];
      #pragma unroll
      for (int mt = 0; mt < 2; mt++)
        af[mt] = *reinterpret_cast<const short8v*>(&Cb[(wr + mt * 16 + ln15) * 72 + ks * 32 + kg * 8]);
      #pragma unroll
      for (int nt = 0; nt < 2; nt++)
        bq[nt] = *reinterpret_cast<const short8v*>(&hb[(wc + nt * 16 + ln15) * 72 + ks * 32 + kg * 8]);
      #pragma unroll
      for (int mt = 0; mt < 2; mt++)
        #pragma unroll
        for (int nt = 0; nt < 2; nt++)
          accZ[mt][nt] = __builtin_amdgcn_mfma_f32_16x16x32_bf16(af[mt], bq[nt], accZ[mt][nt], 0, 0, 0);
    }
  }
  float Dv = Dvec[h];
  #pragma unroll
  for (int mt = 0; mt < 2; mt++)
    #pragma unroll
    for (int q = 0; q < 4; q++) {
      int t = wr + mt * 16 + kg * 4 + q;
      float wB = expf(Cum[t]);
      const unsigned short* xp = xbc + (row0 + t) * conv_dim + (h << 6);
      unsigned short* yp = y + (row0 + t) * d_inner + (h << 6);
      #pragma unroll
      for (int nt = 0; nt < 2; nt++) {
        int p = wc + nt * 16 + ln15;
        yp[p] = f2bf(accY[mt][nt][q] + accZ[mt][nt][q] * wB + bf2f(xp[p]) * Dv);
      }
    }
}

// --- wave-per-row: g = y*silu(z); g *= rsqrt(mean(g^2)+eps)*rms_w; bf16 out ---
template <int CPL>
__global__ __launch_bounds__(256) void gate_rms_bf16(const unsigned short* __restrict__ y,
                                                     const unsigned short* __restrict__ z,
                                                     const float* __restrict__ rmsw,
                                                     unsigned short* __restrict__ ab,
                                                     int d_inner) {
  long row = (long)blockIdx.x * 4 + (threadIdx.x >> 6);
  int lane = threadIdx.x & 63;
  const unsigned short* yr = y + row * d_inner;
  const unsigned short* zr = z + row * d_inner;
  float g[CPL];
  float ss = 0.f;
  #pragma unroll
  for (int j = 0; j < CPL / 4; j++) {
    int c = j * 256 + lane * 4;
    ushort4 yv = *reinterpret_cast<const ushort4*>(&yr[c]);
    ushort4 zv = *reinterpret_cast<const ushort4*>(&zr[c]);
    float g0 = bf2f(yv.x) * siluf(bf2f(zv.x));
    float g1 = bf2f(yv.y) * siluf(bf2f(zv.y));
    float g2 = bf2f(yv.z) * siluf(bf2f(zv.z));
    float g3 = bf2f(yv.w) * siluf(bf2f(zv.w));
    g[j * 4 + 0] = g0; g[j * 4 + 1] = g1; g[j * 4 + 2] = g2; g[j * 4 + 3] = g3;
    ss += g0 * g0 + g1 * g1 + g2 * g2 + g3 * g3;
  }
  #pragma unroll
  for (int o = 32; o; o >>= 1) ss += __shfl_xor(ss, o);
  float inv = rsqrtf(ss / (float)d_inner + EPSV);
  #pragma unroll
  for (int j = 0; j < CPL / 4; j++) {
    int c = j * 256 + lane * 4;
    float4 wv = *reinterpret_cast<const float4*>(&rmsw[c]);
    ushort4 o;
    o.x = f2bf(g[j * 4 + 0] * inv * wv.x);
    o.y = f2bf(g[j * 4 + 1] * inv * wv.y);
    o.z = f2bf(g[j * 4 + 2] * inv * wv.z);
    o.w = f2bf(g[j * 4 + 3] * inv * wv.w);
    *reinterpret_cast<ushort4*>(&ab[row * d_inner + c]) = o;
  }
}

extern "C" void kernel_launch(void* const* d_in, const int* in_sizes, int n_in,
                              void* d_out, int out_size, void* d_ws,
                              size_t ws_size, hipStream_t stream) {
  const float* x        = (const float*)d_in[0];
  const float* ln_spa_w = (const float*)d_in[1];
  const float* ln_spa_b = (const float*)d_in[2];
  const float* ln_spe_w = (const float*)d_in[3];
  const float* ln_spe_b = (const float*)d_in[4];
  const float* spa_W_in   = (const float*)d_in[5];
  const float* spa_conv_w = (const float*)d_in[6];
  const float* spa_conv_b = (const float*)d_in[7];
  const float* spa_dt_b   = (const float*)d_in[8];
  const float* spa_A_log  = (const float*)d_in[9];
  const float* spa_D      = (const float*)d_in[10];
  const float* spa_rms_w  = (const float*)d_in[11];
  const float* spa_W_out  = (const float*)d_in[12];
  const float* spe_W_in   = (const float*)d_in[13];
  const float* spe_conv_w = (const float*)d_in[14];
  const float* spe_conv_b = (const float*)d_in[15];
  const float* spe_dt_b   = (const float*)d_in[16];
  const float* spe_A_log  = (const float*)d_in[17];
  const float* spe_D      = (const float*)d_in[18];
  const float* spe_rms_w  = (const float*)d_in[19];
  const float* spe_W_out  = (const float*)d_in[20];
  float* out = (float*)d_out;

  float* ws = (float*)d_ws;
  float* xspa   = ws;                 // 1,048,576
  unsigned short* z = (unsigned short*)(ws + 1048576);
  unsigned short* xbcraw = (unsigned short*)(ws + 3145728);
  float* Sc     = ws + 3145728;       // overlay (xbcraw dead after conv)
  float* dtraw  = ws + 6291456;       // 32,768 (later Aprod)
  unsigned short* cv = (unsigned short*)(ws + 6324224);
  float* dtb    = ws + 9469952;       // 32,768 (also spe LN partials)
  float* la     = ws + 9502720;       // 32,768
  unsigned short* yb = (unsigned short*)(ws + 9535488);
  unsigned short* Abf     = (unsigned short*)(ws + 11634688);
  unsigned short* Wt_spai = (unsigned short*)(ws + 12683264);
  unsigned short* Wt_spao = (unsigned short*)(ws + 12724480);
  unsigned short* Wt_spei = (unsigned short*)(ws + 12740864);
  unsigned short* Wt_speo = (unsigned short*)(ws + 14919936);

  // 1. fused prologue: spa LN (blocks 0..4095) + all weight transposes
  hipLaunchKernelGGL(ln_wt_fused, dim3(5710), dim3(256), 0, stream,
                     x, ln_spa_w, ln_spa_b, Abf,
                     spa_W_in, Wt_spai, spa_W_out, Wt_spao,
                     spe_W_in, Wt_spei, spe_W_out, Wt_speo);

  // ================= spatial mamba (L=1024, d_model=128) =================
  hipLaunchKernelGGL(gemm128_split, dim3(6, 64), dim3(256), 0, stream,
                     Abf, Wt_spai, z, xbcraw, dtraw,
                     8192, 644, 128, 256, 640);
  hipLaunchKernelGGL(conv_dtda, dim3(3200), dim3(256), 0, stream,
                     xbcraw, spa_conv_w, spa_conv_b, cv,
                     dtraw, spa_dt_b, spa_A_log, dtb, la,
                     8, 1024, 384, 4, 32768, 3072);
  hipLaunchKernelGGL(ssd_local, dim3(480), dim3(256), 0, stream,
                     cv, dtb, la, Sc, dtraw, 16, 15, 4, 384, 256);
  hipLaunchKernelGGL(ssd_out, dim3(512), dim3(256), 0, stream,
                     cv, dtb, la, Sc, dtraw, spa_D, yb, 16, 4, 384, 256);
  hipLaunchKernelGGL((gate_rms_bf16<4>), dim3(2048), dim3(256), 0, stream,
                     yb, z, spa_rms_w, Abf, 256);
  hipLaunchKernelGGL(gemm_mfma1, dim3(2, 128), dim3(256), 0, stream,
                     Abf, Wt_spao, x, xspa, dtb, 8192, 128, 256);

  // ================= spectral mamba (L=128, d_model=1024) =================
  hipLaunchKernelGGL(spe_normT, dim3(2, 8, 8), dim3(256), 0, stream,
                     xspa, dtb, ln_spe_w, ln_spe_b, Abf);
  hipLaunchKernelGGL(gemm128_split, dim3(34, 8), dim3(256), 0, stream,
                     Abf, Wt_spei, z, xbcraw, dtraw,
                     1024, 4256, 1024, 2048, 4224);
  hipLaunchKernelGGL(conv_dtda, dim3(2304), dim3(256), 0, stream,
                     xbcraw, spe_conv_w, spe_conv_b, cv,
                     dtraw, spe_dt_b, spe_A_log, dtb, la,
                     8, 128, 2176, 32, 32768, 2176);
  hipLaunchKernelGGL(ssd_local, dim3(256), dim3(256), 0, stream,
                     cv, dtb, la, Sc, dtraw, 2, 1, 32, 2176, 2048);
  hipLaunchKernelGGL(ssd_out, dim3(512), dim3(256), 0, stream,
                     cv, dtb, la, Sc, dtraw, spe_D, yb, 2, 32, 2176, 2048);
  hipLaunchKernelGGL((gate_rms_bf16<32>), dim3(256), dim3(256), 0, stream,
                     yb, z, spe_rms_w, Abf, 2048);
  hipLaunchKernelGGL(gemm128x64_t, dim3(16, 8), dim3(256), 0, stream,
                     Abf, Wt_speo, xspa, out, 1024, 1024, 2048);
}

// Round 15
// 157.889 us; speedup vs baseline: 1.4183x; 1.0375x over previous
//
#include <hip/hip_runtime.h>
#include <hip/hip_bf16.h>

#define EPSV 1e-5f

typedef __attribute__((ext_vector_type(8))) short short8v;   // 8 bf16 in 4 VGPRs
typedef __attribute__((ext_vector_type(4))) float f32x4;

__device__ inline unsigned short f2bf(float f) {
  __hip_bfloat16 h = __float2bfloat16(f);
  return *reinterpret_cast<unsigned short*>(&h);
}

__device__ inline float bf2f(unsigned short u) {
  return __uint_as_float(((unsigned int)u) << 16);
}

__device__ inline float siluf(float x) { return x / (1.f + expf(-x)); }

// direct global->LDS 16B async copy (lane-linear dest: base + lane*16)
__device__ inline void gload_lds16(const void* g, void* l) {
  __builtin_amdgcn_global_load_lds(
      (const __attribute__((address_space(1))) void*)g,
      (__attribute__((address_space(3))) void*)l, 16, 0, 0);
}

// inclusive prefix sum over 64 lanes (call from wave 0 only)
__device__ inline float wave_prefix_incl(float v, int lane) {
  #pragma unroll
  for (int o = 1; o < 64; o <<= 1) {
    float u = __shfl_up(v, o);
    if (lane >= o) v += u;
  }
  return v;
}

// ------- weight transpose tile W[K][N] -> Wt[N][K] bf16 -------
__device__ inline void wtconv_tile(const float* __restrict__ W,
                                   unsigned short* __restrict__ Wt,
                                   int K, int N, int bx, int by) {
  __shared__ float tile[64][65];
  int n0 = bx * 64, k0 = by * 64;
  int tid = threadIdx.x;
  int r = tid >> 4, c4 = (tid & 15) * 4;
  #pragma unroll
  for (int i = 0; i < 4; i++) {
    int kk = r + i * 16;
    float4 v = make_float4(0.f, 0.f, 0.f, 0.f);
    if (n0 + c4 < N) v = *reinterpret_cast<const float4*>(&W[(long)(k0 + kk) * N + n0 + c4]);
    tile[kk][c4] = v.x; tile[kk][c4 + 1] = v.y; tile[kk][c4 + 2] = v.z; tile[kk][c4 + 3] = v.w;
  }
  __syncthreads();
  #pragma unroll
  for (int i = 0; i < 4; i++) {
    int nl = r + i * 16;
    if (n0 + nl < N) {
      ushort4 o;
      o.x = f2bf(tile[c4 + 0][nl]);
      o.y = f2bf(tile[c4 + 1][nl]);
      o.z = f2bf(tile[c4 + 2][nl]);
      o.w = f2bf(tile[c4 + 3][nl]);
      *reinterpret_cast<ushort4*>(&Wt[(long)(n0 + nl) * K + k0 + c4]) = o;
    }
  }
}

// ---- fused prologue: spa LN (2 rows/block, bf16 out) + all 4 weight transposes ----
__global__ __launch_bounds__(256) void ln_wt_fused(const float* __restrict__ x,
                                                   const float* __restrict__ w,
                                                   const float* __restrict__ bb,
                                                   unsigned short* __restrict__ outA,
                                                   const float* __restrict__ W0,
                                                   unsigned short* __restrict__ T0,
                                                   const float* __restrict__ W1,
                                                   unsigned short* __restrict__ T1,
                                                   const float* __restrict__ W2,
                                                   unsigned short* __restrict__ T2,
                                                   const float* __restrict__ W3,
                                                   unsigned short* __restrict__ T3) {
  int id = blockIdx.x;
  if (id < 4096) {
    int tid = threadIdx.x;
    __shared__ float lds[4];
    long row = (long)id * 2 + (tid >> 7);
    int lane = tid & 127;
    int base = (tid >> 7) << 1;
    float v = x[row * 128 + lane];
    float s = v;
    #pragma unroll
    for (int o = 32; o; o >>= 1) s += __shfl_xor(s, o);
    if ((tid & 63) == 0) lds[tid >> 6] = s;
    __syncthreads();
    float m = (lds[base] + lds[base + 1]) * (1.f / 128.f);
    float d = v - m;
    float q = d * d;
    #pragma unroll
    for (int o = 32; o; o >>= 1) q += __shfl_xor(q, o);
    __syncthreads();
    if ((tid & 63) == 0) lds[tid >> 6] = q;
    __syncthreads();
    float inv = rsqrtf((lds[base] + lds[base + 1]) * (1.f / 128.f) + EPSV);
    outA[row * 128 + lane] = f2bf(d * inv * w[lane] + bb[lane]);
  } else {
    id -= 4096;
    if (id < 22)        { int r = id;        wtconv_tile(W0, T0, 128,  644,  r % 11, r / 11); }
    else if (id < 30)   { int r = id - 22;   wtconv_tile(W1, T1, 256,  128,  r % 2,  r / 2); }
    else if (id < 1102) { int r = id - 30;   wtconv_tile(W2, T2, 1024, 4256, r % 67, r / 67); }
    else                { int r = id - 1102; wtconv_tile(W3, T3, 2048, 1024, r % 16, r / 16); }
  }
}

// ---- spe LN pass 2: finalize per-(b,ch) stats from GEMM partials,
//      normalize + transpose, emit bf16. part2: float2[(by*2+bx)*64 + cl]
__global__ __launch_bounds__(256) void spe_normT(const float* __restrict__ xspa,
                                                 const float* __restrict__ part2,
                                                 const float* __restrict__ w,
                                                 const float* __restrict__ bb,
                                                 unsigned short* __restrict__ out) {
  __shared__ float tile[128][65];
  int c0 = blockIdx.x * 64, l0 = blockIdx.y * 128, b = blockIdx.z;
  int tid = threadIdx.x;
  int rr = tid >> 4, c4 = (tid & 15) * 4;
  #pragma unroll
  for (int p = 0; p < 8; p++) {
    int l = rr + p * 16;
    f32x4 v = *reinterpret_cast<const f32x4*>(
        &xspa[((long)b * 1024 + l0 + l) * 128 + c0 + c4]);
    tile[l][c4] = v[0]; tile[l][c4 + 1] = v[1];
    tile[l][c4 + 2] = v[2]; tile[l][c4 + 3] = v[3];
  }
  __syncthreads();
  int ch = tid >> 2, lq = tid & 3;
  int gc = c0 + ch;
  int bx = gc >> 6, cl = gc & 63;
  float ssum = 0.f, qsum = 0.f;
  #pragma unroll
  for (int sub = 0; sub < 16; sub++) {
    int by = b * 16 + sub;
    float2 pq = *reinterpret_cast<const float2*>(&part2[(((by * 2 + bx) * 64) + cl) * 2]);
    ssum += pq.x; qsum += pq.y;
  }
  float mm = ssum * (1.f / 1024.f);
  float rstd = rsqrtf(qsum * (1.f / 1024.f) - mm * mm + EPSV);
  #pragma unroll
  for (int j = 0; j < 8; j++) {
    int qidx = lq + j * 4;
    int l = qidx * 4;
    float4 wv = *reinterpret_cast<const float4*>(&w[l0 + l]);
    float4 bv = *reinterpret_cast<const float4*>(&bb[l0 + l]);
    ushort4 o;
    o.x = f2bf((tile[l + 0][ch] - mm) * rstd * wv.x + bv.x);
    o.y = f2bf((tile[l + 1][ch] - mm) * rstd * wv.y + bv.y);
    o.z = f2bf((tile[l + 2][ch] - mm) * rstd * wv.z + bv.z);
    o.w = f2bf((tile[l + 3][ch] - mm) * rstd * wv.w + bv.w);
    *reinterpret_cast<ushort4*>(&out[((long)b * 128 + c0 + ch) * 1024 + l0 + l]) = o;
  }
}

// ------- 128x128-tile bf16 MFMA GEMM, DOUBLE-BUFFERED gload_lds staging -------
// column-split epilogue: c<c1 -> zout (bf16, ld c1); c<c2 -> o2 (bf16); else o3 (f32)
__global__ __launch_bounds__(256) void gemm128_split(const unsigned short* __restrict__ A,
                                                     const unsigned short* __restrict__ Bt,
                                                     unsigned short* __restrict__ zout,
                                                     unsigned short* __restrict__ o2,
                                                     float* __restrict__ o3,
                                                     int M, int N, int K,
                                                     int c1, int c2) {
  __shared__ unsigned short As[2][128 * 32];
  __shared__ unsigned short Bs[2][128 * 32];
  int tid = threadIdx.x;
  int lane = tid & 63, w = tid >> 6;
  int wr = (w >> 1) * 64, wc = (w & 1) * 64;
  int ln15 = lane & 15, kg = lane >> 4;
  int rowBase = blockIdx.y * 128, colBase = blockIdx.x * 128;
  int srow = w * 32 + (lane >> 2);
  int scol = (lane & 3) * 8;
  f32x4 acc[4][4] = {};
  auto stage = [&](int buf, int k0) {
    gload_lds16(&A[(long)(rowBase + srow) * K + k0 + scol], &As[buf][(w * 32) * 32]);
    gload_lds16(&A[(long)(rowBase + srow + 16) * K + k0 + scol], &As[buf][(w * 32 + 16) * 32]);
    gload_lds16(&Bt[(long)(colBase + srow) * K + k0 + scol], &Bs[buf][(w * 32) * 32]);
    gload_lds16(&Bt[(long)(colBase + srow + 16) * K + k0 + scol], &Bs[buf][(w * 32 + 16) * 32]);
  };
  stage(0, 0);
  __syncthreads();
  int cur = 0;
  for (int k0 = 0; k0 < K; k0 += 32) {
    if (k0 + 32 < K) stage(cur ^ 1, k0 + 32);
    short8v af[4], bfr[4];
    #pragma unroll
    for (int mt = 0; mt < 4; mt++)
      af[mt] = *reinterpret_cast<const short8v*>(&As[cur][(wr + mt * 16 + ln15) * 32 + kg * 8]);
    #pragma unroll
    for (int nt = 0; nt < 4; nt++)
      bfr[nt] = *reinterpret_cast<const short8v*>(&Bs[cur][(wc + nt * 16 + ln15) * 32 + kg * 8]);
    #pragma unroll
    for (int mt = 0; mt < 4; mt++)
      #pragma unroll
      for (int nt = 0; nt < 4; nt++)
        acc[mt][nt] = __builtin_amdgcn_mfma_f32_16x16x32_bf16(af[mt], bfr[nt], acc[mt][nt], 0, 0, 0);
    __syncthreads();
    cur ^= 1;
  }
  #pragma unroll
  for (int mt = 0; mt < 4; mt++)
    #pragma unroll
    for (int nt = 0; nt < 4; nt++)
      #pragma unroll
      for (int q = 0; q < 4; q++) {
        int r = rowBase + wr + mt * 16 + kg * 4 + q;
        int c = colBase + wc + nt * 16 + ln15;
        if (c < N) {
          float v = acc[mt][nt][q];
          if (c < c1) zout[(long)r * c1 + c] = f2bf(v);
          else if (c < c2) o2[(long)r * (c2 - c1) + (c - c1)] = f2bf(v);
          else o3[(long)r * (N - c2) + (c - c2)] = v;
        }
      }
}

// ------- 128(rows)x64(cols)-tile GEMM, dbuf gload_lds, transposed-add -------
__global__ __launch_bounds__(256) void gemm128x64_t(const unsigned short* __restrict__ A,
                                                    const unsigned short* __restrict__ Bt,
                                                    const float* __restrict__ R,
                                                    float* __restrict__ out,
                                                    int M, int N, int K) {
  __shared__ unsigned short As[2][128 * 32];
  __shared__ unsigned short Bs[2][64 * 32];
  int tid = threadIdx.x;
  int lane = tid & 63, w = tid >> 6;
  int wr = w * 32;
  int ln15 = lane & 15, kg = lane >> 4;
  int rowBase = blockIdx.y * 128, colBase = blockIdx.x * 64;
  int arow = w * 32 + (lane >> 2);
  int brow = w * 16 + (lane >> 2);
  int scol = (lane & 3) * 8;
  f32x4 acc[2][4] = {};
  auto stage = [&](int buf, int k0) {
    gload_lds16(&A[(long)(rowBase + arow) * K + k0 + scol], &As[buf][(w * 32) * 32]);
    gload_lds16(&A[(long)(rowBase + arow + 16) * K + k0 + scol], &As[buf][(w * 32 + 16) * 32]);
    gload_lds16(&Bt[(long)(colBase + brow) * K + k0 + scol], &Bs[buf][(w * 16) * 32]);
  };
  stage(0, 0);
  __syncthreads();
  int cur = 0;
  for (int k0 = 0; k0 < K; k0 += 32) {
    if (k0 + 32 < K) stage(cur ^ 1, k0 + 32);
    short8v af[2], bfr[4];
    #pragma unroll
    for (int mt = 0; mt < 2; mt++)
      af[mt] = *reinterpret_cast<const short8v*>(&As[cur][(wr + mt * 16 + ln15) * 32 + kg * 8]);
    #pragma unroll
    for (int nt = 0; nt < 4; nt++)
      bfr[nt] = *reinterpret_cast<const short8v*>(&Bs[cur][(nt * 16 + ln15) * 32 + kg * 8]);
    #pragma unroll
    for (int mt = 0; mt < 2; mt++)
      #pragma unroll
      for (int nt = 0; nt < 4; nt++)
        acc[mt][nt] = __builtin_amdgcn_mfma_f32_16x16x32_bf16(af[mt], bfr[nt], acc[mt][nt], 0, 0, 0);
    __syncthreads();
    cur ^= 1;
  }
  #pragma unroll
  for (int mt = 0; mt < 2; mt++)
    #pragma unroll
    for (int nt = 0; nt < 4; nt++)
      #pragma unroll
      for (int q = 0; q < 4; q++) {
        int r = rowBase + wr + mt * 16 + kg * 4 + q;
        int c = colBase + nt * 16 + ln15;
        int bb = r >> 7, ch = r & 127;
        out[(long)bb * 131072 + (long)c * 128 + ch] =
            acc[mt][nt][q] + R[((long)bb * 1024 + c) * 128 + ch];
      }
}

// ------ 64x64-tile bf16 MFMA GEMM (spa W_out), dbuf gload_lds staging ------
// out = v + R; also emits deterministic per-block column {sum,sum^2} partials.
// Requires full tiles (M%64==0, N%64==0).
__global__ __launch_bounds__(256) void gemm_mfma1(const unsigned short* __restrict__ A,
                                                  const unsigned short* __restrict__ Bt,
                                                  const float* __restrict__ R,
                                                  float* __restrict__ out,
                                                  float* __restrict__ part2,
                                                  int M, int N, int K) {
  __shared__ unsigned short As[2][64 * 32];
  __shared__ unsigned short Bs[2][64 * 32];
  int tid = threadIdx.x;
  int lane = tid & 63, w = tid >> 6;
  int wr = (w >> 1) * 32, wc = (w & 1) * 32;
  int ln15 = lane & 15, kg = lane >> 4;
  int rowBase = blockIdx.y * 64, colBase = blockIdx.x * 64;
  int srow = w * 16 + (lane >> 2);
  int scol = (lane & 3) * 8;
  f32x4 acc[2][2] = {};
  auto stage = [&](int buf, int k0) {
    gload_lds16(&A[(long)(rowBase + srow) * K + k0 + scol], &As[buf][(w * 16) * 32]);
    gload_lds16(&Bt[(long)(colBase + srow) * K + k0 + scol], &Bs[buf][(w * 16) * 32]);
  };
  stage(0, 0);
  __syncthreads();
  int cur = 0;
  for (int k0 = 0; k0 < K; k0 += 32) {
    if (k0 + 32 < K) stage(cur ^ 1, k0 + 32);
    short8v af[2], bfr[2];
    #pragma unroll
    for (int mt = 0; mt < 2; mt++)
      af[mt] = *reinterpret_cast<const short8v*>(&As[cur][(wr + mt * 16 + ln15) * 32 + kg * 8]);
    #pragma unroll
    for (int nt = 0; nt < 2; nt++)
      bfr[nt] = *reinterpret_cast<const short8v*>(&Bs[cur][(wc + nt * 16 + ln15) * 32 + kg * 8]);
    #pragma unroll
    for (int mt = 0; mt < 2; mt++)
      #pragma unroll
      for (int nt = 0; nt < 2; nt++)
        acc[mt][nt] = __builtin_amdgcn_mfma_f32_16x16x32_bf16(af[mt], bfr[nt], acc[mt][nt], 0, 0, 0);
    __syncthreads();
    cur ^= 1;
  }
  float sC[2] = {0.f, 0.f}, qC[2] = {0.f, 0.f};
  #pragma unroll
  for (int mt = 0; mt < 2; mt++)
    #pragma unroll
    for (int nt = 0; nt < 2; nt++)
      #pragma unroll
      for (int q = 0; q < 4; q++) {
        int r = rowBase + wr + mt * 16 + kg * 4 + q;
        int c = colBase + wc + nt * 16 + ln15;
        float v = acc[mt][nt][q] + R[(long)r * N + c];
        out[(long)r * N + c] = v;
        sC[nt] += v;
        qC[nt] += v * v;
      }
  __shared__ float redS[4][32], redQ[4][32];
  #pragma unroll
  for (int nt = 0; nt < 2; nt++) {
    sC[nt] += __shfl_xor(sC[nt], 16);
    sC[nt] += __shfl_xor(sC[nt], 32);
    qC[nt] += __shfl_xor(qC[nt], 16);
    qC[nt] += __shfl_xor(qC[nt], 32);
  }
  if (lane < 16) {
    redS[w][ln15] = sC[0];       redQ[w][ln15] = qC[0];
    redS[w][16 + ln15] = sC[1];  redQ[w][16 + ln15] = qC[1];
  }
  __syncthreads();
  if (tid < 64) {
    int c = tid;
    int grp = c >> 5, lo = c & 31;
    float ss = redS[grp][lo] + redS[grp + 2][lo];
    float qq = redQ[grp][lo] + redQ[grp + 2][lo];
    long slot = ((long)(blockIdx.y * 2 + blockIdx.x) * 64 + c) * 2;
    part2[slot] = ss;
    part2[slot + 1] = qq;
  }
}

// ---- fused: causal depthwise conv (bf16 in, bf16 out) + bias + SiLU | dt/la ----
__global__ __launch_bounds__(256) void conv_dtda(const unsigned short* __restrict__ zx,
                                                 const float* __restrict__ cw,
                                                 const float* __restrict__ cb,
                                                 unsigned short* __restrict__ cout,
                                                 const float* __restrict__ raw,
                                                 const float* __restrict__ dtbias,
                                                 const float* __restrict__ alog,
                                                 float* __restrict__ dt,
                                                 float* __restrict__ la,
                                                 int Bb, int L, int conv_dim,
                                                 int H, int rowsH, int convBlocks) {
  int tid = threadIdx.x;
  if ((int)blockIdx.x < convBlocks) {
    long idx4 = (long)blockIdx.x * 256 + tid;
    int nch4 = conv_dim >> 2;
    long total4 = (long)Bb * L * nch4;
    if (idx4 >= total4) return;
    int ch = (int)(idx4 % nch4) << 2;
    long rt = idx4 / nch4;
    int t = (int)(rt % L);
    int b = (int)(rt / L);
    f32x4 acc = *reinterpret_cast<const f32x4*>(&cb[ch]);
    #pragma unroll
    for (int k = 0; k < 4; k++) {
      int tt = t + k - 3;
      if (tt >= 0) {
        f32x4 wv = *reinterpret_cast<const f32x4*>(&cw[k * conv_dim + ch]);
        ushort4 zu = *reinterpret_cast<const ushort4*>(
            &zx[((long)b * L + tt) * conv_dim + ch]);
        acc[0] += wv[0] * bf2f(zu.x);
        acc[1] += wv[1] * bf2f(zu.y);
        acc[2] += wv[2] * bf2f(zu.z);
        acc[3] += wv[3] * bf2f(zu.w);
      }
    }
    ushort4 o;
    o.x = f2bf(siluf(acc[0])); o.y = f2bf(siluf(acc[1]));
    o.z = f2bf(siluf(acc[2])); o.w = f2bf(siluf(acc[3]));
    *reinterpret_cast<ushort4*>(&cout[rt * conv_dim + ch]) = o;
  } else {
    int idx = ((int)blockIdx.x - convBlocks) * 256 + tid;
    if (idx >= rowsH) return;
    int h = idx % H;
    float v = raw[idx] + dtbias[h];
    float sp = (v > 20.f) ? v : log1pf(expf(v));
    dt[idx] = sp;
    la[idx] = -expf(alog[h]) * sp;
  }
}

// ===================== spa chunked SSD (T=64), MFMA, bf16 inputs =====================
// K1: S[p,n] = sum_t (Ws[t]*X[t,p]) * B[t,n]
__global__ __launch_bounds__(256) void ssd_local(const unsigned short* __restrict__ xbc,
                                                 const float* __restrict__ dtv,
                                                 const float* __restrict__ la,
                                                 float* __restrict__ Sc,
                                                 float* __restrict__ Aprod,
                                                 int NC, int nc_launch, int H,
                                                 int conv_dim, int d_inner) {
  int blk = blockIdx.x;
  int c = blk % nc_launch, bh = blk / nc_launch;
  int h = bh % H, b = bh / H;
  int tid = threadIdx.x;
  long row0 = ((long)(b * NC + c)) * 64;
  __shared__ unsigned short XpT[64 * 72];
  __shared__ unsigned short BT[64 * 72];
  __shared__ float Ws[64];
  int tq = tid >> 4, cq = (tid & 15) << 2;
  ushort4 xr[4], br[4];
  #pragma unroll
  for (int i = 0; i < 4; i++) {
    int t = tq + i * 16;
    const unsigned short* rp = xbc + (row0 + t) * conv_dim;
    xr[i] = *reinterpret_cast<const ushort4*>(rp + (h << 6) + cq);
    br[i] = *reinterpret_cast<const ushort4*>(rp + d_inner + cq);
  }
  if (tid < 64) {
    long r = (row0 + tid) * H + h;
    float cum = wave_prefix_incl(la[r], tid);
    float cT = __shfl(cum, 63);
    Ws[tid] = expf(cT - cum) * dtv[r];
    if (tid == 63) Aprod[(long)bh * NC + c] = expf(cT);
  }
  __syncthreads();
  #pragma unroll
  for (int i = 0; i < 4; i++) {
    int t = tq + i * 16;
    float wv = Ws[t];
    XpT[(cq + 0) * 72 + t] = f2bf(wv * bf2f(xr[i].x));
    XpT[(cq + 1) * 72 + t] = f2bf(wv * bf2f(xr[i].y));
    XpT[(cq + 2) * 72 + t] = f2bf(wv * bf2f(xr[i].z));
    XpT[(cq + 3) * 72 + t] = f2bf(wv * bf2f(xr[i].w));
    BT[(cq + 0) * 72 + t] = br[i].x;
    BT[(cq + 1) * 72 + t] = br[i].y;
    BT[(cq + 2) * 72 + t] = br[i].z;
    BT[(cq + 3) * 72 + t] = br[i].w;
  }
  __syncthreads();
  int lane = tid & 63, wv2 = tid >> 6;
  int wr = (wv2 >> 1) * 32, wc = (wv2 & 1) * 32;
  int ln15 = lane & 15, kg = lane >> 4;
  f32x4 acc[2][2] = {};
  #pragma unroll
  for (int ks = 0; ks < 2; ks++) {
    short8v af[2], bq[2];
    #pragma unroll
    for (int mt = 0; mt < 2; mt++)
      af[mt] = *reinterpret_cast<const short8v*>(&XpT[(wr + mt * 16 + ln15) * 72 + ks * 32 + kg * 8]);
    #pragma unroll
    for (int nt = 0; nt < 2; nt++)
      bq[nt] = *reinterpret_cast<const short8v*>(&BT[(wc + nt * 16 + ln15) * 72 + ks * 32 + kg * 8]);
    #pragma unroll
    for (int mt = 0; mt < 2; mt++)
      #pragma unroll
      for (int nt = 0; nt < 2; nt++)
        acc[mt][nt] = __builtin_amdgcn_mfma_f32_16x16x32_bf16(af[mt], bq[nt], acc[mt][nt], 0, 0, 0);
  }
  float* base = Sc + ((long)bh * NC + c) * 4096;
  #pragma unroll
  for (int mt = 0; mt < 2; mt++)
    #pragma unroll
    for (int nt = 0; nt < 2; nt++)
      #pragma unroll
      for (int q = 0; q < 4; q++) {
        int p = wr + mt * 16 + kg * 4 + q;
        int n = wc + nt * 16 + ln15;
        base[p * 64 + n] = acc[mt][nt][q];
      }
}

// K3 (spa): MFMA phases with on-the-fly carry fold (fp32, bit-identical order)
__global__ __launch_bounds__(256) void ssd_out(const unsigned short* __restrict__ xbc,
                                               const float* __restrict__ dtv,
                                               const float* __restrict__ la,
                                               const float* __restrict__ Sc,
                                               const float* __restrict__ Aprod,
                                               const float* __restrict__ Dvec,
                                               unsigned short* __restrict__ y,
                                               int NC, int H, int conv_dim,
                                               int d_inner) {
  int blk = blockIdx.x;
  int c = blk % NC, bh = blk / NC;
  int h = bh % H, b = bh / H;
  int tid = threadIdx.x;
  long row0 = ((long)(b * NC + c)) * 64;
  __shared__ unsigned short Cb[64 * 72];
  __shared__ unsigned short Bb[64 * 72];
  __shared__ unsigned short XT[64 * 72];
  __shared__ unsigned short hb[64 * 72];
  __shared__ float Cum[64], Dt[64];
  int tq = tid >> 4, cq = (tid & 15) << 2;
  #pragma unroll
  for (int i = 0; i < 4; i++) {
    int t = tq + i * 16;
    const unsigned short* rp = xbc + (row0 + t) * conv_dim;
    ushort4 cu = *reinterpret_cast<const ushort4*>(rp + d_inner + 64 + cq);
    ushort4 bu = *reinterpret_cast<const ushort4*>(rp + d_inner + cq);
    ushort4 xu = *reinterpret_cast<const ushort4*>(rp + (h << 6) + cq);
    *reinterpret_cast<ushort4*>(&Cb[t * 72 + cq]) = cu;
    *reinterpret_cast<ushort4*>(&Bb[t * 72 + cq]) = bu;
    XT[(cq + 0) * 72 + t] = xu.x;
    XT[(cq + 1) * 72 + t] = xu.y;
    XT[(cq + 2) * 72 + t] = xu.z;
    XT[(cq + 3) * 72 + t] = xu.w;
  }
  if (c > 0) {
    f32x4 hreg[4] = {};
    const float* ap = Aprod + (long)bh * NC;
    for (int j = 0; j < c; j++) {
      const float* sb = Sc + ((long)bh * NC + j) * 4096;
      float a = ap[j];
      #pragma unroll
      for (int i = 0; i < 4; i++) {
        int p = tq + i * 16;
        f32x4 sv = *reinterpret_cast<const f32x4*>(&sb[p * 64 + cq]);
        hreg[i] = hreg[i] * a + sv;
      }
    }
    #pragma unroll
    for (int i = 0; i < 4; i++) {
      int p = tq + i * 16;
      ushort4 ho;
      ho.x = f2bf(hreg[i][0]); ho.y = f2bf(hreg[i][1]);
      ho.z = f2bf(hreg[i][2]); ho.w = f2bf(hreg[i][3]);
      *reinterpret_cast<ushort4*>(&hb[p * 72 + cq]) = ho;
    }
  }
  if (tid < 64) {
    long r = (row0 + tid) * H + h;
    Cum[tid] = wave_prefix_incl(la[r], tid);
    Dt[tid] = dtv[r];
  }
  __syncthreads();
  int lane = tid & 63, wv2 = tid >> 6;
  int wr = (wv2 >> 1) * 32, wc = (wv2 & 1) * 32;
  int ln15 = lane & 15, kg = lane >> 4;
  f32x4 accA[2][2] = {};
  #pragma unroll
  for (int ks = 0; ks < 2; ks++) {
    short8v af[2], bq[2];
    #pragma unroll
    for (int mt = 0; mt < 2; mt++)
      af[mt] = *reinterpret_cast<const short8v*>(&Cb[(wr + mt * 16 + ln15) * 72 + ks * 32 + kg * 8]);
    #pragma unroll
    for (int nt = 0; nt < 2; nt++)
      bq[nt] = *reinterpret_cast<const short8v*>(&Bb[(wc + nt * 16 + ln15) * 72 + ks * 32 + kg * 8]);
    #pragma unroll
    for (int mt = 0; mt < 2; mt++)
      #pragma unroll
      for (int nt = 0; nt < 2; nt++)
        accA[mt][nt] = __builtin_amdgcn_mfma_f32_16x16x32_bf16(af[mt], bq[nt], accA[mt][nt], 0, 0, 0);
  }
  unsigned short gmb[2][2][4];
  #pragma unroll
  for (int mt = 0; mt < 2; mt++)
    #pragma unroll
    for (int nt = 0; nt < 2; nt++)
      #pragma unroll
      for (int q = 0; q < 4; q++) {
        int t = wr + mt * 16 + kg * 4 + q;
        int s = wc + nt * 16 + ln15;
        float v = (s <= t) ? accA[mt][nt][q] * expf(Cum[t] - Cum[s]) * Dt[s] : 0.f;
        gmb[mt][nt][q] = f2bf(v);
      }
  __syncthreads();
  #pragma unroll
  for (int mt = 0; mt < 2; mt++)
    #pragma unroll
    for (int nt = 0; nt < 2; nt++)
      #pragma unroll
      for (int q = 0; q < 4; q++)
        Bb[(wr + mt * 16 + kg * 4 + q) * 72 + wc + nt * 16 + ln15] = gmb[mt][nt][q];
  __syncthreads();
  f32x4 accY[2][2] = {}, accZ[2][2] = {};
  #pragma unroll
  for (int ks = 0; ks < 2; ks++) {
    short8v af[2], bq[2];
    #pragma unroll
    for (int mt = 0; mt < 2; mt++)
      af[mt] = *reinterpret_cast<const short8v*>(&Bb[(wr + mt * 16 + ln15) * 72 + ks * 32 + kg * 8]);
    #pragma unroll
    for (int nt = 0; nt < 2; nt++)
      bq[nt] = *reinterpret_cast<const short8v*>(&XT[(wc + nt * 16 + ln15) * 72 + ks * 32 + kg * 8]);
    #pragma unroll
    for (int mt = 0; mt < 2; mt++)
      #pragma unroll
      for (int nt = 0; nt < 2; nt++)
        accY[mt][nt] = __builtin_amdgcn_mfma_f32_16x16x32_bf16(af[mt], bq[nt], accY[mt][nt], 0, 0, 0);
  }
  if (c > 0) {
    #pragma unroll
    for (int ks = 0; ks < 2; ks++) {
      short8v af[2], bq[2];
      #pragma unroll
      for (int mt = 0; mt < 2; mt++)
        af[mt] = *reinterpret_cast<const short8v*>(&Cb[(wr + mt * 16 + ln15) * 72 + ks * 32 + kg * 8]);
      #pragma unroll
      for (int nt = 0; nt < 2; nt++)
        bq[nt] = *reinterpret_cast<const short8v*>(&hb[(wc + nt * 16 + ln15) * 72 + ks * 32 + kg * 8]);
      #pragma unroll
      for (int mt = 0; mt < 2; mt++)
        #pragma unroll
        for (int nt = 0; nt < 2; nt++)
          accZ[mt][nt] = __builtin_amdgcn_mfma_f32_16x16x32_bf16(af[mt], bq[nt], accZ[mt][nt], 0, 0, 0);
    }
  }
  float Dv = Dvec[h];
  #pragma unroll
  for (int mt = 0; mt < 2; mt++)
    #pragma unroll
    for (int q = 0; q < 4; q++) {
      int t = wr + mt * 16 + kg * 4 + q;
      float wB = expf(Cum[t]);
      const unsigned short* xp = xbc + (row0 + t) * conv_dim + (h << 6);
      unsigned short* yp = y + (row0 + t) * d_inner + (h << 6);
      #pragma unroll
      for (int nt = 0; nt < 2; nt++) {
        int p = wc + nt * 16 + ln15;
        yp[p] = f2bf(accY[mt][nt][q] + accZ[mt][nt][q] * wB + bf2f(xp[p]) * Dv);
      }
    }
}

// ========== spe fused SSD (NC=2): S_0 + out(c=0) + out(c=1) in one block ==========
// grid = BH = 256 blocks; L=128, T=64, H=32, d_inner=2048, conv_dim=2176.
__global__ __launch_bounds__(256) void ssd_spe2(const unsigned short* __restrict__ xbc,
                                                const float* __restrict__ dtv,
                                                const float* __restrict__ la,
                                                const float* __restrict__ Dvec,
                                                unsigned short* __restrict__ y,
                                                int H, int conv_dim, int d_inner) {
  int bh = blockIdx.x;
  int h = bh % H, b = bh / H;
  int tid = threadIdx.x;
  __shared__ unsigned short Cb[64 * 72];   // C[t][n]
  __shared__ unsigned short Bb[64 * 72];   // B[s][n] -> Gm[t][s]
  __shared__ unsigned short XT[64 * 72];   // X^T[p][s]
  __shared__ unsigned short BT2[64 * 72];  // B^T[n][t] (chunk0, for S_0)
  __shared__ unsigned short WXT[64 * 72];  // (Ws*X)^T[p][t] (chunk0)
  __shared__ unsigned short hb[64 * 72];   // S_0[p][n] bf16
  __shared__ float Cum[64], Dt[64], Wsh[64];
  int tq = tid >> 4, cq = (tid & 15) << 2;
  int lane = tid & 63, wv2 = tid >> 6;
  int wr = (wv2 >> 1) * 32, wc = (wv2 & 1) * 32;
  int ln15 = lane & 15, kg = lane >> 4;
  float Dv = Dvec[h];

  // ---------- chunk 0 ----------
  long row0 = (long)b * 128;
  ushort4 cu[4], bu[4], xu[4];
  #pragma unroll
  for (int i = 0; i < 4; i++) {
    int t = tq + i * 16;
    const unsigned short* rp = xbc + (row0 + t) * conv_dim;
    cu[i] = *reinterpret_cast<const ushort4*>(rp + d_inner + 64 + cq);
    bu[i] = *reinterpret_cast<const ushort4*>(rp + d_inner + cq);
    xu[i] = *reinterpret_cast<const ushort4*>(rp + (h << 6) + cq);
  }
  if (tid < 64) {
    long r = (row0 + tid) * H + h;
    float cum = wave_prefix_incl(la[r], tid);
    float cT = __shfl(cum, 63);
    Cum[tid] = cum;
    Dt[tid] = dtv[r];
    Wsh[tid] = expf(cT - cum) * dtv[r];
  }
  __syncthreads();
  #pragma unroll
  for (int i = 0; i < 4; i++) {
    int t = tq + i * 16;
    float wvv = Wsh[t];
    *reinterpret_cast<ushort4*>(&Cb[t * 72 + cq]) = cu[i];
    *reinterpret_cast<ushort4*>(&Bb[t * 72 + cq]) = bu[i];
    XT[(cq + 0) * 72 + t] = xu[i].x;
    XT[(cq + 1) * 72 + t] = xu[i].y;
    XT[(cq + 2) * 72 + t] = xu[i].z;
    XT[(cq + 3) * 72 + t] = xu[i].w;
    BT2[(cq + 0) * 72 + t] = bu[i].x;
    BT2[(cq + 1) * 72 + t] = bu[i].y;
    BT2[(cq + 2) * 72 + t] = bu[i].z;
    BT2[(cq + 3) * 72 + t] = bu[i].w;
    WXT[(cq + 0) * 72 + t] = f2bf(wvv * bf2f(xu[i].x));
    WXT[(cq + 1) * 72 + t] = f2bf(wvv * bf2f(xu[i].y));
    WXT[(cq + 2) * 72 + t] = f2bf(wvv * bf2f(xu[i].z));
    WXT[(cq + 3) * 72 + t] = f2bf(wvv * bf2f(xu[i].w));
  }
  __syncthreads();
  // S_0[p][n] = sum_t WX[p,t] * B[n,t]
  f32x4 accS[2][2] = {};
  #pragma unroll
  for (int ks = 0; ks < 2; ks++) {
    short8v af[2], bq[2];
    #pragma unroll
    for (int mt = 0; mt < 2; mt++)
      af[mt] = *reinterpret_cast<const short8v*>(&WXT[(wr + mt * 16 + ln15) * 72 + ks * 32 + kg * 8]);
    #pragma unroll
    for (int nt = 0; nt < 2; nt++)
      bq[nt] = *reinterpret_cast<const short8v*>(&BT2[(wc + nt * 16 + ln15) * 72 + ks * 32 + kg * 8]);
    #pragma unroll
    for (int mt = 0; mt < 2; mt++)
      #pragma unroll
      for (int nt = 0; nt < 2; nt++)
        accS[mt][nt] = __builtin_amdgcn_mfma_f32_16x16x32_bf16(af[mt], bq[nt], accS[mt][nt], 0, 0, 0);
  }
  // Phase A0: G = C·B^T
  f32x4 accA[2][2] = {};
  #pragma unroll
  for (int ks = 0; ks < 2; ks++) {
    short8v af[2], bq[2];
    #pragma unroll
    for (int mt = 0; mt < 2; mt++)
      af[mt] = *reinterpret_cast<const short8v*>(&Cb[(wr + mt * 16 + ln15) * 72 + ks * 32 + kg * 8]);
    #pragma unroll
    for (int nt = 0; nt < 2; nt++)
      bq[nt] = *reinterpret_cast<const short8v*>(&Bb[(wc + nt * 16 + ln15) * 72 + ks * 32 + kg * 8]);
    #pragma unroll
    for (int mt = 0; mt < 2; mt++)
      #pragma unroll
      for (int nt = 0; nt < 2; nt++)
        accA[mt][nt] = __builtin_amdgcn_mfma_f32_16x16x32_bf16(af[mt], bq[nt], accA[mt][nt], 0, 0, 0);
  }
  unsigned short gmb[2][2][4];
  #pragma unroll
  for (int mt = 0; mt < 2; mt++)
    #pragma unroll
    for (int nt = 0; nt < 2; nt++)
      #pragma unroll
      for (int q = 0; q < 4; q++) {
        int t = wr + mt * 16 + kg * 4 + q;
        int s = wc + nt * 16 + ln15;
        float v = (s <= t) ? accA[mt][nt][q] * expf(Cum[t] - Cum[s]) * Dt[s] : 0.f;
        gmb[mt][nt][q] = f2bf(v);
      }
  __syncthreads();   // done reading Bb; accS done reading BT2
  #pragma unroll
  for (int mt = 0; mt < 2; mt++)
    #pragma unroll
    for (int nt = 0; nt < 2; nt++)
      #pragma unroll
      for (int q = 0; q < 4; q++) {
        Bb[(wr + mt * 16 + kg * 4 + q) * 72 + wc + nt * 16 + ln15] = gmb[mt][nt][q];
        // stage S_0 as bf16 into hb[p][n]
        int p = wr + mt * 16 + kg * 4 + q;
        int n = wc + nt * 16 + ln15;
        hb[p * 72 + n] = f2bf(accS[mt][nt][q]);
      }
  __syncthreads();
  // Phase B0: Y = Gm·X^T ; output chunk 0 (no Z)
  f32x4 accY[2][2] = {};
  #pragma unroll
  for (int ks = 0; ks < 2; ks++) {
    short8v af[2], bq[2];
    #pragma unroll
    for (int mt = 0; mt < 2; mt++)
      af[mt] = *reinterpret_cast<const short8v*>(&Bb[(wr + mt * 16 + ln15) * 72 + ks * 32 + kg * 8]);
    #pragma unroll
    for (int nt = 0; nt < 2; nt++)
      bq[nt] = *reinterpret_cast<const short8v*>(&XT[(wc + nt * 16 + ln15) * 72 + ks * 32 + kg * 8]);
    #pragma unroll
    for (int mt = 0; mt < 2; mt++)
      #pragma unroll
      for (int nt = 0; nt < 2; nt++)
        accY[mt][nt] = __builtin_amdgcn_mfma_f32_16x16x32_bf16(af[mt], bq[nt], accY[mt][nt], 0, 0, 0);
  }
  #pragma unroll
  for (int mt = 0; mt < 2; mt++)
    #pragma unroll
    for (int q = 0; q < 4; q++) {
      int t = wr + mt * 16 + kg * 4 + q;
      const unsigned short* xp = xbc + (row0 + t) * conv_dim + (h << 6);
      unsigned short* yp = y + (row0 + t) * d_inner + (h << 6);
      #pragma unroll
      for (int nt = 0; nt < 2; nt++) {
        int p = wc + nt * 16 + ln15;
        yp[p] = f2bf(accY[mt][nt][q] + bf2f(xp[p]) * Dv);
      }
    }
  __syncthreads();   // all waves done with chunk-0 LDS (Cb/Bb/XT)

  // ---------- chunk 1 ----------
  long row1 = row0 + 64;
  #pragma unroll
  for (int i = 0; i < 4; i++) {
    int t = tq + i * 16;
    const unsigned short* rp = xbc + (row1 + t) * conv_dim;
    cu[i] = *reinterpret_cast<const ushort4*>(rp + d_inner + 64 + cq);
    bu[i] = *reinterpret_cast<const ushort4*>(rp + d_inner + cq);
    xu[i] = *reinterpret_cast<const ushort4*>(rp + (h << 6) + cq);
  }
  if (tid < 64) {
    long r = (row1 + tid) * H + h;
    Cum[tid] = wave_prefix_incl(la[r], tid);
    Dt[tid] = dtv[r];
  }
  __syncthreads();
  #pragma unroll
  for (int i = 0; i < 4; i++) {
    int t = tq + i * 16;
    *reinterpret_cast<ushort4*>(&Cb[t * 72 + cq]) = cu[i];
    *reinterpret_cast<ushort4*>(&Bb[t * 72 + cq]) = bu[i];
    XT[(cq + 0) * 72 + t] = xu[i].x;
    XT[(cq + 1) * 72 + t] = xu[i].y;
    XT[(cq + 2) * 72 + t] = xu[i].z;
    XT[(cq + 3) * 72 + t] = xu[i].w;
  }
  __syncthreads();
  // Phase A1
  f32x4 accA1[2][2] = {};
  #pragma unroll
  for (int ks = 0; ks < 2; ks++) {
    short8v af[2], bq[2];
    #pragma unroll
    for (int mt = 0; mt < 2; mt++)
      af[mt] = *reinterpret_cast<const short8v*>(&Cb[(wr + mt * 16 + ln15) * 72 + ks * 32 + kg * 8]);
    #pragma unroll
    for (int nt = 0; nt < 2; nt++)
      bq[nt] = *reinterpret_cast<const short8v*>(&Bb[(wc + nt * 16 + ln15) * 72 + ks * 32 + kg * 8]);
    #pragma unroll
    for (int mt = 0; mt < 2; mt++)
      #pragma unroll
      for (int nt = 0; nt < 2; nt++)
        accA1[mt][nt] = __builtin_amdgcn_mfma_f32_16x16x32_bf16(af[mt], bq[nt], accA1[mt][nt], 0, 0, 0);
  }
  #pragma unroll
  for (int mt = 0; mt < 2; mt++)
    #pragma unroll
    for (int nt = 0; nt < 2; nt++)
      #pragma unroll
      for (int q = 0; q < 4; q++) {
        int t = wr + mt * 16 + kg * 4 + q;
        int s = wc + nt * 16 + ln15;
        float v = (s <= t) ? accA1[mt][nt][q] * expf(Cum[t] - Cum[s]) * Dt[s] : 0.f;
        gmb[mt][nt][q] = f2bf(v);
      }
  __syncthreads();
  #pragma unroll
  for (int mt = 0; mt < 2; mt++)
    #pragma unroll
    for (int nt = 0; nt < 2; nt++)
      #pragma unroll
      for (int q = 0; q < 4; q++)
        Bb[(wr + mt * 16 + kg * 4 + q) * 72 + wc + nt * 16 + ln15] = gmb[mt][nt][q];
  __syncthreads();
  // Phase B1 + C1
  f32x4 accY1[2][2] = {}, accZ1[2][2] = {};
  #pragma unroll
  for (int ks = 0; ks < 2; ks++) {
    short8v af[2], bq[2];
    #pragma unroll
    for (int mt = 0; mt < 2; mt++)
      af[mt] = *reinterpret_cast<const short8v*>(&Bb[(wr + mt * 16 + ln15) * 72 + ks * 32 + kg * 8]);
    #pragma unroll
    for (int nt = 0; nt < 2; nt++)
      bq[nt] = *reinterpret_cast<const short8v*>(&XT[(wc + nt * 16 + ln15) * 72 + ks * 32 + kg * 8]);
    #pragma unroll
    for (int mt = 0; mt < 2; mt++)
      #pragma unroll
      for (int nt = 0; nt < 2; nt++)
        accY1[mt][nt] = __builtin_amdgcn_mfma_f32_16x16x32_bf16(af[mt], bq[nt], accY1[mt][nt], 0, 0, 0);
  }
  #pragma unroll
  for (int ks = 0; ks < 2; ks++) {
    short8v af[2], bq[2];
    #pragma unroll
    for (int mt = 0; mt < 2; mt++)
      af[mt] = *reinterpret_cast<const short8v*>(&Cb[(wr + mt * 16 + ln15) * 72 + ks * 32 + kg * 8]);
    #pragma unroll
    for (int nt = 0; nt < 2; nt++)
      bq[nt] = *reinterpret_cast<const short8v*>(&hb[(wc + nt * 16 + ln15) * 72 + ks * 32 + kg * 8]);
    #pragma unroll
    for (int mt = 0; mt < 2; mt++)
      #pragma unroll
      for (int nt = 0; nt < 2; nt++)
        accZ1[mt][nt] = __builtin_amdgcn_mfma_f32_16x16x32_bf16(af[mt], bq[nt], accZ1[mt][nt], 0, 0, 0);
  }
  #pragma unroll
  for (int mt = 0; mt < 2; mt++)
    #pragma unroll
    for (int q = 0; q < 4; q++) {
      int t = wr + mt * 16 + kg * 4 + q;
      float wB = expf(Cum[t]);
      const unsigned short* xp = xbc + (row1 + t) * conv_dim + (h << 6);
      unsigned short* yp = y + (row1 + t) * d_inner + (h << 6);
      #pragma unroll
      for (int nt = 0; nt < 2; nt++) {
        int p = wc + nt * 16 + ln15;
        yp[p] = f2bf(accY1[mt][nt][q] + accZ1[mt][nt][q] * wB + bf2f(xp[p]) * Dv);
      }
    }
}

// --- wave-per-row: g = y*silu(z); g *= rsqrt(mean(g^2)+eps)*rms_w; bf16 out ---
template <int CPL>
__global__ __launch_bounds__(256) void gate_rms_bf16(const unsigned short* __restrict__ y,
                                                     const unsigned short* __restrict__ z,
                                                     const float* __restrict__ rmsw,
                                                     unsigned short* __restrict__ ab,
                                                     int d_inner) {
  long row = (long)blockIdx.x * 4 + (threadIdx.x >> 6);
  int lane = threadIdx.x & 63;
  const unsigned short* yr = y + row * d_inner;
  const unsigned short* zr = z + row * d_inner;
  float g[CPL];
  float ss = 0.f;
  #pragma unroll
  for (int j = 0; j < CPL / 4; j++) {
    int c = j * 256 + lane * 4;
    ushort4 yv = *reinterpret_cast<const ushort4*>(&yr[c]);
    ushort4 zv = *reinterpret_cast<const ushort4*>(&zr[c]);
    float g0 = bf2f(yv.x) * siluf(bf2f(zv.x));
    float g1 = bf2f(yv.y) * siluf(bf2f(zv.y));
    float g2 = bf2f(yv.z) * siluf(bf2f(zv.z));
    float g3 = bf2f(yv.w) * siluf(bf2f(zv.w));
    g[j * 4 + 0] = g0; g[j * 4 + 1] = g1; g[j * 4 + 2] = g2; g[j * 4 + 3] = g3;
    ss += g0 * g0 + g1 * g1 + g2 * g2 + g3 * g3;
  }
  #pragma unroll
  for (int o = 32; o; o >>= 1) ss += __shfl_xor(ss, o);
  float inv = rsqrtf(ss / (float)d_inner + EPSV);
  #pragma unroll
  for (int j = 0; j < CPL / 4; j++) {
    int c = j * 256 + lane * 4;
    float4 wv = *reinterpret_cast<const float4*>(&rmsw[c]);
    ushort4 o;
    o.x = f2bf(g[j * 4 + 0] * inv * wv.x);
    o.y = f2bf(g[j * 4 + 1] * inv * wv.y);
    o.z = f2bf(g[j * 4 + 2] * inv * wv.z);
    o.w = f2bf(g[j * 4 + 3] * inv * wv.w);
    *reinterpret_cast<ushort4*>(&ab[row * d_inner + c]) = o;
  }
}

extern "C" void kernel_launch(void* const* d_in, const int* in_sizes, int n_in,
                              void* d_out, int out_size, void* d_ws,
                              size_t ws_size, hipStream_t stream) {
  const float* x        = (const float*)d_in[0];
  const float* ln_spa_w = (const float*)d_in[1];
  const float* ln_spa_b = (const float*)d_in[2];
  const float* ln_spe_w = (const float*)d_in[3];
  const float* ln_spe_b = (const float*)d_in[4];
  const float* spa_W_in   = (const float*)d_in[5];
  const float* spa_conv_w = (const float*)d_in[6];
  const float* spa_conv_b = (const float*)d_in[7];
  const float* spa_dt_b   = (const float*)d_in[8];
  const float* spa_A_log  = (const float*)d_in[9];
  const float* spa_D      = (const float*)d_in[10];
  const float* spa_rms_w  = (const float*)d_in[11];
  const float* spa_W_out  = (const float*)d_in[12];
  const float* spe_W_in   = (const float*)d_in[13];
  const float* spe_conv_w = (const float*)d_in[14];
  const float* spe_conv_b = (const float*)d_in[15];
  const float* spe_dt_b   = (const float*)d_in[16];
  const float* spe_A_log  = (const float*)d_in[17];
  const float* spe_D      = (const float*)d_in[18];
  const float* spe_rms_w  = (const float*)d_in[19];
  const float* spe_W_out  = (const float*)d_in[20];
  float* out = (float*)d_out;

  float* ws = (float*)d_ws;
  float* xspa   = ws;                 // 1,048,576
  unsigned short* z = (unsigned short*)(ws + 1048576);
  unsigned short* xbcraw = (unsigned short*)(ws + 3145728);
  float* Sc     = ws + 3145728;       // overlay (xbcraw dead after conv; spa only)
  float* dtraw  = ws + 6291456;       // 32,768 (later Aprod)
  unsigned short* cv = (unsigned short*)(ws + 6324224);
  float* dtb    = ws + 9469952;       // 32,768 (also spe LN partials)
  float* la     = ws + 9502720;       // 32,768
  unsigned short* yb = (unsigned short*)(ws + 9535488);
  unsigned short* Abf     = (unsigned short*)(ws + 11634688);
  unsigned short* Wt_spai = (unsigned short*)(ws + 12683264);
  unsigned short* Wt_spao = (unsigned short*)(ws + 12724480);
  unsigned short* Wt_spei = (unsigned short*)(ws + 12740864);
  unsigned short* Wt_speo = (unsigned short*)(ws + 14919936);

  // 1. fused prologue: spa LN (blocks 0..4095) + all weight transposes
  hipLaunchKernelGGL(ln_wt_fused, dim3(5710), dim3(256), 0, stream,
                     x, ln_spa_w, ln_spa_b, Abf,
                     spa_W_in, Wt_spai, spa_W_out, Wt_spao,
                     spe_W_in, Wt_spei, spe_W_out, Wt_speo);

  // ================= spatial mamba (L=1024, d_model=128) =================
  hipLaunchKernelGGL(gemm128_split, dim3(6, 64), dim3(256), 0, stream,
                     Abf, Wt_spai, z, xbcraw, dtraw,
                     8192, 644, 128, 256, 640);
  hipLaunchKernelGGL(conv_dtda, dim3(3200), dim3(256), 0, stream,
                     xbcraw, spa_conv_w, spa_conv_b, cv,
                     dtraw, spa_dt_b, spa_A_log, dtb, la,
                     8, 1024, 384, 4, 32768, 3072);
  hipLaunchKernelGGL(ssd_local, dim3(480), dim3(256), 0, stream,
                     cv, dtb, la, Sc, dtraw, 16, 15, 4, 384, 256);
  hipLaunchKernelGGL(ssd_out, dim3(512), dim3(256), 0, stream,
                     cv, dtb, la, Sc, dtraw, spa_D, yb, 16, 4, 384, 256);
  hipLaunchKernelGGL((gate_rms_bf16<4>), dim3(2048), dim3(256), 0, stream,
                     yb, z, spa_rms_w, Abf, 256);
  hipLaunchKernelGGL(gemm_mfma1, dim3(2, 128), dim3(256), 0, stream,
                     Abf, Wt_spao, x, xspa, dtb, 8192, 128, 256);

  // ================= spectral mamba (L=128, d_model=1024) =================
  hipLaunchKernelGGL(spe_normT, dim3(2, 8, 8), dim3(256), 0, stream,
                     xspa, dtb, ln_spe_w, ln_spe_b, Abf);
  hipLaunchKernelGGL(gemm128_split, dim3(34, 8), dim3(256), 0, stream,
                     Abf, Wt_spei, z, xbcraw, dtraw,
                     1024, 4256, 1024, 2048, 4224);
  hipLaunchKernelGGL(conv_dtda, dim3(2304), dim3(256), 0, stream,
                     xbcraw, spe_conv_w, spe_conv_b, cv,
                     dtraw, spe_dt_b, spe_A_log, dtb, la,
                     8, 128, 2176, 32, 32768, 2176);
  hipLaunchKernelGGL(ssd_spe2, dim3(256), dim3(256), 0, stream,
                     cv, dtb, la, spe_D, yb, 32, 2176, 2048);
  hipLaunchKernelGGL((gate_rms_bf16<32>), dim3(256), dim3(256), 0, stream,
                     yb, z, spe_rms_w, Abf, 2048);
  hipLaunchKernelGGL(gemm128x64_t, dim3(16, 8), dim3(256), 0, stream,
                     Abf, Wt_speo, xspa, out, 1024, 1024, 2048);
}

// Round 16
// 157.053 us; speedup vs baseline: 1.4258x; 1.0053x over previous
//
#include <hip/hip_runtime.h>
#include <hip/hip_bf16.h>

#define EPSV 1e-5f

typedef __attribute__((ext_vector_type(8))) short short8v;   // 8 bf16 in 4 VGPRs
typedef __attribute__((ext_vector_type(4))) float f32x4;

__device__ inline unsigned short f2bf(float f) {
  __hip_bfloat16 h = __float2bfloat16(f);
  return *reinterpret_cast<unsigned short*>(&h);
}

__device__ inline float bf2f(unsigned short u) {
  return __uint_as_float(((unsigned int)u) << 16);
}

__device__ inline float siluf(float x) { return x / (1.f + expf(-x)); }

// direct global->LDS 16B async copy (lane-linear dest: base + lane*16)
__device__ inline void gload_lds16(const void* g, void* l) {
  __builtin_amdgcn_global_load_lds(
      (const __attribute__((address_space(1))) void*)g,
      (__attribute__((address_space(3))) void*)l, 16, 0, 0);
}

// inclusive prefix sum over 64 lanes (call from wave 0 only)
__device__ inline float wave_prefix_incl(float v, int lane) {
  #pragma unroll
  for (int o = 1; o < 64; o <<= 1) {
    float u = __shfl_up(v, o);
    if (lane >= o) v += u;
  }
  return v;
}

// ------- weight transpose tile W[K][N] -> Wt[N][K] bf16 -------
__device__ inline void wtconv_tile(const float* __restrict__ W,
                                   unsigned short* __restrict__ Wt,
                                   int K, int N, int bx, int by) {
  __shared__ float tile[64][65];
  int n0 = bx * 64, k0 = by * 64;
  int tid = threadIdx.x;
  int r = tid >> 4, c4 = (tid & 15) * 4;
  #pragma unroll
  for (int i = 0; i < 4; i++) {
    int kk = r + i * 16;
    float4 v = make_float4(0.f, 0.f, 0.f, 0.f);
    if (n0 + c4 < N) v = *reinterpret_cast<const float4*>(&W[(long)(k0 + kk) * N + n0 + c4]);
    tile[kk][c4] = v.x; tile[kk][c4 + 1] = v.y; tile[kk][c4 + 2] = v.z; tile[kk][c4 + 3] = v.w;
  }
  __syncthreads();
  #pragma unroll
  for (int i = 0; i < 4; i++) {
    int nl = r + i * 16;
    if (n0 + nl < N) {
      ushort4 o;
      o.x = f2bf(tile[c4 + 0][nl]);
      o.y = f2bf(tile[c4 + 1][nl]);
      o.z = f2bf(tile[c4 + 2][nl]);
      o.w = f2bf(tile[c4 + 3][nl]);
      *reinterpret_cast<ushort4*>(&Wt[(long)(n0 + nl) * K + k0 + c4]) = o;
    }
  }
}

// ---- prologue: spa LN (2 rows/block, bf16 out) + spa_W_in transpose only ----
__global__ __launch_bounds__(256) void ln_wt0(const float* __restrict__ x,
                                              const float* __restrict__ w,
                                              const float* __restrict__ bb,
                                              unsigned short* __restrict__ outA,
                                              const float* __restrict__ W0,
                                              unsigned short* __restrict__ T0) {
  int id = blockIdx.x;
  if (id < 4096) {
    int tid = threadIdx.x;
    __shared__ float lds[4];
    long row = (long)id * 2 + (tid >> 7);
    int lane = tid & 127;
    int base = (tid >> 7) << 1;
    float v = x[row * 128 + lane];
    float s = v;
    #pragma unroll
    for (int o = 32; o; o >>= 1) s += __shfl_xor(s, o);
    if ((tid & 63) == 0) lds[tid >> 6] = s;
    __syncthreads();
    float m = (lds[base] + lds[base + 1]) * (1.f / 128.f);
    float d = v - m;
    float q = d * d;
    #pragma unroll
    for (int o = 32; o; o >>= 1) q += __shfl_xor(q, o);
    __syncthreads();
    if ((tid & 63) == 0) lds[tid >> 6] = q;
    __syncthreads();
    float inv = rsqrtf((lds[base] + lds[base + 1]) * (1.f / 128.f) + EPSV);
    outA[row * 128 + lane] = f2bf(d * inv * w[lane] + bb[lane]);
  } else {
    int r = id - 4096;
    wtconv_tile(W0, T0, 128, 644, r % 11, r / 11);
  }
}

// ---- spe LN pass 2: finalize per-(b,ch) stats from GEMM partials,
//      normalize + transpose, emit bf16. part2: float2[(by*2+bx)*64 + cl]
__global__ __launch_bounds__(256) void spe_normT(const float* __restrict__ xspa,
                                                 const float* __restrict__ part2,
                                                 const float* __restrict__ w,
                                                 const float* __restrict__ bb,
                                                 unsigned short* __restrict__ out) {
  __shared__ float tile[128][65];
  int c0 = blockIdx.x * 64, l0 = blockIdx.y * 128, b = blockIdx.z;
  int tid = threadIdx.x;
  int rr = tid >> 4, c4 = (tid & 15) * 4;
  #pragma unroll
  for (int p = 0; p < 8; p++) {
    int l = rr + p * 16;
    f32x4 v = *reinterpret_cast<const f32x4*>(
        &xspa[((long)b * 1024 + l0 + l) * 128 + c0 + c4]);
    tile[l][c4] = v[0]; tile[l][c4 + 1] = v[1];
    tile[l][c4 + 2] = v[2]; tile[l][c4 + 3] = v[3];
  }
  __syncthreads();
  int ch = tid >> 2, lq = tid & 3;
  int gc = c0 + ch;
  int bx = gc >> 6, cl = gc & 63;
  float ssum = 0.f, qsum = 0.f;
  #pragma unroll
  for (int sub = 0; sub < 16; sub++) {
    int by = b * 16 + sub;
    float2 pq = *reinterpret_cast<const float2*>(&part2[(((by * 2 + bx) * 64) + cl) * 2]);
    ssum += pq.x; qsum += pq.y;
  }
  float mm = ssum * (1.f / 1024.f);
  float rstd = rsqrtf(qsum * (1.f / 1024.f) - mm * mm + EPSV);
  #pragma unroll
  for (int j = 0; j < 8; j++) {
    int qidx = lq + j * 4;
    int l = qidx * 4;
    float4 wv = *reinterpret_cast<const float4*>(&w[l0 + l]);
    float4 bv = *reinterpret_cast<const float4*>(&bb[l0 + l]);
    ushort4 o;
    o.x = f2bf((tile[l + 0][ch] - mm) * rstd * wv.x + bv.x);
    o.y = f2bf((tile[l + 1][ch] - mm) * rstd * wv.y + bv.y);
    o.z = f2bf((tile[l + 2][ch] - mm) * rstd * wv.z + bv.z);
    o.w = f2bf((tile[l + 3][ch] - mm) * rstd * wv.w + bv.w);
    *reinterpret_cast<ushort4*>(&out[((long)b * 128 + c0 + ch) * 1024 + l0 + l]) = o;
  }
}

// ------- 128x128-tile bf16 MFMA GEMM, DOUBLE-BUFFERED gload_lds staging -------
// column-split epilogue: c<c1 -> zout (bf16, ld c1); c<c2 -> o2 (bf16); else o3 (f32)
__global__ __launch_bounds__(256) void gemm128_split(const unsigned short* __restrict__ A,
                                                     const unsigned short* __restrict__ Bt,
                                                     unsigned short* __restrict__ zout,
                                                     unsigned short* __restrict__ o2,
                                                     float* __restrict__ o3,
                                                     int M, int N, int K,
                                                     int c1, int c2) {
  __shared__ unsigned short As[2][128 * 32];
  __shared__ unsigned short Bs[2][128 * 32];
  int tid = threadIdx.x;
  int lane = tid & 63, w = tid >> 6;
  int wr = (w >> 1) * 64, wc = (w & 1) * 64;
  int ln15 = lane & 15, kg = lane >> 4;
  int rowBase = blockIdx.y * 128, colBase = blockIdx.x * 128;
  int srow = w * 32 + (lane >> 2);
  int scol = (lane & 3) * 8;
  f32x4 acc[4][4] = {};
  auto stage = [&](int buf, int k0) {
    gload_lds16(&A[(long)(rowBase + srow) * K + k0 + scol], &As[buf][(w * 32) * 32]);
    gload_lds16(&A[(long)(rowBase + srow + 16) * K + k0 + scol], &As[buf][(w * 32 + 16) * 32]);
    gload_lds16(&Bt[(long)(colBase + srow) * K + k0 + scol], &Bs[buf][(w * 32) * 32]);
    gload_lds16(&Bt[(long)(colBase + srow + 16) * K + k0 + scol], &Bs[buf][(w * 32 + 16) * 32]);
  };
  stage(0, 0);
  __syncthreads();
  int cur = 0;
  for (int k0 = 0; k0 < K; k0 += 32) {
    if (k0 + 32 < K) stage(cur ^ 1, k0 + 32);
    short8v af[4], bfr[4];
    #pragma unroll
    for (int mt = 0; mt < 4; mt++)
      af[mt] = *reinterpret_cast<const short8v*>(&As[cur][(wr + mt * 16 + ln15) * 32 + kg * 8]);
    #pragma unroll
    for (int nt = 0; nt < 4; nt++)
      bfr[nt] = *reinterpret_cast<const short8v*>(&Bs[cur][(wc + nt * 16 + ln15) * 32 + kg * 8]);
    #pragma unroll
    for (int mt = 0; mt < 4; mt++)
      #pragma unroll
      for (int nt = 0; nt < 4; nt++)
        acc[mt][nt] = __builtin_amdgcn_mfma_f32_16x16x32_bf16(af[mt], bfr[nt], acc[mt][nt], 0, 0, 0);
    __syncthreads();
    cur ^= 1;
  }
  #pragma unroll
  for (int mt = 0; mt < 4; mt++)
    #pragma unroll
    for (int nt = 0; nt < 4; nt++)
      #pragma unroll
      for (int q = 0; q < 4; q++) {
        int r = rowBase + wr + mt * 16 + kg * 4 + q;
        int c = colBase + wc + nt * 16 + ln15;
        if (c < N) {
          float v = acc[mt][nt][q];
          if (c < c1) zout[(long)r * c1 + c] = f2bf(v);
          else if (c < c2) o2[(long)r * (c2 - c1) + (c - c1)] = f2bf(v);
          else o3[(long)r * (N - c2) + (c - c2)] = v;
        }
      }
}

// ------- 128(rows)x64(cols)-tile GEMM, dbuf gload_lds, transposed-add -------
__global__ __launch_bounds__(256) void gemm128x64_t(const unsigned short* __restrict__ A,
                                                    const unsigned short* __restrict__ Bt,
                                                    const float* __restrict__ R,
                                                    float* __restrict__ out,
                                                    int M, int N, int K) {
  __shared__ unsigned short As[2][128 * 32];
  __shared__ unsigned short Bs[2][64 * 32];
  int tid = threadIdx.x;
  int lane = tid & 63, w = tid >> 6;
  int wr = w * 32;
  int ln15 = lane & 15, kg = lane >> 4;
  int rowBase = blockIdx.y * 128, colBase = blockIdx.x * 64;
  int arow = w * 32 + (lane >> 2);
  int brow = w * 16 + (lane >> 2);
  int scol = (lane & 3) * 8;
  f32x4 acc[2][4] = {};
  auto stage = [&](int buf, int k0) {
    gload_lds16(&A[(long)(rowBase + arow) * K + k0 + scol], &As[buf][(w * 32) * 32]);
    gload_lds16(&A[(long)(rowBase + arow + 16) * K + k0 + scol], &As[buf][(w * 32 + 16) * 32]);
    gload_lds16(&Bt[(long)(colBase + brow) * K + k0 + scol], &Bs[buf][(w * 16) * 32]);
  };
  stage(0, 0);
  __syncthreads();
  int cur = 0;
  for (int k0 = 0; k0 < K; k0 += 32) {
    if (k0 + 32 < K) stage(cur ^ 1, k0 + 32);
    short8v af[2], bfr[4];
    #pragma unroll
    for (int mt = 0; mt < 2; mt++)
      af[mt] = *reinterpret_cast<const short8v*>(&As[cur][(wr + mt * 16 + ln15) * 32 + kg * 8]);
    #pragma unroll
    for (int nt = 0; nt < 4; nt++)
      bfr[nt] = *reinterpret_cast<const short8v*>(&Bs[cur][(nt * 16 + ln15) * 32 + kg * 8]);
    #pragma unroll
    for (int mt = 0; mt < 2; mt++)
      #pragma unroll
      for (int nt = 0; nt < 4; nt++)
        acc[mt][nt] = __builtin_amdgcn_mfma_f32_16x16x32_bf16(af[mt], bfr[nt], acc[mt][nt], 0, 0, 0);
    __syncthreads();
    cur ^= 1;
  }
  #pragma unroll
  for (int mt = 0; mt < 2; mt++)
    #pragma unroll
    for (int nt = 0; nt < 4; nt++)
      #pragma unroll
      for (int q = 0; q < 4; q++) {
        int r = rowBase + wr + mt * 16 + kg * 4 + q;
        int c = colBase + nt * 16 + ln15;
        int bb = r >> 7, ch = r & 127;
        out[(long)bb * 131072 + (long)c * 128 + ch] =
            acc[mt][nt][q] + R[((long)bb * 1024 + c) * 128 + ch];
      }
}

// ------ 64x64-tile bf16 MFMA GEMM (spa W_out), dbuf gload_lds staging ------
// out = v + R; also emits deterministic per-block column {sum,sum^2} partials.
__global__ __launch_bounds__(256) void gemm_mfma1(const unsigned short* __restrict__ A,
                                                  const unsigned short* __restrict__ Bt,
                                                  const float* __restrict__ R,
                                                  float* __restrict__ out,
                                                  float* __restrict__ part2,
                                                  int M, int N, int K) {
  __shared__ unsigned short As[2][64 * 32];
  __shared__ unsigned short Bs[2][64 * 32];
  int tid = threadIdx.x;
  int lane = tid & 63, w = tid >> 6;
  int wr = (w >> 1) * 32, wc = (w & 1) * 32;
  int ln15 = lane & 15, kg = lane >> 4;
  int rowBase = blockIdx.y * 64, colBase = blockIdx.x * 64;
  int srow = w * 16 + (lane >> 2);
  int scol = (lane & 3) * 8;
  f32x4 acc[2][2] = {};
  auto stage = [&](int buf, int k0) {
    gload_lds16(&A[(long)(rowBase + srow) * K + k0 + scol], &As[buf][(w * 16) * 32]);
    gload_lds16(&Bt[(long)(colBase + srow) * K + k0 + scol], &Bs[buf][(w * 16) * 32]);
  };
  stage(0, 0);
  __syncthreads();
  int cur = 0;
  for (int k0 = 0; k0 < K; k0 += 32) {
    if (k0 + 32 < K) stage(cur ^ 1, k0 + 32);
    short8v af[2], bfr[2];
    #pragma unroll
    for (int mt = 0; mt < 2; mt++)
      af[mt] = *reinterpret_cast<const short8v*>(&As[cur][(wr + mt * 16 + ln15) * 32 + kg * 8]);
    #pragma unroll
    for (int nt = 0; nt < 2; nt++)
      bfr[nt] = *reinterpret_cast<const short8v*>(&Bs[cur][(wc + nt * 16 + ln15) * 32 + kg * 8]);
    #pragma unroll
    for (int mt = 0; mt < 2; mt++)
      #pragma unroll
      for (int nt = 0; nt < 2; nt++)
        acc[mt][nt] = __builtin_amdgcn_mfma_f32_16x16x32_bf16(af[mt], bfr[nt], acc[mt][nt], 0, 0, 0);
    __syncthreads();
    cur ^= 1;
  }
  float sC[2] = {0.f, 0.f}, qC[2] = {0.f, 0.f};
  #pragma unroll
  for (int mt = 0; mt < 2; mt++)
    #pragma unroll
    for (int nt = 0; nt < 2; nt++)
      #pragma unroll
      for (int q = 0; q < 4; q++) {
        int r = rowBase + wr + mt * 16 + kg * 4 + q;
        int c = colBase + wc + nt * 16 + ln15;
        float v = acc[mt][nt][q] + R[(long)r * N + c];
        out[(long)r * N + c] = v;
        sC[nt] += v;
        qC[nt] += v * v;
      }
  __shared__ float redS[4][32], redQ[4][32];
  #pragma unroll
  for (int nt = 0; nt < 2; nt++) {
    sC[nt] += __shfl_xor(sC[nt], 16);
    sC[nt] += __shfl_xor(sC[nt], 32);
    qC[nt] += __shfl_xor(qC[nt], 16);
    qC[nt] += __shfl_xor(qC[nt], 32);
  }
  if (lane < 16) {
    redS[w][ln15] = sC[0];       redQ[w][ln15] = qC[0];
    redS[w][16 + ln15] = sC[1];  redQ[w][16 + ln15] = qC[1];
  }
  __syncthreads();
  if (tid < 64) {
    int c = tid;
    int grp = c >> 5, lo = c & 31;
    float ss = redS[grp][lo] + redS[grp + 2][lo];
    float qq = redQ[grp][lo] + redQ[grp + 2][lo];
    long slot = ((long)(blockIdx.y * 2 + blockIdx.x) * 64 + c) * 2;
    part2[slot] = ss;
    part2[slot + 1] = qq;
  }
}

// ---- fused: causal depthwise conv (bf16 in/out) + SiLU | dt/la | wt tiles ----
// blocks >= wtBase carry weight-transpose tiles (Wa: 8 tiles, then Wb: 1072).
__global__ __launch_bounds__(256) void conv_dtda(const unsigned short* __restrict__ zx,
                                                 const float* __restrict__ cw,
                                                 const float* __restrict__ cb,
                                                 unsigned short* __restrict__ cout,
                                                 const float* __restrict__ raw,
                                                 const float* __restrict__ dtbias,
                                                 const float* __restrict__ alog,
                                                 float* __restrict__ dt,
                                                 float* __restrict__ la,
                                                 int Bb, int L, int conv_dim,
                                                 int H, int rowsH, int convBlocks,
                                                 const float* __restrict__ Wa,
                                                 unsigned short* __restrict__ Ta,
                                                 const float* __restrict__ Wb,
                                                 unsigned short* __restrict__ Tb,
                                                 int wtBase) {
  int bid = blockIdx.x;
  int tid = threadIdx.x;
  if (bid >= wtBase) {
    int id = bid - wtBase;
    if (id < 8) wtconv_tile(Wa, Ta, 256, 128, id % 2, id / 2);
    else { int r = id - 8; wtconv_tile(Wb, Tb, 1024, 4256, r % 67, r / 67); }
    return;
  }
  if (bid < convBlocks) {
    long idx4 = (long)bid * 256 + tid;
    int nch4 = conv_dim >> 2;
    long total4 = (long)Bb * L * nch4;
    if (idx4 >= total4) return;
    int ch = (int)(idx4 % nch4) << 2;
    long rt = idx4 / nch4;
    int t = (int)(rt % L);
    int b = (int)(rt / L);
    f32x4 acc = *reinterpret_cast<const f32x4*>(&cb[ch]);
    #pragma unroll
    for (int k = 0; k < 4; k++) {
      int tt = t + k - 3;
      if (tt >= 0) {
        f32x4 wv = *reinterpret_cast<const f32x4*>(&cw[k * conv_dim + ch]);
        ushort4 zu = *reinterpret_cast<const ushort4*>(
            &zx[((long)b * L + tt) * conv_dim + ch]);
        acc[0] += wv[0] * bf2f(zu.x);
        acc[1] += wv[1] * bf2f(zu.y);
        acc[2] += wv[2] * bf2f(zu.z);
        acc[3] += wv[3] * bf2f(zu.w);
      }
    }
    ushort4 o;
    o.x = f2bf(siluf(acc[0])); o.y = f2bf(siluf(acc[1]));
    o.z = f2bf(siluf(acc[2])); o.w = f2bf(siluf(acc[3]));
    *reinterpret_cast<ushort4*>(&cout[rt * conv_dim + ch]) = o;
  } else {
    int idx = (bid - convBlocks) * 256 + tid;
    if (idx >= rowsH) return;
    int h = idx % H;
    float v = raw[idx] + dtbias[h];
    float sp = (v > 20.f) ? v : log1pf(expf(v));
    dt[idx] = sp;
    la[idx] = -expf(alog[h]) * sp;
  }
}

// ===================== spa chunked SSD (T=64), MFMA, bf16 inputs =====================
// K1: S[p,n] = sum_t (Ws[t]*X[t,p]) * B[t,n].  blocks >= wtBase: spe_W_out tiles.
__global__ __launch_bounds__(256) void ssd_local(const unsigned short* __restrict__ xbc,
                                                 const float* __restrict__ dtv,
                                                 const float* __restrict__ la,
                                                 float* __restrict__ Sc,
                                                 float* __restrict__ Aprod,
                                                 int NC, int nc_launch, int H,
                                                 int conv_dim, int d_inner,
                                                 const float* __restrict__ Wc,
                                                 unsigned short* __restrict__ Tc,
                                                 int wtBase) {
  int blk = blockIdx.x;
  if (blk >= wtBase) {
    int r = blk - wtBase;
    wtconv_tile(Wc, Tc, 2048, 1024, r % 16, r / 16);
    return;
  }
  int c = blk % nc_launch, bh = blk / nc_launch;
  int h = bh % H, b = bh / H;
  int tid = threadIdx.x;
  long row0 = ((long)(b * NC + c)) * 64;
  __shared__ unsigned short XpT[64 * 72];
  __shared__ unsigned short BT[64 * 72];
  __shared__ float Ws[64];
  int tq = tid >> 4, cq = (tid & 15) << 2;
  ushort4 xr[4], br[4];
  #pragma unroll
  for (int i = 0; i < 4; i++) {
    int t = tq + i * 16;
    const unsigned short* rp = xbc + (row0 + t) * conv_dim;
    xr[i] = *reinterpret_cast<const ushort4*>(rp + (h << 6) + cq);
    br[i] = *reinterpret_cast<const ushort4*>(rp + d_inner + cq);
  }
  if (tid < 64) {
    long r = (row0 + tid) * H + h;
    float cum = wave_prefix_incl(la[r], tid);
    float cT = __shfl(cum, 63);
    Ws[tid] = expf(cT - cum) * dtv[r];
    if (tid == 63) Aprod[(long)bh * NC + c] = expf(cT);
  }
  __syncthreads();
  #pragma unroll
  for (int i = 0; i < 4; i++) {
    int t = tq + i * 16;
    float wv = Ws[t];
    XpT[(cq + 0) * 72 + t] = f2bf(wv * bf2f(xr[i].x));
    XpT[(cq + 1) * 72 + t] = f2bf(wv * bf2f(xr[i].y));
    XpT[(cq + 2) * 72 + t] = f2bf(wv * bf2f(xr[i].z));
    XpT[(cq + 3) * 72 + t] = f2bf(wv * bf2f(xr[i].w));
    BT[(cq + 0) * 72 + t] = br[i].x;
    BT[(cq + 1) * 72 + t] = br[i].y;
    BT[(cq + 2) * 72 + t] = br[i].z;
    BT[(cq + 3) * 72 + t] = br[i].w;
  }
  __syncthreads();
  int lane = tid & 63, wv2 = tid >> 6;
  int wr = (wv2 >> 1) * 32, wc = (wv2 & 1) * 32;
  int ln15 = lane & 15, kg = lane >> 4;
  f32x4 acc[2][2] = {};
  #pragma unroll
  for (int ks = 0; ks < 2; ks++) {
    short8v af[2], bq[2];
    #pragma unroll
    for (int mt = 0; mt < 2; mt++)
      af[mt] = *reinterpret_cast<const short8v*>(&XpT[(wr + mt * 16 + ln15) * 72 + ks * 32 + kg * 8]);
    #pragma unroll
    for (int nt = 0; nt < 2; nt++)
      bq[nt] = *reinterpret_cast<const short8v*>(&BT[(wc + nt * 16 + ln15) * 72 + ks * 32 + kg * 8]);
    #pragma unroll
    for (int mt = 0; mt < 2; mt++)
      #pragma unroll
      for (int nt = 0; nt < 2; nt++)
        acc[mt][nt] = __builtin_amdgcn_mfma_f32_16x16x32_bf16(af[mt], bq[nt], acc[mt][nt], 0, 0, 0);
  }
  float* base = Sc + ((long)bh * NC + c) * 4096;
  #pragma unroll
  for (int mt = 0; mt < 2; mt++)
    #pragma unroll
    for (int nt = 0; nt < 2; nt++)
      #pragma unroll
      for (int q = 0; q < 4; q++) {
        int p = wr + mt * 16 + kg * 4 + q;
        int n = wc + nt * 16 + ln15;
        base[p * 64 + n] = acc[mt][nt][q];
      }
}

// K3 (spa): MFMA phases with on-the-fly carry fold (fp32, bit-identical order)
__global__ __launch_bounds__(256) void ssd_out(const unsigned short* __restrict__ xbc,
                                               const float* __restrict__ dtv,
                                               const float* __restrict__ la,
                                               const float* __restrict__ Sc,
                                               const float* __restrict__ Aprod,
                                               const float* __restrict__ Dvec,
                                               unsigned short* __restrict__ y,
                                               int NC, int H, int conv_dim,
                                               int d_inner) {
  int blk = blockIdx.x;
  int c = blk % NC, bh = blk / NC;
  int h = bh % H, b = bh / H;
  int tid = threadIdx.x;
  long row0 = ((long)(b * NC + c)) * 64;
  __shared__ unsigned short Cb[64 * 72];
  __shared__ unsigned short Bb[64 * 72];
  __shared__ unsigned short XT[64 * 72];
  __shared__ unsigned short hb[64 * 72];
  __shared__ float Cum[64], Dt[64];
  int tq = tid >> 4, cq = (tid & 15) << 2;
  #pragma unroll
  for (int i = 0; i < 4; i++) {
    int t = tq + i * 16;
    const unsigned short* rp = xbc + (row0 + t) * conv_dim;
    ushort4 cu = *reinterpret_cast<const ushort4*>(rp + d_inner + 64 + cq);
    ushort4 bu = *reinterpret_cast<const ushort4*>(rp + d_inner + cq);
    ushort4 xu = *reinterpret_cast<const ushort4*>(rp + (h << 6) + cq);
    *reinterpret_cast<ushort4*>(&Cb[t * 72 + cq]) = cu;
    *reinterpret_cast<ushort4*>(&Bb[t * 72 + cq]) = bu;
    XT[(cq + 0) * 72 + t] = xu.x;
    XT[(cq + 1) * 72 + t] = xu.y;
    XT[(cq + 2) * 72 + t] = xu.z;
    XT[(cq + 3) * 72 + t] = xu.w;
  }
  if (c > 0) {
    f32x4 hreg[4] = {};
    const float* ap = Aprod + (long)bh * NC;
    for (int j = 0; j < c; j++) {
      const float* sb = Sc + ((long)bh * NC + j) * 4096;
      float a = ap[j];
      #pragma unroll
      for (int i = 0; i < 4; i++) {
        int p = tq + i * 16;
        f32x4 sv = *reinterpret_cast<const f32x4*>(&sb[p * 64 + cq]);
        hreg[i] = hreg[i] * a + sv;
      }
    }
    #pragma unroll
    for (int i = 0; i < 4; i++) {
      int p = tq + i * 16;
      ushort4 ho;
      ho.x = f2bf(hreg[i][0]); ho.y = f2bf(hreg[i][1]);
      ho.z = f2bf(hreg[i][2]); ho.w = f2bf(hreg[i][3]);
      *reinterpret_cast<ushort4*>(&hb[p * 72 + cq]) = ho;
    }
  }
  if (tid < 64) {
    long r = (row0 + tid) * H + h;
    Cum[tid] = wave_prefix_incl(la[r], tid);
    Dt[tid] = dtv[r];
  }
  __syncthreads();
  int lane = tid & 63, wv2 = tid >> 6;
  int wr = (wv2 >> 1) * 32, wc = (wv2 & 1) * 32;
  int ln15 = lane & 15, kg = lane >> 4;
  f32x4 accA[2][2] = {};
  #pragma unroll
  for (int ks = 0; ks < 2; ks++) {
    short8v af[2], bq[2];
    #pragma unroll
    for (int mt = 0; mt < 2; mt++)
      af[mt] = *reinterpret_cast<const short8v*>(&Cb[(wr + mt * 16 + ln15) * 72 + ks * 32 + kg * 8]);
    #pragma unroll
    for (int nt = 0; nt < 2; nt++)
      bq[nt] = *reinterpret_cast<const short8v*>(&Bb[(wc + nt * 16 + ln15) * 72 + ks * 32 + kg * 8]);
    #pragma unroll
    for (int mt = 0; mt < 2; mt++)
      #pragma unroll
      for (int nt = 0; nt < 2; nt++)
        accA[mt][nt] = __builtin_amdgcn_mfma_f32_16x16x32_bf16(af[mt], bq[nt], accA[mt][nt], 0, 0, 0);
  }
  unsigned short gmb[2][2][4];
  #pragma unroll
  for (int mt = 0; mt < 2; mt++)
    #pragma unroll
    for (int nt = 0; nt < 2; nt++)
      #pragma unroll
      for (int q = 0; q < 4; q++) {
        int t = wr + mt * 16 + kg * 4 + q;
        int s = wc + nt * 16 + ln15;
        float v = (s <= t) ? accA[mt][nt][q] * expf(Cum[t] - Cum[s]) * Dt[s] : 0.f;
        gmb[mt][nt][q] = f2bf(v);
      }
  __syncthreads();
  #pragma unroll
  for (int mt = 0; mt < 2; mt++)
    #pragma unroll
    for (int nt = 0; nt < 2; nt++)
      #pragma unroll
      for (int q = 0; q < 4; q++)
        Bb[(wr + mt * 16 + kg * 4 + q) * 72 + wc + nt * 16 + ln15] = gmb[mt][nt][q];
  __syncthreads();
  f32x4 accY[2][2] = {}, accZ[2][2] = {};
  #pragma unroll
  for (int ks = 0; ks < 2; ks++) {
    short8v af[2], bq[2];
    #pragma unroll
    for (int mt = 0; mt < 2; mt++)
      af[mt] = *reinterpret_cast<const short8v*>(&Bb[(wr + mt * 16 + ln15) * 72 + ks * 32 + kg * 8]);
    #pragma unroll
    for (int nt = 0; nt < 2; nt++)
      bq[nt] = *reinterpret_cast<const short8v*>(&XT[(wc + nt * 16 + ln15) * 72 + ks * 32 + kg * 8]);
    #pragma unroll
    for (int mt = 0; mt < 2; mt++)
      #pragma unroll
      for (int nt = 0; nt < 2; nt++)
        accY[mt][nt] = __builtin_amdgcn_mfma_f32_16x16x32_bf16(af[mt], bq[nt], accY[mt][nt], 0, 0, 0);
  }
  if (c > 0) {
    #pragma unroll
    for (int ks = 0; ks < 2; ks++) {
      short8v af[2], bq[2];
      #pragma unroll
      for (int mt = 0; mt < 2; mt++)
        af[mt] = *reinterpret_cast<const short8v*>(&Cb[(wr + mt * 16 + ln15) * 72 + ks * 32 + kg * 8]);
      #pragma unroll
      for (int nt = 0; nt < 2; nt++)
        bq[nt] = *reinterpret_cast<const short8v*>(&hb[(wc + nt * 16 + ln15) * 72 + ks * 32 + kg * 8]);
      #pragma unroll
      for (int mt = 0; mt < 2; mt++)
        #pragma unroll
        for (int nt = 0; nt < 2; nt++)
          accZ[mt][nt] = __builtin_amdgcn_mfma_f32_16x16x32_bf16(af[mt], bq[nt], accZ[mt][nt], 0, 0, 0);
    }
  }
  float Dv = Dvec[h];
  #pragma unroll
  for (int mt = 0; mt < 2; mt++)
    #pragma unroll
    for (int q = 0; q < 4; q++) {
      int t = wr + mt * 16 + kg * 4 + q;
      float wB = expf(Cum[t]);
      const unsigned short* xp = xbc + (row0 + t) * conv_dim + (h << 6);
      unsigned short* yp = y + (row0 + t) * d_inner + (h << 6);
      #pragma unroll
      for (int nt = 0; nt < 2; nt++) {
        int p = wc + nt * 16 + ln15;
        yp[p] = f2bf(accY[mt][nt][q] + accZ[mt][nt][q] * wB + bf2f(xp[p]) * Dv);
      }
    }
}

// ========== spe fused SSD (NC=2): S_0 + out(c=0) + out(c=1) in one block ==========
__global__ __launch_bounds__(256) void ssd_spe2(const unsigned short* __restrict__ xbc,
                                                const float* __restrict__ dtv,
                                                const float* __restrict__ la,
                                                const float* __restrict__ Dvec,
                                                unsigned short* __restrict__ y,
                                                int H, int conv_dim, int d_inner) {
  int bh = blockIdx.x;
  int h = bh % H, b = bh / H;
  int tid = threadIdx.x;
  __shared__ unsigned short Cb[64 * 72];
  __shared__ unsigned short Bb[64 * 72];
  __shared__ unsigned short XT[64 * 72];
  __shared__ unsigned short BT2[64 * 72];
  __shared__ unsigned short WXT[64 * 72];
  __shared__ unsigned short hb[64 * 72];
  __shared__ float Cum[64], Dt[64], Wsh[64];
  int tq = tid >> 4, cq = (tid & 15) << 2;
  int lane = tid & 63, wv2 = tid >> 6;
  int wr = (wv2 >> 1) * 32, wc = (wv2 & 1) * 32;
  int ln15 = lane & 15, kg = lane >> 4;
  float Dv = Dvec[h];

  long row0 = (long)b * 128;
  ushort4 cu[4], bu[4], xu[4];
  #pragma unroll
  for (int i = 0; i < 4; i++) {
    int t = tq + i * 16;
    const unsigned short* rp = xbc + (row0 + t) * conv_dim;
    cu[i] = *reinterpret_cast<const ushort4*>(rp + d_inner + 64 + cq);
    bu[i] = *reinterpret_cast<const ushort4*>(rp + d_inner + cq);
    xu[i] = *reinterpret_cast<const ushort4*>(rp + (h << 6) + cq);
  }
  if (tid < 64) {
    long r = (row0 + tid) * H + h;
    float cum = wave_prefix_incl(la[r], tid);
    float cT = __shfl(cum, 63);
    Cum[tid] = cum;
    Dt[tid] = dtv[r];
    Wsh[tid] = expf(cT - cum) * dtv[r];
  }
  __syncthreads();
  #pragma unroll
  for (int i = 0; i < 4; i++) {
    int t = tq + i * 16;
    float wvv = Wsh[t];
    *reinterpret_cast<ushort4*>(&Cb[t * 72 + cq]) = cu[i];
    *reinterpret_cast<ushort4*>(&Bb[t * 72 + cq]) = bu[i];
    XT[(cq + 0) * 72 + t] = xu[i].x;
    XT[(cq + 1) * 72 + t] = xu[i].y;
    XT[(cq + 2) * 72 + t] = xu[i].z;
    XT[(cq + 3) * 72 + t] = xu[i].w;
    BT2[(cq + 0) * 72 + t] = bu[i].x;
    BT2[(cq + 1) * 72 + t] = bu[i].y;
    BT2[(cq + 2) * 72 + t] = bu[i].z;
    BT2[(cq + 3) * 72 + t] = bu[i].w;
    WXT[(cq + 0) * 72 + t] = f2bf(wvv * bf2f(xu[i].x));
    WXT[(cq + 1) * 72 + t] = f2bf(wvv * bf2f(xu[i].y));
    WXT[(cq + 2) * 72 + t] = f2bf(wvv * bf2f(xu[i].z));
    WXT[(cq + 3) * 72 + t] = f2bf(wvv * bf2f(xu[i].w));
  }
  __syncthreads();
  f32x4 accS[2][2] = {};
  #pragma unroll
  for (int ks = 0; ks < 2; ks++) {
    short8v af[2], bq[2];
    #pragma unroll
    for (int mt = 0; mt < 2; mt++)
      af[mt] = *reinterpret_cast<const short8v*>(&WXT[(wr + mt * 16 + ln15) * 72 + ks * 32 + kg * 8]);
    #pragma unroll
    for (int nt = 0; nt < 2; nt++)
      bq[nt] = *reinterpret_cast<const short8v*>(&BT2[(wc + nt * 16 + ln15) * 72 + ks * 32 + kg * 8]);
    #pragma unroll
    for (int mt = 0; mt < 2; mt++)
      #pragma unroll
      for (int nt = 0; nt < 2; nt++)
        accS[mt][nt] = __builtin_amdgcn_mfma_f32_16x16x32_bf16(af[mt], bq[nt], accS[mt][nt], 0, 0, 0);
  }
  f32x4 accA[2][2] = {};
  #pragma unroll
  for (int ks = 0; ks < 2; ks++) {
    short8v af[2], bq[2];
    #pragma unroll
    for (int mt = 0; mt < 2; mt++)
      af[mt] = *reinterpret_cast<const short8v*>(&Cb[(wr + mt * 16 + ln15) * 72 + ks * 32 + kg * 8]);
    #pragma unroll
    for (int nt = 0; nt < 2; nt++)
      bq[nt] = *reinterpret_cast<const short8v*>(&Bb[(wc + nt * 16 + ln15) * 72 + ks * 32 + kg * 8]);
    #pragma unroll
    for (int mt = 0; mt < 2; mt++)
      #pragma unroll
      for (int nt = 0; nt < 2; nt++)
        accA[mt][nt] = __builtin_amdgcn_mfma_f32_16x16x32_bf16(af[mt], bq[nt], accA[mt][nt], 0, 0, 0);
  }
  unsigned short gmb[2][2][4];
  #pragma unroll
  for (int mt = 0; mt < 2; mt++)
    #pragma unroll
    for (int nt = 0; nt < 2; nt++)
      #pragma unroll
      for (int q = 0; q < 4; q++) {
        int t = wr + mt * 16 + kg * 4 + q;
        int s = wc + nt * 16 + ln15;
        float v = (s <= t) ? accA[mt][nt][q] * expf(Cum[t] - Cum[s]) * Dt[s] : 0.f;
        gmb[mt][nt][q] = f2bf(v);
      }
  __syncthreads();
  #pragma unroll
  for (int mt = 0; mt < 2; mt++)
    #pragma unroll
    for (int nt = 0; nt < 2; nt++)
      #pragma unroll
      for (int q = 0; q < 4; q++) {
        Bb[(wr + mt * 16 + kg * 4 + q) * 72 + wc + nt * 16 + ln15] = gmb[mt][nt][q];
        int p = wr + mt * 16 + kg * 4 + q;
        int n = wc + nt * 16 + ln15;
        hb[p * 72 + n] = f2bf(accS[mt][nt][q]);
      }
  __syncthreads();
  f32x4 accY[2][2] = {};
  #pragma unroll
  for (int ks = 0; ks < 2; ks++) {
    short8v af[2], bq[2];
    #pragma unroll
    for (int mt = 0; mt < 2; mt++)
      af[mt] = *reinterpret_cast<const short8v*>(&Bb[(wr + mt * 16 + ln15) * 72 + ks * 32 + kg * 8]);
    #pragma unroll
    for (int nt = 0; nt < 2; nt++)
      bq[nt] = *reinterpret_cast<const short8v*>(&XT[(wc + nt * 16 + ln15) * 72 + ks * 32 + kg * 8]);
    #pragma unroll
    for (int mt = 0; mt < 2; mt++)
      #pragma unroll
      for (int nt = 0; nt < 2; nt++)
        accY[mt][nt] = __builtin_amdgcn_mfma_f32_16x16x32_bf16(af[mt], bq[nt], accY[mt][nt], 0, 0, 0);
  }
  #pragma unroll
  for (int mt = 0; mt < 2; mt++)
    #pragma unroll
    for (int q = 0; q < 4; q++) {
      int t = wr + mt * 16 + kg * 4 + q;
      const unsigned short* xp = xbc + (row0 + t) * conv_dim + (h << 6);
      unsigned short* yp = y + (row0 + t) * d_inner + (h << 6);
      #pragma unroll
      for (int nt = 0; nt < 2; nt++) {
        int p = wc + nt * 16 + ln15;
        yp[p] = f2bf(accY[mt][nt][q] + bf2f(xp[p]) * Dv);
      }
    }
  __syncthreads();

  long row1 = row0 + 64;
  #pragma unroll
  for (int i = 0; i < 4; i++) {
    int t = tq + i * 16;
    const unsigned short* rp = xbc + (row1 + t) * conv_dim;
    cu[i] = *reinterpret_cast<const ushort4*>(rp + d_inner + 64 + cq);
    bu[i] = *reinterpret_cast<const ushort4*>(rp + d_inner + cq);
    xu[i] = *reinterpret_cast<const ushort4*>(rp + (h << 6) + cq);
  }
  if (tid < 64) {
    long r = (row1 + tid) * H + h;
    Cum[tid] = wave_prefix_incl(la[r], tid);
    Dt[tid] = dtv[r];
  }
  __syncthreads();
  #pragma unroll
  for (int i = 0; i < 4; i++) {
    int t = tq + i * 16;
    *reinterpret_cast<ushort4*>(&Cb[t * 72 + cq]) = cu[i];
    *reinterpret_cast<ushort4*>(&Bb[t * 72 + cq]) = bu[i];
    XT[(cq + 0) * 72 + t] = xu[i].x;
    XT[(cq + 1) * 72 + t] = xu[i].y;
    XT[(cq + 2) * 72 + t] = xu[i].z;
    XT[(cq + 3) * 72 + t] = xu[i].w;
  }
  __syncthreads();
  f32x4 accA1[2][2] = {};
  #pragma unroll
  for (int ks = 0; ks < 2; ks++) {
    short8v af[2], bq[2];
    #pragma unroll
    for (int mt = 0; mt < 2; mt++)
      af[mt] = *reinterpret_cast<const short8v*>(&Cb[(wr + mt * 16 + ln15) * 72 + ks * 32 + kg * 8]);
    #pragma unroll
    for (int nt = 0; nt < 2; nt++)
      bq[nt] = *reinterpret_cast<const short8v*>(&Bb[(wc + nt * 16 + ln15) * 72 + ks * 32 + kg * 8]);
    #pragma unroll
    for (int mt = 0; mt < 2; mt++)
      #pragma unroll
      for (int nt = 0; nt < 2; nt++)
        accA1[mt][nt] = __builtin_amdgcn_mfma_f32_16x16x32_bf16(af[mt], bq[nt], accA1[mt][nt], 0, 0, 0);
  }
  #pragma unroll
  for (int mt = 0; mt < 2; mt++)
    #pragma unroll
    for (int nt = 0; nt < 2; nt++)
      #pragma unroll
      for (int q = 0; q < 4; q++) {
        int t = wr + mt * 16 + kg * 4 + q;
        int s = wc + nt * 16 + ln15;
        float v = (s <= t) ? accA1[mt][nt][q] * expf(Cum[t] - Cum[s]) * Dt[s] : 0.f;
        gmb[mt][nt][q] = f2bf(v);
      }
  __syncthreads();
  #pragma unroll
  for (int mt = 0; mt < 2; mt++)
    #pragma unroll
    for (int nt = 0; nt < 2; nt++)
      #pragma unroll
      for (int q = 0; q < 4; q++)
        Bb[(wr + mt * 16 + kg * 4 + q) * 72 + wc + nt * 16 + ln15] = gmb[mt][nt][q];
  __syncthreads();
  f32x4 accY1[2][2] = {}, accZ1[2][2] = {};
  #pragma unroll
  for (int ks = 0; ks < 2; ks++) {
    short8v af[2], bq[2];
    #pragma unroll
    for (int mt = 0; mt < 2; mt++)
      af[mt] = *reinterpret_cast<const short8v*>(&Bb[(wr + mt * 16 + ln15) * 72 + ks * 32 + kg * 8]);
    #pragma unroll
    for (int nt = 0; nt < 2; nt++)
      bq[nt] = *reinterpret_cast<const short8v*>(&XT[(wc + nt * 16 + ln15) * 72 + ks * 32 + kg * 8]);
    #pragma unroll
    for (int mt = 0; mt < 2; mt++)
      #pragma unroll
      for (int nt = 0; nt < 2; nt++)
        accY1[mt][nt] = __builtin_amdgcn_mfma_f32_16x16x32_bf16(af[mt], bq[nt], accY1[mt][nt], 0, 0, 0);
  }
  #pragma unroll
  for (int ks = 0; ks < 2; ks++) {
    short8v af[2], bq[2];
    #pragma unroll
    for (int mt = 0; mt < 2; mt++)
      af[mt] = *reinterpret_cast<const short8v*>(&Cb[(wr + mt * 16 + ln15) * 72 + ks * 32 + kg * 8]);
    #pragma unroll
    for (int nt = 0; nt < 2; nt++)
      bq[nt] = *reinterpret_cast<const short8v*>(&hb[(wc + nt * 16 + ln15) * 72 + ks * 32 + kg * 8]);
    #pragma unroll
    for (int mt = 0; mt < 2; mt++)
      #pragma unroll
      for (int nt = 0; nt < 2; nt++)
        accZ1[mt][nt] = __builtin_amdgcn_mfma_f32_16x16x32_bf16(af[mt], bq[nt], accZ1[mt][nt], 0, 0, 0);
  }
  #pragma unroll
  for (int mt = 0; mt < 2; mt++)
    #pragma unroll
    for (int q = 0; q < 4; q++) {
      int t = wr + mt * 16 + kg * 4 + q;
      float wB = expf(Cum[t]);
      const unsigned short* xp = xbc + (row1 + t) * conv_dim + (h << 6);
      unsigned short* yp = y + (row1 + t) * d_inner + (h << 6);
      #pragma unroll
      for (int nt = 0; nt < 2; nt++) {
        int p = wc + nt * 16 + ln15;
        yp[p] = f2bf(accY1[mt][nt][q] + accZ1[mt][nt][q] * wB + bf2f(xp[p]) * Dv);
      }
    }
}

// --- wave-per-row: g = y*silu(z); g *= rsqrt(mean(g^2)+eps)*rms_w; bf16 out ---
template <int CPL>
__global__ __launch_bounds__(256) void gate_rms_bf16(const unsigned short* __restrict__ y,
                                                     const unsigned short* __restrict__ z,
                                                     const float* __restrict__ rmsw,
                                                     unsigned short* __restrict__ ab,
                                                     int d_inner) {
  long row = (long)blockIdx.x * 4 + (threadIdx.x >> 6);
  int lane = threadIdx.x & 63;
  const unsigned short* yr = y + row * d_inner;
  const unsigned short* zr = z + row * d_inner;
  float g[CPL];
  float ss = 0.f;
  #pragma unroll
  for (int j = 0; j < CPL / 4; j++) {
    int c = j * 256 + lane * 4;
    ushort4 yv = *reinterpret_cast<const ushort4*>(&yr[c]);
    ushort4 zv = *reinterpret_cast<const ushort4*>(&zr[c]);
    float g0 = bf2f(yv.x) * siluf(bf2f(zv.x));
    float g1 = bf2f(yv.y) * siluf(bf2f(zv.y));
    float g2 = bf2f(yv.z) * siluf(bf2f(zv.z));
    float g3 = bf2f(yv.w) * siluf(bf2f(zv.w));
    g[j * 4 + 0] = g0; g[j * 4 + 1] = g1; g[j * 4 + 2] = g2; g[j * 4 + 3] = g3;
    ss += g0 * g0 + g1 * g1 + g2 * g2 + g3 * g3;
  }
  #pragma unroll
  for (int o = 32; o; o >>= 1) ss += __shfl_xor(ss, o);
  float inv = rsqrtf(ss / (float)d_inner + EPSV);
  #pragma unroll
  for (int j = 0; j < CPL / 4; j++) {
    int c = j * 256 + lane * 4;
    float4 wv = *reinterpret_cast<const float4*>(&rmsw[c]);
    ushort4 o;
    o.x = f2bf(g[j * 4 + 0] * inv * wv.x);
    o.y = f2bf(g[j * 4 + 1] * inv * wv.y);
    o.z = f2bf(g[j * 4 + 2] * inv * wv.z);
    o.w = f2bf(g[j * 4 + 3] * inv * wv.w);
    *reinterpret_cast<ushort4*>(&ab[row * d_inner + c]) = o;
  }
}

extern "C" void kernel_launch(void* const* d_in, const int* in_sizes, int n_in,
                              void* d_out, int out_size, void* d_ws,
                              size_t ws_size, hipStream_t stream) {
  const float* x        = (const float*)d_in[0];
  const float* ln_spa_w = (const float*)d_in[1];
  const float* ln_spa_b = (const float*)d_in[2];
  const float* ln_spe_w = (const float*)d_in[3];
  const float* ln_spe_b = (const float*)d_in[4];
  const float* spa_W_in   = (const float*)d_in[5];
  const float* spa_conv_w = (const float*)d_in[6];
  const float* spa_conv_b = (const float*)d_in[7];
  const float* spa_dt_b   = (const float*)d_in[8];
  const float* spa_A_log  = (const float*)d_in[9];
  const float* spa_D      = (const float*)d_in[10];
  const float* spa_rms_w  = (const float*)d_in[11];
  const float* spa_W_out  = (const float*)d_in[12];
  const float* spe_W_in   = (const float*)d_in[13];
  const float* spe_conv_w = (const float*)d_in[14];
  const float* spe_conv_b = (const float*)d_in[15];
  const float* spe_dt_b   = (const float*)d_in[16];
  const float* spe_A_log  = (const float*)d_in[17];
  const float* spe_D      = (const float*)d_in[18];
  const float* spe_rms_w  = (const float*)d_in[19];
  const float* spe_W_out  = (const float*)d_in[20];
  float* out = (float*)d_out;

  float* ws = (float*)d_ws;
  float* xspa   = ws;                 // 1,048,576
  unsigned short* z = (unsigned short*)(ws + 1048576);
  unsigned short* xbcraw = (unsigned short*)(ws + 3145728);
  float* Sc     = ws + 3145728;       // overlay (xbcraw dead after conv; spa only)
  float* dtraw  = ws + 6291456;       // 32,768 (later Aprod)
  unsigned short* cv = (unsigned short*)(ws + 6324224);
  float* dtb    = ws + 9469952;       // 32,768 (also spe LN partials)
  float* la     = ws + 9502720;       // 32,768
  unsigned short* yb = (unsigned short*)(ws + 9535488);
  unsigned short* Abf     = (unsigned short*)(ws + 11634688);
  unsigned short* Wt_spai = (unsigned short*)(ws + 12683264);
  unsigned short* Wt_spao = (unsigned short*)(ws + 12724480);
  unsigned short* Wt_spei = (unsigned short*)(ws + 12740864);
  unsigned short* Wt_speo = (unsigned short*)(ws + 14919936);

  // 1. slim prologue: spa LN + spa_W_in transpose only (22 tiles)
  hipLaunchKernelGGL(ln_wt0, dim3(4118), dim3(256), 0, stream,
                     x, ln_spa_w, ln_spa_b, Abf, spa_W_in, Wt_spai);

  // ================= spatial mamba (L=1024, d_model=128) =================
  hipLaunchKernelGGL(gemm128_split, dim3(6, 64), dim3(256), 0, stream,
                     Abf, Wt_spai, z, xbcraw, dtraw,
                     8192, 644, 128, 256, 640);
  // conv+dtda, plus piggybacked transposes: spa_W_out (8) + spe_W_in (1072)
  hipLaunchKernelGGL(conv_dtda, dim3(4280), dim3(256), 0, stream,
                     xbcraw, spa_conv_w, spa_conv_b, cv,
                     dtraw, spa_dt_b, spa_A_log, dtb, la,
                     8, 1024, 384, 4, 32768, 3072,
                     spa_W_out, Wt_spao, spe_W_in, Wt_spei, 3200);
  // chunk states, plus piggybacked spe_W_out transpose (512 tiles)
  hipLaunchKernelGGL(ssd_local, dim3(992), dim3(256), 0, stream,
                     cv, dtb, la, Sc, dtraw, 16, 15, 4, 384, 256,
                     spe_W_out, Wt_speo, 480);
  hipLaunchKernelGGL(ssd_out, dim3(512), dim3(256), 0, stream,
                     cv, dtb, la, Sc, dtraw, spa_D, yb, 16, 4, 384, 256);
  hipLaunchKernelGGL((gate_rms_bf16<4>), dim3(2048), dim3(256), 0, stream,
                     yb, z, spa_rms_w, Abf, 256);
  hipLaunchKernelGGL(gemm_mfma1, dim3(2, 128), dim3(256), 0, stream,
                     Abf, Wt_spao, x, xspa, dtb, 8192, 128, 256);

  // ================= spectral mamba (L=128, d_model=1024) =================
  hipLaunchKernelGGL(spe_normT, dim3(2, 8, 8), dim3(256), 0, stream,
                     xspa, dtb, ln_spe_w, ln_spe_b, Abf);
  hipLaunchKernelGGL(gemm128_split, dim3(34, 8), dim3(256), 0, stream,
                     Abf, Wt_spei, z, xbcraw, dtraw,
                     1024, 4256, 1024, 2048, 4224);
  hipLaunchKernelGGL(conv_dtda, dim3(2304), dim3(256), 0, stream,
                     xbcraw, spe_conv_w, spe_conv_b, cv,
                     dtraw, spe_dt_b, spe_A_log, dtb, la,
                     8, 128, 2176, 32, 32768, 2176,
                     spa_W_out, Wt_spao, spe_W_in, Wt_spei, 2304);
  hipLaunchKernelGGL(ssd_spe2, dim3(256), dim3(256), 0, stream,
                     cv, dtb, la, spe_D, yb, 32, 2176, 2048);
  hipLaunchKernelGGL((gate_rms_bf16<32>), dim3(256), dim3(256), 0, stream,
                     yb, z, spe_rms_w, Abf, 2048);
  hipLaunchKernelGGL(gemm128x64_t, dim3(16, 8), dim3(256), 0, stream,
                     Abf, Wt_speo, xspa, out, 1024, 1024, 2048);
}